// Round 7
// baseline (2583.186 us; speedup 1.0000x reference)
//
#include <hip/hip_runtime.h>
#include <hip/hip_bf16.h>
#include <cstdint>

#define EMB    768
#define NHEADS 12
#define HDIM   64
#define SEQ    1024
#define BATCH  8
#define MROWS  (BATCH*SEQ)   /* 8192 */
#define FFN    3072

typedef __bf16 bf16_t;
typedef bf16_t bf16x8 __attribute__((ext_vector_type(8)));
typedef float  f32x4  __attribute__((ext_vector_type(4)));

__device__ __forceinline__ float b2f(unsigned short u) {
    union { unsigned int i; float f; } t; t.i = ((unsigned int)u) << 16; return t.f;
}
__device__ __forceinline__ unsigned short f2b(float f) {
    union { float f; unsigned int i; } t; t.f = f;
    unsigned int lsb = (t.i >> 16) & 1u;
    t.i += 0x7fffu + lsb;
    return (unsigned short)(t.i >> 16);
}

// load 8 consecutive logical elements as 8 bf16 halves (packed int4)
__device__ __forceinline__ int4 load8(const void* src, size_t eoff, bool f32) {
    if (f32) {
        const float4* p = reinterpret_cast<const float4*>((const float*)src + eoff);
        float4 a = p[0], b = p[1];
        union { unsigned short u[8]; int4 v; } r;
        r.u[0] = f2b(a.x); r.u[1] = f2b(a.y); r.u[2] = f2b(a.z); r.u[3] = f2b(a.w);
        r.u[4] = f2b(b.x); r.u[5] = f2b(b.y); r.u[6] = f2b(b.z); r.u[7] = f2b(b.w);
        return r.v;
    }
    return *reinterpret_cast<const int4*>((const unsigned short*)src + eoff);
}
// load 4 consecutive logical elements as floats
__device__ __forceinline__ float4 load4f(const void* src, size_t eoff, bool f32) {
    if (f32) return *reinterpret_cast<const float4*>((const float*)src + eoff);
    ushort4 u = *reinterpret_cast<const ushort4*>((const unsigned short*)src + eoff);
    float4 r; r.x = b2f(u.x); r.y = b2f(u.y); r.z = b2f(u.z); r.w = b2f(u.w);
    return r;
}

// ---------------- dtype probe (stable since r4 — unchanged) ---------------
__global__ __launch_bounds__(256) void detect_kernel(
        const unsigned short* __restrict__ src, int n_elems, int* __restrict__ flag) {
    __shared__ int cnt;
    if (threadIdx.x == 0) cnt = 0;
    __syncthreads();
    int npairs = n_elems / 2;
    if (npairs > 4096) npairs = 4096;
    int local = 0;
    for (int p = threadIdx.x; p < npairs; p += 256) {
        unsigned short u0 = src[2 * p], u1 = src[2 * p + 1];
        int e0 = (u0 >> 7) & 0xFF;
        bool insane0 = (e0 == 0xFF) || (u0 != 0 && (e0 < 96 || e0 > 159));
        bool zpat    = (u0 == 0 && u1 != 0);
        if (insane0 || zpat) ++local;
    }
    atomicAdd(&cnt, local);
    __syncthreads();
    if (threadIdx.x == 0) *flag = (cnt * 8 > npairs) ? 1 : 0;  // >12.5% => fp32
}

// ---------------- LayerNorm: one wave per row; bf16 out -------------------
__global__ __launch_bounds__(256) void ln_kernel(
        const void* __restrict__ x,     const int* __restrict__ fx,
        const void* __restrict__ scale, const int* __restrict__ fsc,
        const void* __restrict__ shift, const int* __restrict__ fsh,
        unsigned short* __restrict__ out) {
    const bool xf = fx && *fx, scf = fsc && *fsc, shf = fsh && *fsh;
    int wave = threadIdx.x >> 6;
    int lane = threadIdx.x & 63;
    int row  = blockIdx.x * 4 + wave;
    const size_t rbase = (size_t)row * EMB;
    float v[12];
    float s = 0.f, s2 = 0.f;
    #pragma unroll
    for (int i = 0; i < 3; ++i) {
        float4 a = load4f(x, rbase + i * 256 + lane * 4, xf);
        v[i*4+0] = a.x; v[i*4+1] = a.y; v[i*4+2] = a.z; v[i*4+3] = a.w;
        s  += a.x + a.y + a.z + a.w;
        s2 += a.x*a.x + a.y*a.y + a.z*a.z + a.w*a.w;
    }
    #pragma unroll
    for (int off = 1; off < 64; off <<= 1) {
        s  += __shfl_xor(s,  off);
        s2 += __shfl_xor(s2, off);
    }
    float mean = s * (1.f / EMB);
    float var  = fmaxf(s2 * (1.f / EMB) - mean * mean, 0.f);
    float rstd = rsqrtf(var + 1e-5f);
    unsigned short* orow = out + rbase;
    #pragma unroll
    for (int i = 0; i < 3; ++i) {
        float4 sc = load4f(scale, i * 256 + lane * 4, scf);
        float4 sh = load4f(shift, i * 256 + lane * 4, shf);
        ushort4 o;
        o.x = f2b((v[i*4+0] - mean) * rstd * sc.x + sh.x);
        o.y = f2b((v[i*4+1] - mean) * rstd * sc.y + sh.y);
        o.z = f2b((v[i*4+2] - mean) * rstd * sc.z + sh.z);
        o.w = f2b((v[i*4+3] - mean) * rstd * sc.w + sh.w);
        *reinterpret_cast<ushort4*>(orow + i * 256 + lane * 4) = o;
    }
}

// ---------------- GEMM: C[M,N] = A[M,K] @ W[N,K]^T (+gelu/+resid) ---------
// A: bf16 (our buffers). W: dtype-flagged. R: dtype-flagged + rOff.
// OUTF32: write C as fp32 (final output) else bf16 (staging).
template<bool GELU, bool RESID, bool OUTF32>
__global__ __launch_bounds__(256) void gemm_bt(
        const unsigned short* __restrict__ A,
        const void* __restrict__ W, const int* __restrict__ fW,
        const void* R, const int* __restrict__ fR, size_t rOff,
        void* C,
        int M, int N, int K) {
    const bool wf = fW && *fW;
    const bool rf = fR && *fR;
    constexpr int BK = 32, PAD = 8, LDW = BK + PAD;
    __shared__ __align__(16) unsigned short sA[128 * LDW];
    __shared__ __align__(16) unsigned short sB[128 * LDW];
    const int m0 = blockIdx.x * 128;
    const int n0 = blockIdx.y * 128;
    const int t    = threadIdx.x;
    const int wave = t >> 6, lane = t & 63;
    const int wrow = (wave >> 1) * 64, wcol = (wave & 1) * 64;
    const int quad = lane >> 4, lr = lane & 15;
    const int srow = t >> 2, scol = (t & 3) * 8;

    f32x4 acc[4][4];
    #pragma unroll
    for (int i = 0; i < 4; ++i)
        #pragma unroll
        for (int j = 0; j < 4; ++j)
            acc[i][j] = (f32x4){0.f, 0.f, 0.f, 0.f};

    const size_t aBase = (size_t)(m0 + srow) * K + scol;
    const size_t bBase = (size_t)(n0 + srow) * K + scol;

    for (int k0 = 0; k0 < K; k0 += BK) {
        int4 av0 = *reinterpret_cast<const int4*>(A + aBase + k0);
        int4 av1 = *reinterpret_cast<const int4*>(A + aBase + (size_t)64 * K + k0);
        int4 bv0 = load8(W, bBase + k0, wf);
        int4 bv1 = load8(W, bBase + (size_t)64 * K + k0, wf);
        *reinterpret_cast<int4*>(sA + srow * LDW + scol)        = av0;
        *reinterpret_cast<int4*>(sA + (srow + 64) * LDW + scol) = av1;
        *reinterpret_cast<int4*>(sB + srow * LDW + scol)        = bv0;
        *reinterpret_cast<int4*>(sB + (srow + 64) * LDW + scol) = bv1;
        __syncthreads();
        bf16x8 af[4], bfv[4];
        #pragma unroll
        for (int i = 0; i < 4; ++i)
            af[i] = *reinterpret_cast<const bf16x8*>(sA + (wrow + i * 16 + lr) * LDW + quad * 8);
        #pragma unroll
        for (int j = 0; j < 4; ++j)
            bfv[j] = *reinterpret_cast<const bf16x8*>(sB + (wcol + j * 16 + lr) * LDW + quad * 8);
        #pragma unroll
        for (int i = 0; i < 4; ++i)
            #pragma unroll
            for (int j = 0; j < 4; ++j)
                acc[i][j] = __builtin_amdgcn_mfma_f32_16x16x32_bf16(af[i], bfv[j], acc[i][j], 0, 0, 0);
        __syncthreads();
    }

    // epilogue: C/D layout row = quad*4 + r, col = lane&15
    #pragma unroll
    for (int i = 0; i < 4; ++i) {
        #pragma unroll
        for (int j = 0; j < 4; ++j) {
            #pragma unroll
            for (int r = 0; r < 4; ++r) {
                int row = m0 + wrow + i * 16 + quad * 4 + r;
                int col = n0 + wcol + j * 16 + lr;
                float val = acc[i][j][r];
                if (GELU) {
                    float x3 = val * val * val;
                    val = 0.5f * val * (1.f + tanhf(0.7978845608028654f * (val + 0.044715f * x3)));
                }
                size_t idx = (size_t)row * N + col;
                if (RESID) {
                    float rv = rf ? ((const float*)R)[idx + rOff]
                                  : b2f(((const unsigned short*)R)[idx + rOff]);
                    val += rv;
                }
                if (OUTF32) ((float*)C)[idx] = val;
                else        ((unsigned short*)C)[idx] = f2b(val);
            }
        }
    }
}

// ---------------- Causal attention: one wave per (batch, head, query) -----
__global__ __launch_bounds__(256) void attn_kernel(
        const unsigned short* __restrict__ q,
        const unsigned short* __restrict__ k,
        const unsigned short* __restrict__ v,
        unsigned short* __restrict__ ctx) {
    __shared__ float sc[4][SEQ];
    __shared__ float qs[4][HDIM];
    const int wave = threadIdx.x >> 6, lane = threadIdx.x & 63;
    const int bh = blockIdx.x >> 8;
    const int bb = bh / NHEADS, hd = bh % NHEADS;
    const int qi = ((blockIdx.x & 255) << 2) + wave;
    const int nk = qi + 1;

    const unsigned short* qrow = q + ((size_t)(bb * SEQ + qi) * EMB + hd * HDIM);
    qs[wave][lane] = b2f(qrow[lane]) * 0.125f;
    __syncthreads();

    const unsigned short* kbase = k + ((size_t)bb * SEQ * EMB + hd * HDIM);
    for (int j = lane; j < nk; j += 64) {
        const unsigned short* kr = kbase + (size_t)j * EMB;
        float s = 0.f;
        #pragma unroll
        for (int d4 = 0; d4 < 16; ++d4) {
            ushort4 kv = *reinterpret_cast<const ushort4*>(kr + d4 * 4);
            s += qs[wave][d4*4+0] * b2f(kv.x);
            s += qs[wave][d4*4+1] * b2f(kv.y);
            s += qs[wave][d4*4+2] * b2f(kv.z);
            s += qs[wave][d4*4+3] * b2f(kv.w);
        }
        sc[wave][j] = s;
    }

    float mx = -1e30f;
    for (int j = lane; j < nk; j += 64) mx = fmaxf(mx, sc[wave][j]);
    #pragma unroll
    for (int off = 1; off < 64; off <<= 1) mx = fmaxf(mx, __shfl_xor(mx, off));
    float ssum = 0.f;
    for (int j = lane; j < nk; j += 64) {
        float e = __expf(sc[wave][j] - mx);
        sc[wave][j] = e;
        ssum += e;
    }
    #pragma unroll
    for (int off = 1; off < 64; off <<= 1) ssum += __shfl_xor(ssum, off);
    const float rinv = 1.f / ssum;

    __syncthreads();

    const unsigned short* vbase = v + ((size_t)bb * SEQ * EMB + hd * HDIM + lane);
    float acc = 0.f;
    int j = 0;
    for (; j + 4 <= nk; j += 4) {
        float p0 = sc[wave][j + 0], p1 = sc[wave][j + 1];
        float p2 = sc[wave][j + 2], p3 = sc[wave][j + 3];
        acc += p0 * b2f(vbase[(size_t)(j + 0) * EMB]);
        acc += p1 * b2f(vbase[(size_t)(j + 1) * EMB]);
        acc += p2 * b2f(vbase[(size_t)(j + 2) * EMB]);
        acc += p3 * b2f(vbase[(size_t)(j + 3) * EMB]);
    }
    for (; j < nk; ++j) acc += sc[wave][j] * b2f(vbase[(size_t)j * EMB]);
    ctx[(size_t)(bb * SEQ + qi) * EMB + hd * HDIM + lane] = f2b(acc * rinv);
}

// ---------------------------------------------------------------------------
extern "C" void kernel_launch(void* const* d_in, const int* in_sizes, int n_in,
                              void* d_out, int out_size, void* d_ws, size_t ws_size,
                              hipStream_t stream) {
    const void* x  = d_in[0];
    const void* wq = d_in[1], *wk = d_in[2], *wv = d_in[3], *wo = d_in[4];
    const void* w1 = d_in[5], *w2 = d_in[6];
    const void* g1 = d_in[7], *s1 = d_in[8], *g2 = d_in[9], *s2 = d_in[10];
    char* ws = (char*)d_ws;
    dim3 blk(256);

    int* F = (int*)ws;
    for (int i = 0; i < 11; ++i)
        detect_kernel<<<1, blk, 0, stream>>>((const unsigned short*)d_in[i], in_sizes[i], F + i);

    const size_t SZE = (size_t)MROWS * EMB;   // 6,291,456 elems
    const size_t SZB = SZE * 2;               // 12,582,912 bytes (bf16 buf)
    unsigned short* base = (unsigned short*)(ws + 256);
    dim3 g768(MROWS / 128, EMB / 128);

    if (ws_size >= 256 + 7 * SZB) {
        // ---- tier A: full-width; d_out untouched until final fp32 store ----
        unsigned short* B0 = base;            // h -> ctx
        unsigned short* B1 = B0 + SZE;        // q -> x2
        unsigned short* B2 = B1 + SZE;        // k -> h2
        unsigned short* Bg = B2 + SZE;        // v, then g [4*SZE]
        dim3 g3072(MROWS / 128, FFN / 128);
        ln_kernel<<<MROWS / 4, blk, 0, stream>>>(x, F+0, g1, F+7, s1, F+8, B0);
        gemm_bt<false, false, false><<<g768, blk, 0, stream>>>(B0, wq, F+1, nullptr, nullptr, 0, B1, MROWS, EMB, EMB);
        gemm_bt<false, false, false><<<g768, blk, 0, stream>>>(B0, wk, F+2, nullptr, nullptr, 0, B2, MROWS, EMB, EMB);
        gemm_bt<false, false, false><<<g768, blk, 0, stream>>>(B0, wv, F+3, nullptr, nullptr, 0, Bg, MROWS, EMB, EMB);
        attn_kernel<<<BATCH * NHEADS * 256, blk, 0, stream>>>(B1, B2, Bg, B0);
        gemm_bt<false, true, false><<<g768, blk, 0, stream>>>(B0, wo, F+4, x, F+0, 0, B1, MROWS, EMB, EMB);
        ln_kernel<<<MROWS / 4, blk, 0, stream>>>(B1, nullptr, g2, F+9, s2, F+10, B2);
        gemm_bt<true, false, false><<<g3072, blk, 0, stream>>>(B2, w1, F+5, nullptr, nullptr, 0, Bg, MROWS, FFN, EMB);
        gemm_bt<false, true, true><<<g768, blk, 0, stream>>>(Bg, w2, F+6, B1, nullptr, 0, d_out, MROWS, EMB, FFN);
    } else if (ws_size >= 256 + 4 * SZB) {
        // ---- tier M: full attention, FFN in 2048-row chunks ----
        unsigned short* B0 = base;
        unsigned short* B1 = B0 + SZE;
        unsigned short* B2 = B1 + SZE;
        unsigned short* B3 = B2 + SZE;
        ln_kernel<<<MROWS / 4, blk, 0, stream>>>(x, F+0, g1, F+7, s1, F+8, B0);
        gemm_bt<false, false, false><<<g768, blk, 0, stream>>>(B0, wq, F+1, nullptr, nullptr, 0, B1, MROWS, EMB, EMB);
        gemm_bt<false, false, false><<<g768, blk, 0, stream>>>(B0, wk, F+2, nullptr, nullptr, 0, B2, MROWS, EMB, EMB);
        gemm_bt<false, false, false><<<g768, blk, 0, stream>>>(B0, wv, F+3, nullptr, nullptr, 0, B3, MROWS, EMB, EMB);
        attn_kernel<<<BATCH * NHEADS * 256, blk, 0, stream>>>(B1, B2, B3, B0);
        gemm_bt<false, true, false><<<g768, blk, 0, stream>>>(B0, wo, F+4, x, F+0, 0, B1, MROWS, EMB, EMB);
        ln_kernel<<<MROWS / 4, blk, 0, stream>>>(B1, nullptr, g2, F+9, s2, F+10, B2);
        dim3 c3072(2048 / 128, FFN / 128), c768(2048 / 128, EMB / 128);
        for (int c = 0; c < 4; ++c) {
            const size_t r0 = (size_t)c * 2048;
            gemm_bt<true, false, false><<<c3072, blk, 0, stream>>>(B2 + r0 * EMB, w1, F+5, nullptr, nullptr, 0, B3, 2048, FFN, EMB);
            gemm_bt<false, true, true><<<c768, blk, 0, stream>>>(B3, w2, F+6, B1 + r0 * EMB, nullptr, 0, (float*)d_out + r0 * EMB, 2048, EMB, FFN);
        }
    } else {
        // ---- tier B: d_out (25.17 MB fp32) stages bf16 h (lower half) and
        //      x2 (upper half); fp32 write-front never passes the x2 read-front
        //      (c*3.146MB <= 12.58MB + c*1.573MB for all c<8); per-chunk x2 is
        //      bounced to ws before its own fp32 overwrite. ws peak 9.44 MB.
        unsigned short* hlow = (unsigned short*)d_out;        // h bf16 [8192,768]
        unsigned short* x2up = (unsigned short*)d_out + SZE;  // x2 bf16 [8192,768]
        unsigned short* wsQ = base;
        unsigned short* wsK = wsQ + (size_t)1024 * EMB;
        unsigned short* wsV = wsK + (size_t)1024 * EMB;
        unsigned short* wsC = wsV + (size_t)1024 * EMB;
        ln_kernel<<<MROWS / 4, blk, 0, stream>>>(x, F+0, g1, F+7, s1, F+8, hlow);
        dim3 q768(1024 / 128, EMB / 128);
        for (int grp = 0; grp < BATCH; ++grp) {
            const size_t r0 = (size_t)grp * 1024;
            gemm_bt<false, false, false><<<q768, blk, 0, stream>>>(hlow + r0 * EMB, wq, F+1, nullptr, nullptr, 0, wsQ, 1024, EMB, EMB);
            gemm_bt<false, false, false><<<q768, blk, 0, stream>>>(hlow + r0 * EMB, wk, F+2, nullptr, nullptr, 0, wsK, 1024, EMB, EMB);
            gemm_bt<false, false, false><<<q768, blk, 0, stream>>>(hlow + r0 * EMB, wv, F+3, nullptr, nullptr, 0, wsV, 1024, EMB, EMB);
            attn_kernel<<<1 * NHEADS * 256, blk, 0, stream>>>(wsQ, wsK, wsV, wsC);
            gemm_bt<false, true, false><<<q768, blk, 0, stream>>>(wsC, wo, F+4, x, F+0, r0 * EMB, x2up + r0 * EMB, 1024, EMB, EMB);
        }
        unsigned short* xb = base;                          // x2 bounce [1024,768]
        unsigned short* h2 = xb + (size_t)1024 * EMB;       // [1024,768]
        unsigned short* gb = h2 + (size_t)1024 * EMB;       // [1024,3072]
        dim3 f3072(1024 / 128, FFN / 128), f768(1024 / 128, EMB / 128);
        for (int c = 0; c < BATCH; ++c) {
            const size_t r0 = (size_t)c * 1024;
            hipMemcpyAsync(xb, x2up + r0 * EMB, (size_t)1024 * EMB * 2,
                           hipMemcpyDeviceToDevice, stream);
            ln_kernel<<<1024 / 4, blk, 0, stream>>>(xb, nullptr, g2, F+9, s2, F+10, h2);
            gemm_bt<true, false, false><<<f3072, blk, 0, stream>>>(h2, w1, F+5, nullptr, nullptr, 0, gb, 1024, FFN, EMB);
            gemm_bt<false, true, true><<<f768, blk, 0, stream>>>(gb, w2, F+6, xb, nullptr, 0, (float*)d_out + r0 * EMB, 1024, EMB, FFN);
        }
    }
}

// Round 8
// 773.724 us; speedup vs baseline: 3.3386x; 3.3386x over previous
//
#include <hip/hip_runtime.h>
#include <hip/hip_bf16.h>
#include <cstdint>

#define EMB    768
#define NHEADS 12
#define HDIM   64
#define SEQ    1024
#define BATCH  8
#define MROWS  (BATCH*SEQ)   /* 8192 */
#define FFN    3072

typedef __bf16 bf16_t;
typedef bf16_t bf16x8 __attribute__((ext_vector_type(8)));
typedef float  f32x4  __attribute__((ext_vector_type(4)));

__device__ __forceinline__ float b2f(unsigned short u) {
    union { unsigned int i; float f; } t; t.i = ((unsigned int)u) << 16; return t.f;
}
__device__ __forceinline__ unsigned short f2b(float f) {
    union { float f; unsigned int i; } t; t.f = f;
    unsigned int lsb = (t.i >> 16) & 1u;
    t.i += 0x7fffu + lsb;
    return (unsigned short)(t.i >> 16);
}

// load 8 consecutive logical elements as 8 bf16 halves (packed int4)
__device__ __forceinline__ int4 load8(const void* src, size_t eoff, bool f32) {
    if (f32) {
        const float4* p = reinterpret_cast<const float4*>((const float*)src + eoff);
        float4 a = p[0], b = p[1];
        union { unsigned short u[8]; int4 v; } r;
        r.u[0] = f2b(a.x); r.u[1] = f2b(a.y); r.u[2] = f2b(a.z); r.u[3] = f2b(a.w);
        r.u[4] = f2b(b.x); r.u[5] = f2b(b.y); r.u[6] = f2b(b.z); r.u[7] = f2b(b.w);
        return r.v;
    }
    return *reinterpret_cast<const int4*>((const unsigned short*)src + eoff);
}
// load 4 consecutive logical elements as floats
__device__ __forceinline__ float4 load4f(const void* src, size_t eoff, bool f32) {
    if (f32) return *reinterpret_cast<const float4*>((const float*)src + eoff);
    ushort4 u = *reinterpret_cast<const ushort4*>((const unsigned short*)src + eoff);
    float4 r; r.x = b2f(u.x); r.y = b2f(u.y); r.z = b2f(u.z); r.w = b2f(u.w);
    return r;
}

// ---------------- dtype probe (stable since r4 — unchanged) ---------------
__global__ __launch_bounds__(256) void detect_kernel(
        const unsigned short* __restrict__ src, int n_elems, int* __restrict__ flag) {
    __shared__ int cnt;
    if (threadIdx.x == 0) cnt = 0;
    __syncthreads();
    int npairs = n_elems / 2;
    if (npairs > 4096) npairs = 4096;
    int local = 0;
    for (int p = threadIdx.x; p < npairs; p += 256) {
        unsigned short u0 = src[2 * p], u1 = src[2 * p + 1];
        int e0 = (u0 >> 7) & 0xFF;
        bool insane0 = (e0 == 0xFF) || (u0 != 0 && (e0 < 96 || e0 > 159));
        bool zpat    = (u0 == 0 && u1 != 0);
        if (insane0 || zpat) ++local;
    }
    atomicAdd(&cnt, local);
    __syncthreads();
    if (threadIdx.x == 0) *flag = (cnt * 8 > npairs) ? 1 : 0;  // >12.5% => fp32
}

// ---------------- LayerNorm: one wave per row; bf16 out -------------------
__global__ __launch_bounds__(256) void ln_kernel(
        const void* __restrict__ x,     const int* __restrict__ fx,
        const void* __restrict__ scale, const int* __restrict__ fsc,
        const void* __restrict__ shift, const int* __restrict__ fsh,
        unsigned short* __restrict__ out) {
    const bool xf = fx && *fx, scf = fsc && *fsc, shf = fsh && *fsh;
    int wave = threadIdx.x >> 6;
    int lane = threadIdx.x & 63;
    int row  = blockIdx.x * 4 + wave;
    const size_t rbase = (size_t)row * EMB;
    float v[12];
    float s = 0.f, s2 = 0.f;
    #pragma unroll
    for (int i = 0; i < 3; ++i) {
        float4 a = load4f(x, rbase + i * 256 + lane * 4, xf);
        v[i*4+0] = a.x; v[i*4+1] = a.y; v[i*4+2] = a.z; v[i*4+3] = a.w;
        s  += a.x + a.y + a.z + a.w;
        s2 += a.x*a.x + a.y*a.y + a.z*a.z + a.w*a.w;
    }
    #pragma unroll
    for (int off = 1; off < 64; off <<= 1) {
        s  += __shfl_xor(s,  off);
        s2 += __shfl_xor(s2, off);
    }
    float mean = s * (1.f / EMB);
    float var  = fmaxf(s2 * (1.f / EMB) - mean * mean, 0.f);
    float rstd = rsqrtf(var + 1e-5f);
    unsigned short* orow = out + rbase;
    #pragma unroll
    for (int i = 0; i < 3; ++i) {
        float4 sc = load4f(scale, i * 256 + lane * 4, scf);
        float4 sh = load4f(shift, i * 256 + lane * 4, shf);
        ushort4 o;
        o.x = f2b((v[i*4+0] - mean) * rstd * sc.x + sh.x);
        o.y = f2b((v[i*4+1] - mean) * rstd * sc.y + sh.y);
        o.z = f2b((v[i*4+2] - mean) * rstd * sc.z + sh.z);
        o.w = f2b((v[i*4+3] - mean) * rstd * sc.w + sh.w);
        *reinterpret_cast<ushort4*>(orow + i * 256 + lane * 4) = o;
    }
}

// ---------------- GEMM: C[M,N] = A[M,K] @ W[N,K]^T (+gelu/+resid) ---------
template<bool GELU, bool RESID, bool OUTF32>
__global__ __launch_bounds__(256) void gemm_bt(
        const unsigned short* __restrict__ A,
        const void* __restrict__ W, const int* __restrict__ fW,
        const void* R, const int* __restrict__ fR, size_t rOff,
        void* C,
        int M, int N, int K) {
    const bool wf = fW && *fW;
    const bool rf = fR && *fR;
    constexpr int BK = 32, PAD = 8, LDW = BK + PAD;
    __shared__ __align__(16) unsigned short sA[128 * LDW];
    __shared__ __align__(16) unsigned short sB[128 * LDW];
    const int m0 = blockIdx.x * 128;
    const int n0 = blockIdx.y * 128;
    const int t    = threadIdx.x;
    const int wave = t >> 6, lane = t & 63;
    const int wrow = (wave >> 1) * 64, wcol = (wave & 1) * 64;
    const int quad = lane >> 4, lr = lane & 15;
    const int srow = t >> 2, scol = (t & 3) * 8;

    f32x4 acc[4][4];
    #pragma unroll
    for (int i = 0; i < 4; ++i)
        #pragma unroll
        for (int j = 0; j < 4; ++j)
            acc[i][j] = (f32x4){0.f, 0.f, 0.f, 0.f};

    const size_t aBase = (size_t)(m0 + srow) * K + scol;
    const size_t bBase = (size_t)(n0 + srow) * K + scol;

    for (int k0 = 0; k0 < K; k0 += BK) {
        int4 av0 = *reinterpret_cast<const int4*>(A + aBase + k0);
        int4 av1 = *reinterpret_cast<const int4*>(A + aBase + (size_t)64 * K + k0);
        int4 bv0 = load8(W, bBase + k0, wf);
        int4 bv1 = load8(W, bBase + (size_t)64 * K + k0, wf);
        *reinterpret_cast<int4*>(sA + srow * LDW + scol)        = av0;
        *reinterpret_cast<int4*>(sA + (srow + 64) * LDW + scol) = av1;
        *reinterpret_cast<int4*>(sB + srow * LDW + scol)        = bv0;
        *reinterpret_cast<int4*>(sB + (srow + 64) * LDW + scol) = bv1;
        __syncthreads();
        bf16x8 af[4], bfv[4];
        #pragma unroll
        for (int i = 0; i < 4; ++i)
            af[i] = *reinterpret_cast<const bf16x8*>(sA + (wrow + i * 16 + lr) * LDW + quad * 8);
        #pragma unroll
        for (int j = 0; j < 4; ++j)
            bfv[j] = *reinterpret_cast<const bf16x8*>(sB + (wcol + j * 16 + lr) * LDW + quad * 8);
        #pragma unroll
        for (int i = 0; i < 4; ++i)
            #pragma unroll
            for (int j = 0; j < 4; ++j)
                acc[i][j] = __builtin_amdgcn_mfma_f32_16x16x32_bf16(af[i], bfv[j], acc[i][j], 0, 0, 0);
        __syncthreads();
    }

    #pragma unroll
    for (int i = 0; i < 4; ++i) {
        #pragma unroll
        for (int j = 0; j < 4; ++j) {
            #pragma unroll
            for (int r = 0; r < 4; ++r) {
                int row = m0 + wrow + i * 16 + quad * 4 + r;
                int col = n0 + wcol + j * 16 + lr;
                float val = acc[i][j][r];
                if (GELU) {
                    float x3 = val * val * val;
                    val = 0.5f * val * (1.f + tanhf(0.7978845608028654f * (val + 0.044715f * x3)));
                }
                size_t idx = (size_t)row * N + col;
                if (RESID) {
                    float rv = rf ? ((const float*)R)[idx + rOff]
                                  : b2f(((const unsigned short*)R)[idx + rOff]);
                    val += rv;
                }
                if (OUTF32) ((float*)C)[idx] = val;
                else        ((unsigned short*)C)[idx] = f2b(val);
            }
        }
    }
}

// ---------------- MFMA flash attention -------------------------------------
// grid.x = nb*NHEADS*16. Block: one (b,h) head x 64-query tile, 4 waves x 16q.
// Layouts (verified by the passing GEMM): A[m=lane&15][k=quad*8+j],
// B[n=lane&15][k=quad*8+j], C/D row=quad*4+r col=lane&15.
__global__ __launch_bounds__(256) void fattn_kernel(
        const unsigned short* __restrict__ q,
        const unsigned short* __restrict__ k,
        const unsigned short* __restrict__ v,
        unsigned short* __restrict__ ctx) {
    constexpr int VTP = 72;   // padded row length (halves); keeps 16B alignment
    __shared__ unsigned short Vt[64 * VTP];        // V^T tile: Vt[d][key]
    __shared__ unsigned short Pl[4][16 * VTP];     // per-wave P: Pl[w][q][key]
    const int tid  = threadIdx.x;
    const int wave = tid >> 6, lane = tid & 63;
    const int quad = lane >> 4, lr = lane & 15;
    const int head = blockIdx.x >> 4;
    const int qt   = blockIdx.x & 15;
    const int bb   = head / NHEADS, hd = head % NHEADS;
    const size_t seqbase = (size_t)bb * SEQ;
    const int q0 = qt * 64 + wave * 16;

    // Q fragment (A-operand), two 32-wide d-halves, loaded once
    bf16x8 aQ0, aQ1;
    {
        const unsigned short* qp = q + ((seqbase + q0 + lr) * EMB + hd * HDIM + quad * 8);
        aQ0 = *reinterpret_cast<const bf16x8*>(qp);
        aQ1 = *reinterpret_cast<const bf16x8*>(qp + 32);
    }

    f32x4 O[4];
    #pragma unroll
    for (int i = 0; i < 4; ++i) O[i] = (f32x4){0.f, 0.f, 0.f, 0.f};
    float mrow[4], lrow[4];
    #pragma unroll
    for (int r = 0; r < 4; ++r) { mrow[r] = -__builtin_inff(); lrow[r] = 0.f; }

    for (int kt = 0; kt <= qt; ++kt) {
        // ---- stage V^T tile (coalesced read, transposed LDS write) ----
        {
            const int vrow = tid >> 2;          // key within tile, 0..63
            const int vcol = (tid & 3) * 16;    // d base, 0/16/32/48
            const unsigned short* vp = v + ((seqbase + kt * 64 + vrow) * EMB + hd * HDIM + vcol);
            union { int4 v4; unsigned short u[8]; } ua, ub;
            ua.v4 = *reinterpret_cast<const int4*>(vp);
            ub.v4 = *reinterpret_cast<const int4*>(vp + 8);
            #pragma unroll
            for (int e = 0; e < 8; ++e) Vt[(vcol + e) * VTP + vrow]     = ua.u[e];
            #pragma unroll
            for (int e = 0; e < 8; ++e) Vt[(vcol + 8 + e) * VTP + vrow] = ub.u[e];
        }
        __syncthreads();

        // ---- S = Q K^T for 4 key-subtiles (B direct from global) ----
        f32x4 S[4];
        #pragma unroll
        for (int sub = 0; sub < 4; ++sub) {
            const unsigned short* kp = k + ((seqbase + kt * 64 + sub * 16 + lr) * EMB + hd * HDIM + quad * 8);
            bf16x8 b0 = *reinterpret_cast<const bf16x8*>(kp);
            bf16x8 b1 = *reinterpret_cast<const bf16x8*>(kp + 32);
            f32x4 accS = (f32x4){0.f, 0.f, 0.f, 0.f};
            accS = __builtin_amdgcn_mfma_f32_16x16x32_bf16(aQ0, b0, accS, 0, 0, 0);
            accS = __builtin_amdgcn_mfma_f32_16x16x32_bf16(aQ1, b1, accS, 0, 0, 0);
            S[sub] = accS;
        }
        // ---- scale + causal mask (diagonal tile only) ----
        const bool diag = (kt == qt);
        #pragma unroll
        for (int sub = 0; sub < 4; ++sub) {
            const int kg = kt * 64 + sub * 16 + lr;
            #pragma unroll
            for (int r = 0; r < 4; ++r) {
                float s = S[sub][r] * 0.125f;
                if (diag && kg > q0 + quad * 4 + r) s = -__builtin_inff();
                S[sub][r] = s;
            }
        }
        // ---- online softmax (rows = quad*4+r; cols across lane&15) ----
        float mnew[4], alpha[4];
        #pragma unroll
        for (int r = 0; r < 4; ++r) {
            float mx = fmaxf(fmaxf(S[0][r], S[1][r]), fmaxf(S[2][r], S[3][r]));
            #pragma unroll
            for (int m = 1; m < 16; m <<= 1) mx = fmaxf(mx, __shfl_xor(mx, m));
            mnew[r]  = fmaxf(mrow[r], mx);
            alpha[r] = __expf(mrow[r] - mnew[r]);
            mrow[r]  = mnew[r];
        }
        float rsum[4] = {0.f, 0.f, 0.f, 0.f};
        #pragma unroll
        for (int sub = 0; sub < 4; ++sub)
            #pragma unroll
            for (int r = 0; r < 4; ++r) {
                float p = __expf(S[sub][r] - mnew[r]);
                S[sub][r] = p;
                rsum[r] += p;
            }
        #pragma unroll
        for (int r = 0; r < 4; ++r) {
            float rs = rsum[r];
            #pragma unroll
            for (int m = 1; m < 16; m <<= 1) rs += __shfl_xor(rs, m);
            lrow[r] = lrow[r] * alpha[r] + rs;
        }
        #pragma unroll
        for (int ds = 0; ds < 4; ++ds)
            #pragma unroll
            for (int r = 0; r < 4; ++r)
                O[ds][r] *= alpha[r];

        // ---- P: C-layout regs -> LDS -> A-layout frags ----
        unsigned short* Pw = Pl[wave];
        #pragma unroll
        for (int sub = 0; sub < 4; ++sub)
            #pragma unroll
            for (int r = 0; r < 4; ++r)
                Pw[(quad * 4 + r) * VTP + sub * 16 + lr] = f2b(S[sub][r]);
        __syncthreads();   // also covers wave-internal P write->read ordering

        #pragma unroll
        for (int c = 0; c < 2; ++c) {
            bf16x8 aP = *reinterpret_cast<const bf16x8*>(&Pw[lr * VTP + c * 32 + quad * 8]);
            #pragma unroll
            for (int ds = 0; ds < 4; ++ds) {
                bf16x8 bV = *reinterpret_cast<const bf16x8*>(&Vt[(ds * 16 + lr) * VTP + c * 32 + quad * 8]);
                O[ds] = __builtin_amdgcn_mfma_f32_16x16x32_bf16(aP, bV, O[ds], 0, 0, 0);
            }
        }
        __syncthreads();   // before next tile overwrites Vt
    }

    // ---- epilogue: O /= l, store bf16 ----
    #pragma unroll
    for (int r = 0; r < 4; ++r) {
        const float rinv = 1.f / lrow[r];
        const int qg = q0 + quad * 4 + r;
        unsigned short* crow = ctx + (seqbase + qg) * EMB + hd * HDIM;
        #pragma unroll
        for (int ds = 0; ds < 4; ++ds)
            crow[ds * 16 + lr] = f2b(O[ds][r] * rinv);
    }
}

// ---------------------------------------------------------------------------
extern "C" void kernel_launch(void* const* d_in, const int* in_sizes, int n_in,
                              void* d_out, int out_size, void* d_ws, size_t ws_size,
                              hipStream_t stream) {
    const void* x  = d_in[0];
    const void* wq = d_in[1], *wk = d_in[2], *wv = d_in[3], *wo = d_in[4];
    const void* w1 = d_in[5], *w2 = d_in[6];
    const void* g1 = d_in[7], *s1 = d_in[8], *g2 = d_in[9], *s2 = d_in[10];
    char* ws = (char*)d_ws;
    dim3 blk(256);

    int* F = (int*)ws;
    for (int i = 0; i < 11; ++i)
        detect_kernel<<<1, blk, 0, stream>>>((const unsigned short*)d_in[i], in_sizes[i], F + i);

    const size_t SZE = (size_t)MROWS * EMB;   // 6,291,456 elems
    const size_t SZB = SZE * 2;               // 12,582,912 bytes (bf16 buf)
    unsigned short* base = (unsigned short*)(ws + 256);
    dim3 g768(MROWS / 128, EMB / 128);

    if (ws_size >= 256 + 7 * SZB) {
        // ---- tier A: full-width; d_out untouched until final fp32 store ----
        unsigned short* B0 = base;            // h -> ctx
        unsigned short* B1 = B0 + SZE;        // q -> x2
        unsigned short* B2 = B1 + SZE;        // k -> h2
        unsigned short* Bg = B2 + SZE;        // v, then g [4*SZE]
        dim3 g3072(MROWS / 128, FFN / 128);
        ln_kernel<<<MROWS / 4, blk, 0, stream>>>(x, F+0, g1, F+7, s1, F+8, B0);
        gemm_bt<false, false, false><<<g768, blk, 0, stream>>>(B0, wq, F+1, nullptr, nullptr, 0, B1, MROWS, EMB, EMB);
        gemm_bt<false, false, false><<<g768, blk, 0, stream>>>(B0, wk, F+2, nullptr, nullptr, 0, B2, MROWS, EMB, EMB);
        gemm_bt<false, false, false><<<g768, blk, 0, stream>>>(B0, wv, F+3, nullptr, nullptr, 0, Bg, MROWS, EMB, EMB);
        fattn_kernel<<<BATCH * NHEADS * 16, blk, 0, stream>>>(B1, B2, Bg, B0);
        gemm_bt<false, true, false><<<g768, blk, 0, stream>>>(B0, wo, F+4, x, F+0, 0, B1, MROWS, EMB, EMB);
        ln_kernel<<<MROWS / 4, blk, 0, stream>>>(B1, nullptr, g2, F+9, s2, F+10, B2);
        gemm_bt<true, false, false><<<g3072, blk, 0, stream>>>(B2, w1, F+5, nullptr, nullptr, 0, Bg, MROWS, FFN, EMB);
        gemm_bt<false, true, true><<<g768, blk, 0, stream>>>(Bg, w2, F+6, B1, nullptr, 0, d_out, MROWS, EMB, FFN);
    } else if (ws_size >= 256 + 4 * SZB) {
        // ---- tier M: full attention, FFN in 2048-row chunks ----
        unsigned short* B0 = base;
        unsigned short* B1 = B0 + SZE;
        unsigned short* B2 = B1 + SZE;
        unsigned short* B3 = B2 + SZE;
        ln_kernel<<<MROWS / 4, blk, 0, stream>>>(x, F+0, g1, F+7, s1, F+8, B0);
        gemm_bt<false, false, false><<<g768, blk, 0, stream>>>(B0, wq, F+1, nullptr, nullptr, 0, B1, MROWS, EMB, EMB);
        gemm_bt<false, false, false><<<g768, blk, 0, stream>>>(B0, wk, F+2, nullptr, nullptr, 0, B2, MROWS, EMB, EMB);
        gemm_bt<false, false, false><<<g768, blk, 0, stream>>>(B0, wv, F+3, nullptr, nullptr, 0, B3, MROWS, EMB, EMB);
        fattn_kernel<<<BATCH * NHEADS * 16, blk, 0, stream>>>(B1, B2, B3, B0);
        gemm_bt<false, true, false><<<g768, blk, 0, stream>>>(B0, wo, F+4, x, F+0, 0, B1, MROWS, EMB, EMB);
        ln_kernel<<<MROWS / 4, blk, 0, stream>>>(B1, nullptr, g2, F+9, s2, F+10, B2);
        dim3 c3072(2048 / 128, FFN / 128), c768(2048 / 128, EMB / 128);
        for (int c = 0; c < 4; ++c) {
            const size_t r0 = (size_t)c * 2048;
            gemm_bt<true, false, false><<<c3072, blk, 0, stream>>>(B2 + r0 * EMB, w1, F+5, nullptr, nullptr, 0, B3, 2048, FFN, EMB);
            gemm_bt<false, true, true><<<c768, blk, 0, stream>>>(B3, w2, F+6, B1 + r0 * EMB, nullptr, 0, (float*)d_out + r0 * EMB, 2048, EMB, FFN);
        }
    } else {
        // ---- tier B: d_out (fp32, 25.17 MB) stages bf16 h (lower) + x2 (upper) ----
        unsigned short* hlow = (unsigned short*)d_out;
        unsigned short* x2up = (unsigned short*)d_out + SZE;
        unsigned short* wsQ = base;
        unsigned short* wsK = wsQ + (size_t)1024 * EMB;
        unsigned short* wsV = wsK + (size_t)1024 * EMB;
        unsigned short* wsC = wsV + (size_t)1024 * EMB;
        ln_kernel<<<MROWS / 4, blk, 0, stream>>>(x, F+0, g1, F+7, s1, F+8, hlow);
        dim3 q768(1024 / 128, EMB / 128);
        for (int grp = 0; grp < BATCH; ++grp) {
            const size_t r0 = (size_t)grp * 1024;
            gemm_bt<false, false, false><<<q768, blk, 0, stream>>>(hlow + r0 * EMB, wq, F+1, nullptr, nullptr, 0, wsQ, 1024, EMB, EMB);
            gemm_bt<false, false, false><<<q768, blk, 0, stream>>>(hlow + r0 * EMB, wk, F+2, nullptr, nullptr, 0, wsK, 1024, EMB, EMB);
            gemm_bt<false, false, false><<<q768, blk, 0, stream>>>(hlow + r0 * EMB, wv, F+3, nullptr, nullptr, 0, wsV, 1024, EMB, EMB);
            fattn_kernel<<<1 * NHEADS * 16, blk, 0, stream>>>(wsQ, wsK, wsV, wsC);
            gemm_bt<false, true, false><<<q768, blk, 0, stream>>>(wsC, wo, F+4, x, F+0, r0 * EMB, x2up + r0 * EMB, 1024, EMB, EMB);
        }
        unsigned short* xb = base;
        unsigned short* h2 = xb + (size_t)1024 * EMB;
        unsigned short* gb = h2 + (size_t)1024 * EMB;
        dim3 f3072(1024 / 128, FFN / 128), f768(1024 / 128, EMB / 128);
        for (int c = 0; c < BATCH; ++c) {
            const size_t r0 = (size_t)c * 1024;
            hipMemcpyAsync(xb, x2up + r0 * EMB, (size_t)1024 * EMB * 2,
                           hipMemcpyDeviceToDevice, stream);
            ln_kernel<<<1024 / 4, blk, 0, stream>>>(xb, nullptr, g2, F+9, s2, F+10, h2);
            gemm_bt<true, false, false><<<f3072, blk, 0, stream>>>(h2, w1, F+5, nullptr, nullptr, 0, gb, 1024, FFN, EMB);
            gemm_bt<false, true, true><<<f768, blk, 0, stream>>>(gb, w2, F+6, xb, nullptr, 0, (float*)d_out + r0 * EMB, 1024, EMB, FFN);
        }
    }
}

// Round 9
// 592.999 us; speedup vs baseline: 4.3561x; 1.3048x over previous
//
#include <hip/hip_runtime.h>
#include <hip/hip_bf16.h>
#include <cstdint>

#define EMB    768
#define NHEADS 12
#define HDIM   64
#define SEQ    1024
#define BATCH  8
#define MROWS  (BATCH*SEQ)   /* 8192 */
#define FFN    3072

typedef __bf16 bf16_t;
typedef bf16_t bf16x8 __attribute__((ext_vector_type(8)));
typedef float  f32x4  __attribute__((ext_vector_type(4)));

__device__ __forceinline__ float b2f(unsigned short u) {
    union { unsigned int i; float f; } t; t.i = ((unsigned int)u) << 16; return t.f;
}
__device__ __forceinline__ unsigned short f2b(float f) {
    union { float f; unsigned int i; } t; t.f = f;
    unsigned int lsb = (t.i >> 16) & 1u;
    t.i += 0x7fffu + lsb;
    return (unsigned short)(t.i >> 16);
}

// async global->LDS, 16 B per lane; LDS dest = wave-uniform base + lane*16
#if defined(__has_builtin)
#if __has_builtin(__builtin_amdgcn_global_load_lds)
#define HAS_GLL 1
#endif
#endif
#ifndef HAS_GLL
#define HAS_GLL 0
#endif

__device__ __forceinline__ void gll16(const unsigned short* g, unsigned short* lds_wave_base) {
#if HAS_GLL
    __builtin_amdgcn_global_load_lds(
        (const __attribute__((address_space(1))) unsigned int*)g,
        (__attribute__((address_space(3))) unsigned int*)lds_wave_base, 16, 0, 0);
#endif
}

// load 8 consecutive logical elements as 8 bf16 halves (packed int4)
__device__ __forceinline__ int4 load8(const void* src, size_t eoff, bool f32) {
    if (f32) {
        const float4* p = reinterpret_cast<const float4*>((const float*)src + eoff);
        float4 a = p[0], b = p[1];
        union { unsigned short u[8]; int4 v; } r;
        r.u[0] = f2b(a.x); r.u[1] = f2b(a.y); r.u[2] = f2b(a.z); r.u[3] = f2b(a.w);
        r.u[4] = f2b(b.x); r.u[5] = f2b(b.y); r.u[6] = f2b(b.z); r.u[7] = f2b(b.w);
        return r.v;
    }
    return *reinterpret_cast<const int4*>((const unsigned short*)src + eoff);
}
__device__ __forceinline__ float4 load4f(const void* src, size_t eoff, bool f32) {
    if (f32) return *reinterpret_cast<const float4*>((const float*)src + eoff);
    ushort4 u = *reinterpret_cast<const ushort4*>((const unsigned short*)src + eoff);
    float4 r; r.x = b2f(u.x); r.y = b2f(u.y); r.z = b2f(u.z); r.w = b2f(u.w);
    return r;
}

// ---------------- dtype probe: one block per input ------------------------
struct DetectArgs { const unsigned short* p[11]; int n[11]; };

__global__ __launch_bounds__(256) void detect_all(DetectArgs a, int* __restrict__ flags) {
    __shared__ int cnt;
    if (threadIdx.x == 0) cnt = 0;
    __syncthreads();
    const unsigned short* src = a.p[blockIdx.x];
    int npairs = a.n[blockIdx.x] / 2;
    if (npairs > 4096) npairs = 4096;
    int local = 0;
    for (int p = threadIdx.x; p < npairs; p += 256) {
        unsigned short u0 = src[2 * p], u1 = src[2 * p + 1];
        int e0 = (u0 >> 7) & 0xFF;
        bool insane0 = (e0 == 0xFF) || (u0 != 0 && (e0 < 96 || e0 > 159));
        bool zpat    = (u0 == 0 && u1 != 0);
        if (insane0 || zpat) ++local;
    }
    atomicAdd(&cnt, local);
    __syncthreads();
    if (threadIdx.x == 0) flags[blockIdx.x] = (cnt * 8 > npairs) ? 1 : 0;
}

// ---------------- adaptive convert: normalize to bf16 ---------------------
__global__ __launch_bounds__(256) void cvt_adapt(
        const void* __restrict__ src, unsigned short* __restrict__ dst,
        int n, const int* __restrict__ flag) {
    int i = blockIdx.x * 256 + threadIdx.x;   // one per 4 elems
    if (i * 4 >= n) return;
    if (*flag) {
        float4 f = reinterpret_cast<const float4*>(src)[i];
        ushort4 o;
        o.x = f2b(f.x); o.y = f2b(f.y); o.z = f2b(f.z); o.w = f2b(f.w);
        reinterpret_cast<ushort4*>(dst)[i] = o;
    } else {
        reinterpret_cast<ushort4*>(dst)[i] = reinterpret_cast<const ushort4*>(src)[i];
    }
}

// ---------------- LayerNorm: one wave per row; bf16 out -------------------
__global__ __launch_bounds__(256) void ln_kernel(
        const void* __restrict__ x,     const int* __restrict__ fx,
        const void* __restrict__ scale, const int* __restrict__ fsc,
        const void* __restrict__ shift, const int* __restrict__ fsh,
        unsigned short* __restrict__ out) {
    const bool xf = fx && *fx, scf = fsc && *fsc, shf = fsh && *fsh;
    int wave = threadIdx.x >> 6;
    int lane = threadIdx.x & 63;
    int row  = blockIdx.x * 4 + wave;
    const size_t rbase = (size_t)row * EMB;
    float v[12];
    float s = 0.f, s2 = 0.f;
    #pragma unroll
    for (int i = 0; i < 3; ++i) {
        float4 a = load4f(x, rbase + i * 256 + lane * 4, xf);
        v[i*4+0] = a.x; v[i*4+1] = a.y; v[i*4+2] = a.z; v[i*4+3] = a.w;
        s  += a.x + a.y + a.z + a.w;
        s2 += a.x*a.x + a.y*a.y + a.z*a.z + a.w*a.w;
    }
    #pragma unroll
    for (int off = 1; off < 64; off <<= 1) {
        s  += __shfl_xor(s,  off);
        s2 += __shfl_xor(s2, off);
    }
    float mean = s * (1.f / EMB);
    float var  = fmaxf(s2 * (1.f / EMB) - mean * mean, 0.f);
    float rstd = rsqrtf(var + 1e-5f);
    unsigned short* orow = out + rbase;
    #pragma unroll
    for (int i = 0; i < 3; ++i) {
        float4 sc = load4f(scale, i * 256 + lane * 4, scf);
        float4 sh = load4f(shift, i * 256 + lane * 4, shf);
        ushort4 o;
        o.x = f2b((v[i*4+0] - mean) * rstd * sc.x + sh.x);
        o.y = f2b((v[i*4+1] - mean) * rstd * sc.y + sh.y);
        o.z = f2b((v[i*4+2] - mean) * rstd * sc.z + sh.z);
        o.w = f2b((v[i*4+3] - mean) * rstd * sc.w + sh.w);
        *reinterpret_cast<ushort4*>(orow + i * 256 + lane * 4) = o;
    }
}

// ---------------- gemm_lds: pure-bf16 GEMM with async LDS staging ---------
// C[M,N] = A[M,K] @ W[N,K]^T. 128x128 tile, BK=32, UNPADDED 128x32 LDS tiles
// (lane-linear layout required by global_load_lds). m97-style structure.
template<bool GELU, bool RESID, bool OUTF32>
__global__ __launch_bounds__(256) void gemm_lds(
        const unsigned short* __restrict__ A,
        const unsigned short* __restrict__ W,
        const void* R, const int* __restrict__ fR, size_t rOff,
        void* C, int M, int N, int K) {
    constexpr int BK = 32;
    __shared__ __align__(16) unsigned short sA[128 * BK];
    __shared__ __align__(16) unsigned short sB[128 * BK];
    const int m0 = blockIdx.x * 128, n0 = blockIdx.y * 128;
    const int t = threadIdx.x, wave = t >> 6, lane = t & 63;
    const int wrow = (wave >> 1) * 64, wcol = (wave & 1) * 64;
    const int quad = lane >> 4, lr = lane & 15;
    const int r0 = t >> 2;              // row within 64-row chunk
    const int c0 = (t & 3) * 8;         // col halves
    const bool rf = fR && *fR;

    f32x4 acc[4][4];
    #pragma unroll
    for (int i = 0; i < 4; ++i)
        #pragma unroll
        for (int j = 0; j < 4; ++j)
            acc[i][j] = (f32x4){0.f, 0.f, 0.f, 0.f};

    const unsigned short* gA0 = A + (size_t)(m0 + r0) * K + c0;
    const unsigned short* gA1 = A + (size_t)(m0 + 64 + r0) * K + c0;
    const unsigned short* gB0 = W + (size_t)(n0 + r0) * K + c0;
    const unsigned short* gB1 = W + (size_t)(n0 + 64 + r0) * K + c0;
    // wave-uniform LDS bases (bytes: wave*1024 within each 4096-B chunk)
    unsigned short* lA0 = sA + wave * 512;
    unsigned short* lA1 = sA + 2048 + wave * 512;
    unsigned short* lB0 = sB + wave * 512;
    unsigned short* lB1 = sB + 2048 + wave * 512;

    for (int k0 = 0; k0 < K; k0 += BK) {
#if HAS_GLL
        gll16(gA0 + k0, lA0);
        gll16(gA1 + k0, lA1);
        gll16(gB0 + k0, lB0);
        gll16(gB1 + k0, lB1);
#else
        // fallback: VGPR round-trip to the same lane-linear layout (t*16 B)
        *reinterpret_cast<int4*>(sA + t * 8)        = *reinterpret_cast<const int4*>(gA0 + k0);
        *reinterpret_cast<int4*>(sA + 2048 + t * 8) = *reinterpret_cast<const int4*>(gA1 + k0);
        *reinterpret_cast<int4*>(sB + t * 8)        = *reinterpret_cast<const int4*>(gB0 + k0);
        *reinterpret_cast<int4*>(sB + 2048 + t * 8) = *reinterpret_cast<const int4*>(gB1 + k0);
#endif
        __syncthreads();
        bf16x8 af[4], bfv[4];
        #pragma unroll
        for (int i = 0; i < 4; ++i)
            af[i] = *reinterpret_cast<const bf16x8*>(sA + (wrow + i * 16 + lr) * BK + quad * 8);
        #pragma unroll
        for (int j = 0; j < 4; ++j)
            bfv[j] = *reinterpret_cast<const bf16x8*>(sB + (wcol + j * 16 + lr) * BK + quad * 8);
        #pragma unroll
        for (int i = 0; i < 4; ++i)
            #pragma unroll
            for (int j = 0; j < 4; ++j)
                acc[i][j] = __builtin_amdgcn_mfma_f32_16x16x32_bf16(af[i], bfv[j], acc[i][j], 0, 0, 0);
        __syncthreads();
    }

    // epilogue: C/D layout row = quad*4 + r, col = lane&15
    #pragma unroll
    for (int i = 0; i < 4; ++i) {
        #pragma unroll
        for (int j = 0; j < 4; ++j) {
            #pragma unroll
            for (int r = 0; r < 4; ++r) {
                int row = m0 + wrow + i * 16 + quad * 4 + r;
                int col = n0 + wcol + j * 16 + lr;
                float val = acc[i][j][r];
                if (GELU) {
                    float x3 = val * val * val;
                    val = 0.5f * val * (1.f + tanhf(0.7978845608028654f * (val + 0.044715f * x3)));
                }
                size_t idx = (size_t)row * N + col;
                if (RESID) {
                    float rv = rf ? ((const float*)R)[idx + rOff]
                                  : b2f(((const unsigned short*)R)[idx + rOff]);
                    val += rv;
                }
                if (OUTF32) ((float*)C)[idx] = val;
                else        ((unsigned short*)C)[idx] = f2b(val);
            }
        }
    }
}

// ---------------- legacy flagged GEMM (fallback tiers only) ---------------
template<bool GELU, bool RESID, bool OUTF32>
__global__ __launch_bounds__(256) void gemm_bt(
        const unsigned short* __restrict__ A,
        const void* __restrict__ W, const int* __restrict__ fW,
        const void* R, const int* __restrict__ fR, size_t rOff,
        void* C,
        int M, int N, int K) {
    const bool wf = fW && *fW;
    const bool rf = fR && *fR;
    constexpr int BK = 32, PAD = 8, LDW = BK + PAD;
    __shared__ __align__(16) unsigned short sA[128 * LDW];
    __shared__ __align__(16) unsigned short sB[128 * LDW];
    const int m0 = blockIdx.x * 128;
    const int n0 = blockIdx.y * 128;
    const int t    = threadIdx.x;
    const int wave = t >> 6, lane = t & 63;
    const int wrow = (wave >> 1) * 64, wcol = (wave & 1) * 64;
    const int quad = lane >> 4, lr = lane & 15;
    const int srow = t >> 2, scol = (t & 3) * 8;

    f32x4 acc[4][4];
    #pragma unroll
    for (int i = 0; i < 4; ++i)
        #pragma unroll
        for (int j = 0; j < 4; ++j)
            acc[i][j] = (f32x4){0.f, 0.f, 0.f, 0.f};

    const size_t aBase = (size_t)(m0 + srow) * K + scol;
    const size_t bBase = (size_t)(n0 + srow) * K + scol;

    for (int k0 = 0; k0 < K; k0 += BK) {
        int4 av0 = *reinterpret_cast<const int4*>(A + aBase + k0);
        int4 av1 = *reinterpret_cast<const int4*>(A + aBase + (size_t)64 * K + k0);
        int4 bv0 = load8(W, bBase + k0, wf);
        int4 bv1 = load8(W, bBase + (size_t)64 * K + k0, wf);
        *reinterpret_cast<int4*>(sA + srow * LDW + scol)        = av0;
        *reinterpret_cast<int4*>(sA + (srow + 64) * LDW + scol) = av1;
        *reinterpret_cast<int4*>(sB + srow * LDW + scol)        = bv0;
        *reinterpret_cast<int4*>(sB + (srow + 64) * LDW + scol) = bv1;
        __syncthreads();
        bf16x8 af[4], bfv[4];
        #pragma unroll
        for (int i = 0; i < 4; ++i)
            af[i] = *reinterpret_cast<const bf16x8*>(sA + (wrow + i * 16 + lr) * LDW + quad * 8);
        #pragma unroll
        for (int j = 0; j < 4; ++j)
            bfv[j] = *reinterpret_cast<const bf16x8*>(sB + (wcol + j * 16 + lr) * LDW + quad * 8);
        #pragma unroll
        for (int i = 0; i < 4; ++i)
            #pragma unroll
            for (int j = 0; j < 4; ++j)
                acc[i][j] = __builtin_amdgcn_mfma_f32_16x16x32_bf16(af[i], bfv[j], acc[i][j], 0, 0, 0);
        __syncthreads();
    }

    #pragma unroll
    for (int i = 0; i < 4; ++i) {
        #pragma unroll
        for (int j = 0; j < 4; ++j) {
            #pragma unroll
            for (int r = 0; r < 4; ++r) {
                int row = m0 + wrow + i * 16 + quad * 4 + r;
                int col = n0 + wcol + j * 16 + lr;
                float val = acc[i][j][r];
                if (GELU) {
                    float x3 = val * val * val;
                    val = 0.5f * val * (1.f + tanhf(0.7978845608028654f * (val + 0.044715f * x3)));
                }
                size_t idx = (size_t)row * N + col;
                if (RESID) {
                    float rv = rf ? ((const float*)R)[idx + rOff]
                                  : b2f(((const unsigned short*)R)[idx + rOff]);
                    val += rv;
                }
                if (OUTF32) ((float*)C)[idx] = val;
                else        ((unsigned short*)C)[idx] = f2b(val);
            }
        }
    }
}

// ---------------- MFMA flash attention (r8, verified) ---------------------
__global__ __launch_bounds__(256) void fattn_kernel(
        const unsigned short* __restrict__ q,
        const unsigned short* __restrict__ k,
        const unsigned short* __restrict__ v,
        unsigned short* __restrict__ ctx) {
    constexpr int VTP = 72;
    __shared__ unsigned short Vt[64 * VTP];
    __shared__ unsigned short Pl[4][16 * VTP];
    const int tid  = threadIdx.x;
    const int wave = tid >> 6, lane = tid & 63;
    const int quad = lane >> 4, lr = lane & 15;
    const int head = blockIdx.x >> 4;
    const int qt   = blockIdx.x & 15;
    const int bb   = head / NHEADS, hd = head % NHEADS;
    const size_t seqbase = (size_t)bb * SEQ;
    const int q0 = qt * 64 + wave * 16;

    bf16x8 aQ0, aQ1;
    {
        const unsigned short* qp = q + ((seqbase + q0 + lr) * EMB + hd * HDIM + quad * 8);
        aQ0 = *reinterpret_cast<const bf16x8*>(qp);
        aQ1 = *reinterpret_cast<const bf16x8*>(qp + 32);
    }

    f32x4 O[4];
    #pragma unroll
    for (int i = 0; i < 4; ++i) O[i] = (f32x4){0.f, 0.f, 0.f, 0.f};
    float mrow[4], lrow[4];
    #pragma unroll
    for (int r = 0; r < 4; ++r) { mrow[r] = -__builtin_inff(); lrow[r] = 0.f; }

    for (int kt = 0; kt <= qt; ++kt) {
        {
            const int vrow = tid >> 2;
            const int vcol = (tid & 3) * 16;
            const unsigned short* vp = v + ((seqbase + kt * 64 + vrow) * EMB + hd * HDIM + vcol);
            union { int4 v4; unsigned short u[8]; } ua, ub;
            ua.v4 = *reinterpret_cast<const int4*>(vp);
            ub.v4 = *reinterpret_cast<const int4*>(vp + 8);
            #pragma unroll
            for (int e = 0; e < 8; ++e) Vt[(vcol + e) * VTP + vrow]     = ua.u[e];
            #pragma unroll
            for (int e = 0; e < 8; ++e) Vt[(vcol + 8 + e) * VTP + vrow] = ub.u[e];
        }
        __syncthreads();

        f32x4 S[4];
        #pragma unroll
        for (int sub = 0; sub < 4; ++sub) {
            const unsigned short* kp = k + ((seqbase + kt * 64 + sub * 16 + lr) * EMB + hd * HDIM + quad * 8);
            bf16x8 b0 = *reinterpret_cast<const bf16x8*>(kp);
            bf16x8 b1 = *reinterpret_cast<const bf16x8*>(kp + 32);
            f32x4 accS = (f32x4){0.f, 0.f, 0.f, 0.f};
            accS = __builtin_amdgcn_mfma_f32_16x16x32_bf16(aQ0, b0, accS, 0, 0, 0);
            accS = __builtin_amdgcn_mfma_f32_16x16x32_bf16(aQ1, b1, accS, 0, 0, 0);
            S[sub] = accS;
        }
        const bool diag = (kt == qt);
        #pragma unroll
        for (int sub = 0; sub < 4; ++sub) {
            const int kg = kt * 64 + sub * 16 + lr;
            #pragma unroll
            for (int r = 0; r < 4; ++r) {
                float s = S[sub][r] * 0.125f;
                if (diag && kg > q0 + quad * 4 + r) s = -__builtin_inff();
                S[sub][r] = s;
            }
        }
        float mnew[4], alpha[4];
        #pragma unroll
        for (int r = 0; r < 4; ++r) {
            float mx = fmaxf(fmaxf(S[0][r], S[1][r]), fmaxf(S[2][r], S[3][r]));
            #pragma unroll
            for (int m = 1; m < 16; m <<= 1) mx = fmaxf(mx, __shfl_xor(mx, m));
            mnew[r]  = fmaxf(mrow[r], mx);
            alpha[r] = __expf(mrow[r] - mnew[r]);
            mrow[r]  = mnew[r];
        }
        float rsum[4] = {0.f, 0.f, 0.f, 0.f};
        #pragma unroll
        for (int sub = 0; sub < 4; ++sub)
            #pragma unroll
            for (int r = 0; r < 4; ++r) {
                float p = __expf(S[sub][r] - mnew[r]);
                S[sub][r] = p;
                rsum[r] += p;
            }
        #pragma unroll
        for (int r = 0; r < 4; ++r) {
            float rs = rsum[r];
            #pragma unroll
            for (int m = 1; m < 16; m <<= 1) rs += __shfl_xor(rs, m);
            lrow[r] = lrow[r] * alpha[r] + rs;
        }
        #pragma unroll
        for (int ds = 0; ds < 4; ++ds)
            #pragma unroll
            for (int r = 0; r < 4; ++r)
                O[ds][r] *= alpha[r];

        unsigned short* Pw = Pl[wave];
        #pragma unroll
        for (int sub = 0; sub < 4; ++sub)
            #pragma unroll
            for (int r = 0; r < 4; ++r)
                Pw[(quad * 4 + r) * VTP + sub * 16 + lr] = f2b(S[sub][r]);
        __syncthreads();

        #pragma unroll
        for (int c = 0; c < 2; ++c) {
            bf16x8 aP = *reinterpret_cast<const bf16x8*>(&Pw[lr * VTP + c * 32 + quad * 8]);
            #pragma unroll
            for (int ds = 0; ds < 4; ++ds) {
                bf16x8 bV = *reinterpret_cast<const bf16x8*>(&Vt[(ds * 16 + lr) * VTP + c * 32 + quad * 8]);
                O[ds] = __builtin_amdgcn_mfma_f32_16x16x32_bf16(aP, bV, O[ds], 0, 0, 0);
            }
        }
        __syncthreads();
    }

    #pragma unroll
    for (int r = 0; r < 4; ++r) {
        const float rinv = 1.f / lrow[r];
        const int qg = q0 + quad * 4 + r;
        unsigned short* crow = ctx + (seqbase + qg) * EMB + hd * HDIM;
        #pragma unroll
        for (int ds = 0; ds < 4; ++ds)
            crow[ds * 16 + lr] = f2b(O[ds][r] * rinv);
    }
}

// ---------------------------------------------------------------------------
extern "C" void kernel_launch(void* const* d_in, const int* in_sizes, int n_in,
                              void* d_out, int out_size, void* d_ws, size_t ws_size,
                              hipStream_t stream) {
    const void* x  = d_in[0];
    const void* wq = d_in[1], *wk = d_in[2], *wv = d_in[3], *wo = d_in[4];
    const void* w1 = d_in[5], *w2 = d_in[6];
    const void* g1 = d_in[7], *s1 = d_in[8], *g2 = d_in[9], *s2 = d_in[10];
    char* ws = (char*)d_ws;
    dim3 blk(256);

    int* F = (int*)ws;
    {
        DetectArgs da;
        for (int i = 0; i < 11; ++i) { da.p[i] = (const unsigned short*)d_in[i]; da.n[i] = in_sizes[i]; }
        detect_all<<<11, blk, 0, stream>>>(da, F);
    }

    const size_t SZE = (size_t)MROWS * EMB;   // 6,291,456 elems
    const size_t SZB = SZE * 2;               // 12,582,912 bytes
    unsigned short* base = (unsigned short*)(ws + 256);
    dim3 g768(MROWS / 128, EMB / 128);

    if (ws_size >= 256 + 7 * SZB) {
        // ---- optimized path (ws >= 88.3 MB proven by r8 profile; uses 77.1) ----
        const int W2 = 589824, W4 = 2359296;
        unsigned short* wqb = base;
        unsigned short* wkb = wqb + W2;
        unsigned short* wvb = wkb + W2;
        unsigned short* wob = wvb + W2;
        unsigned short* w1b = wob + W2;
        unsigned short* w2b = w1b + W4;
        unsigned short* B0  = w2b + W4;       // h -> ctx
        unsigned short* B1  = B0 + SZE;       // q -> x2
        unsigned short* B2  = B1 + SZE;       // k -> h2
        unsigned short* B3  = B2 + SZE;       // v -> g-chunk [2*SZE]

        cvt_adapt<<<W2 / 1024, blk, 0, stream>>>(wq, wqb, W2, F + 1);
        cvt_adapt<<<W2 / 1024, blk, 0, stream>>>(wk, wkb, W2, F + 2);
        cvt_adapt<<<W2 / 1024, blk, 0, stream>>>(wv, wvb, W2, F + 3);
        cvt_adapt<<<W2 / 1024, blk, 0, stream>>>(wo, wob, W2, F + 4);
        cvt_adapt<<<W4 / 1024, blk, 0, stream>>>(w1, w1b, W4, F + 5);
        cvt_adapt<<<W4 / 1024, blk, 0, stream>>>(w2, w2b, W4, F + 6);

        ln_kernel<<<MROWS / 4, blk, 0, stream>>>(x, F+0, g1, F+7, s1, F+8, B0);
        gemm_lds<false, false, false><<<g768, blk, 0, stream>>>(B0, wqb, nullptr, nullptr, 0, B1, MROWS, EMB, EMB);
        gemm_lds<false, false, false><<<g768, blk, 0, stream>>>(B0, wkb, nullptr, nullptr, 0, B2, MROWS, EMB, EMB);
        gemm_lds<false, false, false><<<g768, blk, 0, stream>>>(B0, wvb, nullptr, nullptr, 0, B3, MROWS, EMB, EMB);
        fattn_kernel<<<BATCH * NHEADS * 16, blk, 0, stream>>>(B1, B2, B3, B0);
        gemm_lds<false, true, false><<<g768, blk, 0, stream>>>(B0, wob, x, F+0, 0, B1, MROWS, EMB, EMB); // x2->B1
        ln_kernel<<<MROWS / 4, blk, 0, stream>>>(B1, nullptr, g2, F+9, s2, F+10, B2);                     // h2->B2
        dim3 c3072(4096 / 128, FFN / 128), c768(4096 / 128, EMB / 128);
        for (int c = 0; c < 2; ++c) {
            const size_t r0 = (size_t)c * 4096;
            gemm_lds<true, false, false><<<c3072, blk, 0, stream>>>(B2 + r0 * EMB, w1b, nullptr, nullptr, 0, B3, 4096, FFN, EMB);
            gemm_lds<false, true, true><<<c768, blk, 0, stream>>>(B3, w2b, B1 + r0 * EMB, nullptr, 0, (float*)d_out + r0 * EMB, 4096, EMB, FFN);
        }
    } else if (ws_size >= 256 + 4 * SZB) {
        // ---- fallback tier M (r8 code) ----
        unsigned short* B0 = base;
        unsigned short* B1 = B0 + SZE;
        unsigned short* B2 = B1 + SZE;
        unsigned short* B3 = B2 + SZE;
        ln_kernel<<<MROWS / 4, blk, 0, stream>>>(x, F+0, g1, F+7, s1, F+8, B0);
        gemm_bt<false, false, false><<<g768, blk, 0, stream>>>(B0, wq, F+1, nullptr, nullptr, 0, B1, MROWS, EMB, EMB);
        gemm_bt<false, false, false><<<g768, blk, 0, stream>>>(B0, wk, F+2, nullptr, nullptr, 0, B2, MROWS, EMB, EMB);
        gemm_bt<false, false, false><<<g768, blk, 0, stream>>>(B0, wv, F+3, nullptr, nullptr, 0, B3, MROWS, EMB, EMB);
        fattn_kernel<<<BATCH * NHEADS * 16, blk, 0, stream>>>(B1, B2, B3, B0);
        gemm_bt<false, true, false><<<g768, blk, 0, stream>>>(B0, wo, F+4, x, F+0, 0, B1, MROWS, EMB, EMB);
        ln_kernel<<<MROWS / 4, blk, 0, stream>>>(B1, nullptr, g2, F+9, s2, F+10, B2);
        dim3 c3072(2048 / 128, FFN / 128), c768(2048 / 128, EMB / 128);
        for (int c = 0; c < 4; ++c) {
            const size_t r0 = (size_t)c * 2048;
            gemm_bt<true, false, false><<<c3072, blk, 0, stream>>>(B2 + r0 * EMB, w1, F+5, nullptr, nullptr, 0, B3, 2048, FFN, EMB);
            gemm_bt<false, true, true><<<c768, blk, 0, stream>>>(B3, w2, F+6, B1 + r0 * EMB, nullptr, 0, (float*)d_out + r0 * EMB, 2048, EMB, FFN);
        }
    } else {
        // ---- fallback tier B (r8 code) ----
        unsigned short* hlow = (unsigned short*)d_out;
        unsigned short* x2up = (unsigned short*)d_out + SZE;
        unsigned short* wsQ = base;
        unsigned short* wsK = wsQ + (size_t)1024 * EMB;
        unsigned short* wsV = wsK + (size_t)1024 * EMB;
        unsigned short* wsC = wsV + (size_t)1024 * EMB;
        ln_kernel<<<MROWS / 4, blk, 0, stream>>>(x, F+0, g1, F+7, s1, F+8, hlow);
        dim3 q768(1024 / 128, EMB / 128);
        for (int grp = 0; grp < BATCH; ++grp) {
            const size_t r0 = (size_t)grp * 1024;
            gemm_bt<false, false, false><<<q768, blk, 0, stream>>>(hlow + r0 * EMB, wq, F+1, nullptr, nullptr, 0, wsQ, 1024, EMB, EMB);
            gemm_bt<false, false, false><<<q768, blk, 0, stream>>>(hlow + r0 * EMB, wk, F+2, nullptr, nullptr, 0, wsK, 1024, EMB, EMB);
            gemm_bt<false, false, false><<<q768, blk, 0, stream>>>(hlow + r0 * EMB, wv, F+3, nullptr, nullptr, 0, wsV, 1024, EMB, EMB);
            fattn_kernel<<<1 * NHEADS * 16, blk, 0, stream>>>(wsQ, wsK, wsV, wsC);
            gemm_bt<false, true, false><<<q768, blk, 0, stream>>>(wsC, wo, F+4, x, F+0, r0 * EMB, x2up + r0 * EMB, 1024, EMB, EMB);
        }
        unsigned short* xb = base;
        unsigned short* h2 = xb + (size_t)1024 * EMB;
        unsigned short* gb = h2 + (size_t)1024 * EMB;
        dim3 f3072(1024 / 128, FFN / 128), f768(1024 / 128, EMB / 128);
        for (int c = 0; c < BATCH; ++c) {
            const size_t r0 = (size_t)c * 1024;
            hipMemcpyAsync(xb, x2up + r0 * EMB, (size_t)1024 * EMB * 2,
                           hipMemcpyDeviceToDevice, stream);
            ln_kernel<<<1024 / 4, blk, 0, stream>>>(xb, nullptr, g2, F+9, s2, F+10, h2);
            gemm_bt<true, false, false><<<f3072, blk, 0, stream>>>(h2, w1, F+5, nullptr, nullptr, 0, gb, 1024, FFN, EMB);
            gemm_bt<false, true, true><<<f768, blk, 0, stream>>>(gb, w2, F+6, xb, nullptr, 0, (float*)d_out + r0 * EMB, 1024, EMB, FFN);
        }
    }
}

// Round 10
// 503.124 us; speedup vs baseline: 5.1343x; 1.1786x over previous
//
#include <hip/hip_runtime.h>
#include <hip/hip_bf16.h>
#include <cstdint>

#define EMB    768
#define NHEADS 12
#define HDIM   64
#define SEQ    1024
#define BATCH  8
#define MROWS  (BATCH*SEQ)   /* 8192 */
#define FFN    3072
#define W2E    (EMB*EMB)     /* 589824 */
#define W4E    (FFN*EMB)     /* 2359296 */

typedef __bf16 bf16_t;
typedef bf16_t bf16x8 __attribute__((ext_vector_type(8)));
typedef float  f32x4  __attribute__((ext_vector_type(4)));

__device__ __forceinline__ float b2f(unsigned short u) {
    union { unsigned int i; float f; } t; t.i = ((unsigned int)u) << 16; return t.f;
}
__device__ __forceinline__ unsigned short f2b(float f) {
    union { float f; unsigned int i; } t; t.f = f;
    unsigned int lsb = (t.i >> 16) & 1u;
    t.i += 0x7fffu + lsb;
    return (unsigned short)(t.i >> 16);
}

#if defined(__has_builtin)
#if __has_builtin(__builtin_amdgcn_global_load_lds)
#define HAS_GLL 1
#endif
#endif
#ifndef HAS_GLL
#define HAS_GLL 0
#endif

__device__ __forceinline__ void gll16(const unsigned short* g, unsigned short* lds_wave_base) {
#if HAS_GLL
    __builtin_amdgcn_global_load_lds(
        (const __attribute__((address_space(1))) unsigned int*)g,
        (__attribute__((address_space(3))) unsigned int*)lds_wave_base, 16, 0, 0);
#endif
}

__device__ __forceinline__ int4 load8(const void* src, size_t eoff, bool f32) {
    if (f32) {
        const float4* p = reinterpret_cast<const float4*>((const float*)src + eoff);
        float4 a = p[0], b = p[1];
        union { unsigned short u[8]; int4 v; } r;
        r.u[0] = f2b(a.x); r.u[1] = f2b(a.y); r.u[2] = f2b(a.z); r.u[3] = f2b(a.w);
        r.u[4] = f2b(b.x); r.u[5] = f2b(b.y); r.u[6] = f2b(b.z); r.u[7] = f2b(b.w);
        return r.v;
    }
    return *reinterpret_cast<const int4*>((const unsigned short*)src + eoff);
}
__device__ __forceinline__ float4 load4f(const void* src, size_t eoff, bool f32) {
    if (f32) return *reinterpret_cast<const float4*>((const float*)src + eoff);
    ushort4 u = *reinterpret_cast<const ushort4*>((const unsigned short*)src + eoff);
    float4 r; r.x = b2f(u.x); r.y = b2f(u.y); r.z = b2f(u.z); r.w = b2f(u.w);
    return r;
}

// ---------------- dtype probe: one block per input ------------------------
struct DetectArgs { const unsigned short* p[11]; int n[11]; };

__global__ __launch_bounds__(256) void detect_all(DetectArgs a, int* __restrict__ flags) {
    __shared__ int cnt;
    if (threadIdx.x == 0) cnt = 0;
    __syncthreads();
    const unsigned short* src = a.p[blockIdx.x];
    int npairs = a.n[blockIdx.x] / 2;
    if (npairs > 4096) npairs = 4096;
    int local = 0;
    for (int p = threadIdx.x; p < npairs; p += 256) {
        unsigned short u0 = src[2 * p], u1 = src[2 * p + 1];
        int e0 = (u0 >> 7) & 0xFF;
        bool insane0 = (e0 == 0xFF) || (u0 != 0 && (e0 < 96 || e0 > 159));
        bool zpat    = (u0 == 0 && u1 != 0);
        if (insane0 || zpat) ++local;
    }
    atomicAdd(&cnt, local);
    __syncthreads();
    if (threadIdx.x == 0) flags[blockIdx.x] = (cnt * 8 > npairs) ? 1 : 0;
}

// ---------------- adaptive convert (single buffer; middle tier) -----------
__global__ __launch_bounds__(256) void cvt_adapt(
        const void* __restrict__ src, unsigned short* __restrict__ dst,
        int n, const int* __restrict__ flag) {
    int i = blockIdx.x * 256 + threadIdx.x;
    if (i * 4 >= n) return;
    if (*flag) {
        float4 f = reinterpret_cast<const float4*>(src)[i];
        ushort4 o;
        o.x = f2b(f.x); o.y = f2b(f.y); o.z = f2b(f.z); o.w = f2b(f.w);
        reinterpret_cast<ushort4*>(dst)[i] = o;
    } else {
        reinterpret_cast<ushort4*>(dst)[i] = reinterpret_cast<const ushort4*>(src)[i];
    }
}

// ---------------- fused weight convert: all 6 weights, one launch ---------
struct CvtArgs {
    const void* src[6];
    unsigned short* dst[6];
    int n[6];
    int blkoff[7];
    const int* F;
    int fidx[6];
};
__global__ __launch_bounds__(256) void cvt_weights(CvtArgs a) {
    int b = blockIdx.x, seg = 0;
    #pragma unroll
    for (int s = 0; s < 6; ++s) if (b >= a.blkoff[s + 1]) seg = s + 1;
    int i = (b - a.blkoff[seg]) * 256 + threadIdx.x;
    if (i * 4 >= a.n[seg]) return;
    if (a.F[a.fidx[seg]]) {
        float4 f = reinterpret_cast<const float4*>(a.src[seg])[i];
        ushort4 o;
        o.x = f2b(f.x); o.y = f2b(f.y); o.z = f2b(f.z); o.w = f2b(f.w);
        reinterpret_cast<ushort4*>(a.dst[seg])[i] = o;
    } else {
        reinterpret_cast<ushort4*>(a.dst[seg])[i] =
            reinterpret_cast<const ushort4*>(a.src[seg])[i];
    }
}

// ---------------- LayerNorm: one wave per row; bf16 out -------------------
__global__ __launch_bounds__(256) void ln_kernel(
        const void* __restrict__ x,     const int* __restrict__ fx,
        const void* __restrict__ scale, const int* __restrict__ fsc,
        const void* __restrict__ shift, const int* __restrict__ fsh,
        unsigned short* __restrict__ out) {
    const bool xf = fx && *fx, scf = fsc && *fsc, shf = fsh && *fsh;
    int wave = threadIdx.x >> 6;
    int lane = threadIdx.x & 63;
    int row  = blockIdx.x * 4 + wave;
    const size_t rbase = (size_t)row * EMB;
    float v[12];
    float s = 0.f, s2 = 0.f;
    #pragma unroll
    for (int i = 0; i < 3; ++i) {
        float4 a = load4f(x, rbase + i * 256 + lane * 4, xf);
        v[i*4+0] = a.x; v[i*4+1] = a.y; v[i*4+2] = a.z; v[i*4+3] = a.w;
        s  += a.x + a.y + a.z + a.w;
        s2 += a.x*a.x + a.y*a.y + a.z*a.z + a.w*a.w;
    }
    #pragma unroll
    for (int off = 1; off < 64; off <<= 1) {
        s  += __shfl_xor(s,  off);
        s2 += __shfl_xor(s2, off);
    }
    float mean = s * (1.f / EMB);
    float var  = fmaxf(s2 * (1.f / EMB) - mean * mean, 0.f);
    float rstd = rsqrtf(var + 1e-5f);
    unsigned short* orow = out + rbase;
    #pragma unroll
    for (int i = 0; i < 3; ++i) {
        float4 sc = load4f(scale, i * 256 + lane * 4, scf);
        float4 sh = load4f(shift, i * 256 + lane * 4, shf);
        ushort4 o;
        o.x = f2b((v[i*4+0] - mean) * rstd * sc.x + sh.x);
        o.y = f2b((v[i*4+1] - mean) * rstd * sc.y + sh.y);
        o.z = f2b((v[i*4+2] - mean) * rstd * sc.z + sh.z);
        o.w = f2b((v[i*4+3] - mean) * rstd * sc.w + sh.w);
        *reinterpret_cast<ushort4*>(orow + i * 256 + lane * 4) = o;
    }
}

// ---------------- gemm_lds: pure-bf16 GEMM with async LDS staging ---------
template<bool GELU, bool RESID, bool OUTF32>
__global__ __launch_bounds__(256) void gemm_lds(
        const unsigned short* __restrict__ A,
        const unsigned short* __restrict__ W,
        const void* R, const int* __restrict__ fR, size_t rOff,
        void* C, int M, int N, int K) {
    constexpr int BK = 32;
    __shared__ __align__(16) unsigned short sA[128 * BK];
    __shared__ __align__(16) unsigned short sB[128 * BK];
    const int m0 = blockIdx.x * 128, n0 = blockIdx.y * 128;
    const int t = threadIdx.x, wave = t >> 6, lane = t & 63;
    const int wrow = (wave >> 1) * 64, wcol = (wave & 1) * 64;
    const int quad = lane >> 4, lr = lane & 15;
    const int r0 = t >> 2;
    const int c0 = (t & 3) * 8;
    const bool rf = fR && *fR;

    f32x4 acc[4][4];
    #pragma unroll
    for (int i = 0; i < 4; ++i)
        #pragma unroll
        for (int j = 0; j < 4; ++j)
            acc[i][j] = (f32x4){0.f, 0.f, 0.f, 0.f};

    const unsigned short* gA0 = A + (size_t)(m0 + r0) * K + c0;
    const unsigned short* gA1 = A + (size_t)(m0 + 64 + r0) * K + c0;
    const unsigned short* gB0 = W + (size_t)(n0 + r0) * K + c0;
    const unsigned short* gB1 = W + (size_t)(n0 + 64 + r0) * K + c0;
    unsigned short* lA0 = sA + wave * 512;
    unsigned short* lA1 = sA + 2048 + wave * 512;
    unsigned short* lB0 = sB + wave * 512;
    unsigned short* lB1 = sB + 2048 + wave * 512;

    for (int k0 = 0; k0 < K; k0 += BK) {
#if HAS_GLL
        gll16(gA0 + k0, lA0);
        gll16(gA1 + k0, lA1);
        gll16(gB0 + k0, lB0);
        gll16(gB1 + k0, lB1);
#else
        *reinterpret_cast<int4*>(sA + t * 8)        = *reinterpret_cast<const int4*>(gA0 + k0);
        *reinterpret_cast<int4*>(sA + 2048 + t * 8) = *reinterpret_cast<const int4*>(gA1 + k0);
        *reinterpret_cast<int4*>(sB + t * 8)        = *reinterpret_cast<const int4*>(gB0 + k0);
        *reinterpret_cast<int4*>(sB + 2048 + t * 8) = *reinterpret_cast<const int4*>(gB1 + k0);
#endif
        __syncthreads();
        bf16x8 af[4], bfv[4];
        #pragma unroll
        for (int i = 0; i < 4; ++i)
            af[i] = *reinterpret_cast<const bf16x8*>(sA + (wrow + i * 16 + lr) * BK + quad * 8);
        #pragma unroll
        for (int j = 0; j < 4; ++j)
            bfv[j] = *reinterpret_cast<const bf16x8*>(sB + (wcol + j * 16 + lr) * BK + quad * 8);
        #pragma unroll
        for (int i = 0; i < 4; ++i)
            #pragma unroll
            for (int j = 0; j < 4; ++j)
                acc[i][j] = __builtin_amdgcn_mfma_f32_16x16x32_bf16(af[i], bfv[j], acc[i][j], 0, 0, 0);
        __syncthreads();
    }

    #pragma unroll
    for (int i = 0; i < 4; ++i) {
        #pragma unroll
        for (int j = 0; j < 4; ++j) {
            #pragma unroll
            for (int r = 0; r < 4; ++r) {
                int row = m0 + wrow + i * 16 + quad * 4 + r;
                int col = n0 + wcol + j * 16 + lr;
                float val = acc[i][j][r];
                if (GELU) {
                    float x3 = val * val * val;
                    val = 0.5f * val * (1.f + tanhf(0.7978845608028654f * (val + 0.044715f * x3)));
                }
                size_t idx = (size_t)row * N + col;
                if (RESID) {
                    float rv = rf ? ((const float*)R)[idx + rOff]
                                  : b2f(((const unsigned short*)R)[idx + rOff]);
                    val += rv;
                }
                if (OUTF32) ((float*)C)[idx] = val;
                else        ((unsigned short*)C)[idx] = f2b(val);
            }
        }
    }
}

// ---------------- legacy flagged GEMM (fallback tiers only) ---------------
template<bool GELU, bool RESID, bool OUTF32>
__global__ __launch_bounds__(256) void gemm_bt(
        const unsigned short* __restrict__ A,
        const void* __restrict__ W, const int* __restrict__ fW,
        const void* R, const int* __restrict__ fR, size_t rOff,
        void* C,
        int M, int N, int K) {
    const bool wf = fW && *fW;
    const bool rf = fR && *fR;
    constexpr int BK = 32, PAD = 8, LDW = BK + PAD;
    __shared__ __align__(16) unsigned short sA[128 * LDW];
    __shared__ __align__(16) unsigned short sB[128 * LDW];
    const int m0 = blockIdx.x * 128;
    const int n0 = blockIdx.y * 128;
    const int t    = threadIdx.x;
    const int wave = t >> 6, lane = t & 63;
    const int wrow = (wave >> 1) * 64, wcol = (wave & 1) * 64;
    const int quad = lane >> 4, lr = lane & 15;
    const int srow = t >> 2, scol = (t & 3) * 8;

    f32x4 acc[4][4];
    #pragma unroll
    for (int i = 0; i < 4; ++i)
        #pragma unroll
        for (int j = 0; j < 4; ++j)
            acc[i][j] = (f32x4){0.f, 0.f, 0.f, 0.f};

    const size_t aBase = (size_t)(m0 + srow) * K + scol;
    const size_t bBase = (size_t)(n0 + srow) * K + scol;

    for (int k0 = 0; k0 < K; k0 += BK) {
        int4 av0 = *reinterpret_cast<const int4*>(A + aBase + k0);
        int4 av1 = *reinterpret_cast<const int4*>(A + aBase + (size_t)64 * K + k0);
        int4 bv0 = load8(W, bBase + k0, wf);
        int4 bv1 = load8(W, bBase + (size_t)64 * K + k0, wf);
        *reinterpret_cast<int4*>(sA + srow * LDW + scol)        = av0;
        *reinterpret_cast<int4*>(sA + (srow + 64) * LDW + scol) = av1;
        *reinterpret_cast<int4*>(sB + srow * LDW + scol)        = bv0;
        *reinterpret_cast<int4*>(sB + (srow + 64) * LDW + scol) = bv1;
        __syncthreads();
        bf16x8 af[4], bfv[4];
        #pragma unroll
        for (int i = 0; i < 4; ++i)
            af[i] = *reinterpret_cast<const bf16x8*>(sA + (wrow + i * 16 + lr) * LDW + quad * 8);
        #pragma unroll
        for (int j = 0; j < 4; ++j)
            bfv[j] = *reinterpret_cast<const bf16x8*>(sB + (wcol + j * 16 + lr) * LDW + quad * 8);
        #pragma unroll
        for (int i = 0; i < 4; ++i)
            #pragma unroll
            for (int j = 0; j < 4; ++j)
                acc[i][j] = __builtin_amdgcn_mfma_f32_16x16x32_bf16(af[i], bfv[j], acc[i][j], 0, 0, 0);
        __syncthreads();
    }

    #pragma unroll
    for (int i = 0; i < 4; ++i) {
        #pragma unroll
        for (int j = 0; j < 4; ++j) {
            #pragma unroll
            for (int r = 0; r < 4; ++r) {
                int row = m0 + wrow + i * 16 + quad * 4 + r;
                int col = n0 + wcol + j * 16 + lr;
                float val = acc[i][j][r];
                if (GELU) {
                    float x3 = val * val * val;
                    val = 0.5f * val * (1.f + tanhf(0.7978845608028654f * (val + 0.044715f * x3)));
                }
                size_t idx = (size_t)row * N + col;
                if (RESID) {
                    float rv = rf ? ((const float*)R)[idx + rOff]
                                  : b2f(((const unsigned short*)R)[idx + rOff]);
                    val += rv;
                }
                if (OUTF32) ((float*)C)[idx] = val;
                else        ((unsigned short*)C)[idx] = f2b(val);
            }
        }
    }
}

// ---------------- MFMA flash attention, 128-query tiles -------------------
// grid.x = nb*NHEADS*8. Block: one head x 128 queries; wave owns 2x16 rows.
// q/k/v: row pointers with element row-stride rs (supports packed QKV).
__global__ __launch_bounds__(256) void fattn_kernel(
        const unsigned short* __restrict__ q,
        const unsigned short* __restrict__ k,
        const unsigned short* __restrict__ v,
        int rs, unsigned short* __restrict__ ctx) {
    constexpr int VTP = 72;
    __shared__ unsigned short Vt[64 * VTP];         // V^T tile [d][key]
    __shared__ unsigned short Pl[4][32 * VTP];      // per-wave P [2*16 q][key]
    const int tid  = threadIdx.x;
    const int wave = tid >> 6, lane = tid & 63;
    const int quad = lane >> 4, lr = lane & 15;
    const int head = blockIdx.x >> 3;
    const int qt   = blockIdx.x & 7;                // 128-query tile
    const int bb   = head / NHEADS, hd = head % NHEADS;
    const size_t seqbase = (size_t)bb * SEQ;
    const int q0w = qt * 128 + wave * 32;           // wave's 32 queries

    bf16x8 aQ[2][2];
    #pragma unroll
    for (int s = 0; s < 2; ++s) {
        const unsigned short* qp = q + (seqbase + q0w + s * 16 + lr) * rs + hd * HDIM + quad * 8;
        aQ[s][0] = *reinterpret_cast<const bf16x8*>(qp);
        aQ[s][1] = *reinterpret_cast<const bf16x8*>(qp + 32);
    }

    f32x4 O[2][4];
    float mrow[2][4], lrow[2][4];
    #pragma unroll
    for (int s = 0; s < 2; ++s) {
        #pragma unroll
        for (int d = 0; d < 4; ++d) O[s][d] = (f32x4){0.f, 0.f, 0.f, 0.f};
        #pragma unroll
        for (int r = 0; r < 4; ++r) { mrow[s][r] = -__builtin_inff(); lrow[s][r] = 0.f; }
    }

    const int ktmax = 2 * qt + 1;
    for (int kt = 0; kt <= ktmax; ++kt) {
        {   // stage V^T tile
            const int vrow = tid >> 2;
            const int vcol = (tid & 3) * 16;
            const unsigned short* vp = v + (seqbase + kt * 64 + vrow) * rs + hd * HDIM + vcol;
            union { int4 v4; unsigned short u[8]; } ua, ub;
            ua.v4 = *reinterpret_cast<const int4*>(vp);
            ub.v4 = *reinterpret_cast<const int4*>(vp + 8);
            #pragma unroll
            for (int e = 0; e < 8; ++e) Vt[(vcol + e) * VTP + vrow]     = ua.u[e];
            #pragma unroll
            for (int e = 0; e < 8; ++e) Vt[(vcol + 8 + e) * VTP + vrow] = ub.u[e];
        }
        __syncthreads();

        const bool active = (kt * 64 <= q0w + 31);   // any key <= wave's max q
        if (active) {
            bf16x8 kb[4][2];
            #pragma unroll
            for (int sub = 0; sub < 4; ++sub) {
                const unsigned short* kp = k + (seqbase + kt * 64 + sub * 16 + lr) * rs + hd * HDIM + quad * 8;
                kb[sub][0] = *reinterpret_cast<const bf16x8*>(kp);
                kb[sub][1] = *reinterpret_cast<const bf16x8*>(kp + 32);
            }
            unsigned short* Pw = Pl[wave];
            #pragma unroll
            for (int s = 0; s < 2; ++s) {
                f32x4 S[4];
                #pragma unroll
                for (int sub = 0; sub < 4; ++sub) {
                    f32x4 a = (f32x4){0.f, 0.f, 0.f, 0.f};
                    a = __builtin_amdgcn_mfma_f32_16x16x32_bf16(aQ[s][0], kb[sub][0], a, 0, 0, 0);
                    a = __builtin_amdgcn_mfma_f32_16x16x32_bf16(aQ[s][1], kb[sub][1], a, 0, 0, 0);
                    S[sub] = a;
                }
                const int qsb = q0w + s * 16;
                const bool anymask = (kt * 64 + 63) > qsb;
                #pragma unroll
                for (int sub = 0; sub < 4; ++sub) {
                    const int kg = kt * 64 + sub * 16 + lr;
                    #pragma unroll
                    for (int r = 0; r < 4; ++r) {
                        float sv = S[sub][r] * 0.125f;
                        if (anymask && kg > qsb + quad * 4 + r) sv = -__builtin_inff();
                        S[sub][r] = sv;
                    }
                }
                float mnew[4], alpha[4];
                #pragma unroll
                for (int r = 0; r < 4; ++r) {
                    float mx = fmaxf(fmaxf(S[0][r], S[1][r]), fmaxf(S[2][r], S[3][r]));
                    #pragma unroll
                    for (int m = 1; m < 16; m <<= 1) mx = fmaxf(mx, __shfl_xor(mx, m));
                    mnew[r]  = fmaxf(mrow[s][r], mx);
                    alpha[r] = __expf(mrow[s][r] - mnew[r]);
                    mrow[s][r] = mnew[r];
                }
                float rsum[4] = {0.f, 0.f, 0.f, 0.f};
                #pragma unroll
                for (int sub = 0; sub < 4; ++sub)
                    #pragma unroll
                    for (int r = 0; r < 4; ++r) {
                        float p = __expf(S[sub][r] - mnew[r]);
                        S[sub][r] = p;
                        rsum[r] += p;
                    }
                #pragma unroll
                for (int r = 0; r < 4; ++r) {
                    float rsv = rsum[r];
                    #pragma unroll
                    for (int m = 1; m < 16; m <<= 1) rsv += __shfl_xor(rsv, m);
                    lrow[s][r] = lrow[s][r] * alpha[r] + rsv;
                }
                #pragma unroll
                for (int d = 0; d < 4; ++d)
                    #pragma unroll
                    for (int r = 0; r < 4; ++r)
                        O[s][d][r] *= alpha[r];
                #pragma unroll
                for (int sub = 0; sub < 4; ++sub)
                    #pragma unroll
                    for (int r = 0; r < 4; ++r)
                        Pw[(s * 16 + quad * 4 + r) * VTP + sub * 16 + lr] = f2b(S[sub][r]);
            }
        }
        __syncthreads();

        if (active) {
            unsigned short* Pw = Pl[wave];
            #pragma unroll
            for (int s = 0; s < 2; ++s)
                #pragma unroll
                for (int c = 0; c < 2; ++c) {
                    bf16x8 aP = *reinterpret_cast<const bf16x8*>(&Pw[(s * 16 + lr) * VTP + c * 32 + quad * 8]);
                    #pragma unroll
                    for (int d = 0; d < 4; ++d) {
                        bf16x8 bV = *reinterpret_cast<const bf16x8*>(&Vt[(d * 16 + lr) * VTP + c * 32 + quad * 8]);
                        O[s][d] = __builtin_amdgcn_mfma_f32_16x16x32_bf16(aP, bV, O[s][d], 0, 0, 0);
                    }
                }
        }
        __syncthreads();
    }

    #pragma unroll
    for (int s = 0; s < 2; ++s)
        #pragma unroll
        for (int r = 0; r < 4; ++r) {
            const float rinv = 1.f / lrow[s][r];
            const int qg = q0w + s * 16 + quad * 4 + r;
            unsigned short* crow = ctx + (seqbase + qg) * EMB + hd * HDIM;
            #pragma unroll
            for (int d = 0; d < 4; ++d)
                crow[d * 16 + lr] = f2b(O[s][d][r] * rinv);
        }
}

// ---------------------------------------------------------------------------
extern "C" void kernel_launch(void* const* d_in, const int* in_sizes, int n_in,
                              void* d_out, int out_size, void* d_ws, size_t ws_size,
                              hipStream_t stream) {
    const void* x  = d_in[0];
    const void* wq = d_in[1], *wk = d_in[2], *wv = d_in[3], *wo = d_in[4];
    const void* w1 = d_in[5], *w2 = d_in[6];
    const void* g1 = d_in[7], *s1 = d_in[8], *g2 = d_in[9], *s2 = d_in[10];
    char* ws = (char*)d_ws;
    dim3 blk(256);

    int* F = (int*)ws;
    {
        DetectArgs da;
        for (int i = 0; i < 11; ++i) { da.p[i] = (const unsigned short*)d_in[i]; da.n[i] = in_sizes[i]; }
        detect_all<<<11, blk, 0, stream>>>(da, F);
    }

    const size_t SZE = (size_t)MROWS * EMB;   // 6,291,456 elems
    const size_t SZB = SZE * 2;
    unsigned short* base = (unsigned short*)(ws + 256);
    dim3 g768(MROWS / 128, EMB / 128);

    // full-path footprint: 2*W4 + 4*W2(qkv+o) + P(8192*2304) + 2*SZE + g(8192*3072)
    const size_t FULLB = 256 + 2ULL * (2 * W4E) + 2ULL * (4 * W2E)
                       + 2ULL * ((size_t)MROWS * 2304) + 2 * SZB
                       + 2ULL * ((size_t)MROWS * FFN);   // = 127,402,240 B

    if (ws_size >= FULLB) {
        // ---- full path: fused QKV, 128q flash, full-width FFN (9 launches) ----
        unsigned short* w1b   = base;
        unsigned short* w2b   = w1b + W4E;
        unsigned short* wqkvb = w2b + W4E;          // [2304, 768] packed rows
        unsigned short* wob   = wqkvb + 3 * W2E;
        unsigned short* P     = wob + W2E;          // [8192, 2304] packed qkv
        unsigned short* B0    = P + (size_t)MROWS * 2304;  // ctx -> h2
        unsigned short* B1    = B0 + SZE;           // h -> x2
        unsigned short* G     = B1 + SZE;           // [8192, 3072]

        {
            CvtArgs ca;
            ca.src[0] = wq; ca.src[1] = wk; ca.src[2] = wv;
            ca.src[3] = wo; ca.src[4] = w1; ca.src[5] = w2;
            ca.dst[0] = wqkvb; ca.dst[1] = wqkvb + W2E; ca.dst[2] = wqkvb + 2 * W2E;
            ca.dst[3] = wob;   ca.dst[4] = w1b;         ca.dst[5] = w2b;
            ca.n[0] = ca.n[1] = ca.n[2] = ca.n[3] = W2E; ca.n[4] = ca.n[5] = W4E;
            int off = 0;
            for (int s = 0; s < 6; ++s) { ca.blkoff[s] = off; off += ca.n[s] / 1024; }
            ca.blkoff[6] = off;
            ca.F = F;
            ca.fidx[0] = 1; ca.fidx[1] = 2; ca.fidx[2] = 3;
            ca.fidx[3] = 4; ca.fidx[4] = 5; ca.fidx[5] = 6;
            cvt_weights<<<off, blk, 0, stream>>>(ca);
        }

        ln_kernel<<<MROWS / 4, blk, 0, stream>>>(x, F+0, g1, F+7, s1, F+8, B1);     // h -> B1
        dim3 gqkv(MROWS / 128, 2304 / 128);                                          // (64,18)
        gemm_lds<false, false, false><<<gqkv, blk, 0, stream>>>(B1, wqkvb, nullptr, nullptr, 0, P, MROWS, 2304, EMB);
        fattn_kernel<<<BATCH * NHEADS * 8, blk, 0, stream>>>(P, P + 768, P + 1536, 2304, B0);  // ctx -> B0
        gemm_lds<false, true, false><<<g768, blk, 0, stream>>>(B0, wob, x, F+0, 0, B1, MROWS, EMB, EMB); // x2 -> B1
        ln_kernel<<<MROWS / 4, blk, 0, stream>>>(B1, nullptr, g2, F+9, s2, F+10, B0);           // h2 -> B0
        dim3 gffn1(MROWS / 128, FFN / 128);                                          // (64,24)
        gemm_lds<true, false, false><<<gffn1, blk, 0, stream>>>(B0, w1b, nullptr, nullptr, 0, G, MROWS, FFN, EMB);
        gemm_lds<false, true, true><<<g768, blk, 0, stream>>>(G, w2b, B1, nullptr, 0, d_out, MROWS, EMB, FFN);
    } else if (ws_size >= 256 + 7 * SZB) {
        // ---- r9 optimized path (77 MB) ----
        unsigned short* wqb = base;
        unsigned short* wkb = wqb + W2E;
        unsigned short* wvb = wkb + W2E;
        unsigned short* wob = wvb + W2E;
        unsigned short* w1b = wob + W2E;
        unsigned short* w2b = w1b + W4E;
        unsigned short* B0  = w2b + W4E;
        unsigned short* B1  = B0 + SZE;
        unsigned short* B2  = B1 + SZE;
        unsigned short* B3  = B2 + SZE;

        cvt_adapt<<<W2E / 1024, blk, 0, stream>>>(wq, wqb, W2E, F + 1);
        cvt_adapt<<<W2E / 1024, blk, 0, stream>>>(wk, wkb, W2E, F + 2);
        cvt_adapt<<<W2E / 1024, blk, 0, stream>>>(wv, wvb, W2E, F + 3);
        cvt_adapt<<<W2E / 1024, blk, 0, stream>>>(wo, wob, W2E, F + 4);
        cvt_adapt<<<W4E / 1024, blk, 0, stream>>>(w1, w1b, W4E, F + 5);
        cvt_adapt<<<W4E / 1024, blk, 0, stream>>>(w2, w2b, W4E, F + 6);

        ln_kernel<<<MROWS / 4, blk, 0, stream>>>(x, F+0, g1, F+7, s1, F+8, B0);
        gemm_lds<false, false, false><<<g768, blk, 0, stream>>>(B0, wqb, nullptr, nullptr, 0, B1, MROWS, EMB, EMB);
        gemm_lds<false, false, false><<<g768, blk, 0, stream>>>(B0, wkb, nullptr, nullptr, 0, B2, MROWS, EMB, EMB);
        gemm_lds<false, false, false><<<g768, blk, 0, stream>>>(B0, wvb, nullptr, nullptr, 0, B3, MROWS, EMB, EMB);
        fattn_kernel<<<BATCH * NHEADS * 8, blk, 0, stream>>>(B1, B2, B3, EMB, B0);
        gemm_lds<false, true, false><<<g768, blk, 0, stream>>>(B0, wob, x, F+0, 0, B1, MROWS, EMB, EMB);
        ln_kernel<<<MROWS / 4, blk, 0, stream>>>(B1, nullptr, g2, F+9, s2, F+10, B2);
        dim3 c3072(4096 / 128, FFN / 128), c768(4096 / 128, EMB / 128);
        for (int c = 0; c < 2; ++c) {
            const size_t r0 = (size_t)c * 4096;
            gemm_lds<true, false, false><<<c3072, blk, 0, stream>>>(B2 + r0 * EMB, w1b, nullptr, nullptr, 0, B3, 4096, FFN, EMB);
            gemm_lds<false, true, true><<<c768, blk, 0, stream>>>(B3, w2b, B1 + r0 * EMB, nullptr, 0, (float*)d_out + r0 * EMB, 4096, EMB, FFN);
        }
    } else if (ws_size >= 256 + 4 * SZB) {
        // ---- fallback tier M ----
        unsigned short* B0 = base;
        unsigned short* B1 = B0 + SZE;
        unsigned short* B2 = B1 + SZE;
        unsigned short* B3 = B2 + SZE;
        ln_kernel<<<MROWS / 4, blk, 0, stream>>>(x, F+0, g1, F+7, s1, F+8, B0);
        gemm_bt<false, false, false><<<g768, blk, 0, stream>>>(B0, wq, F+1, nullptr, nullptr, 0, B1, MROWS, EMB, EMB);
        gemm_bt<false, false, false><<<g768, blk, 0, stream>>>(B0, wk, F+2, nullptr, nullptr, 0, B2, MROWS, EMB, EMB);
        gemm_bt<false, false, false><<<g768, blk, 0, stream>>>(B0, wv, F+3, nullptr, nullptr, 0, B3, MROWS, EMB, EMB);
        fattn_kernel<<<BATCH * NHEADS * 8, blk, 0, stream>>>(B1, B2, B3, EMB, B0);
        gemm_bt<false, true, false><<<g768, blk, 0, stream>>>(B0, wo, F+4, x, F+0, 0, B1, MROWS, EMB, EMB);
        ln_kernel<<<MROWS / 4, blk, 0, stream>>>(B1, nullptr, g2, F+9, s2, F+10, B2);
        dim3 c3072(2048 / 128, FFN / 128), c768(2048 / 128, EMB / 128);
        for (int c = 0; c < 4; ++c) {
            const size_t r0 = (size_t)c * 2048;
            gemm_bt<true, false, false><<<c3072, blk, 0, stream>>>(B2 + r0 * EMB, w1, F+5, nullptr, nullptr, 0, B3, 2048, FFN, EMB);
            gemm_bt<false, true, true><<<c768, blk, 0, stream>>>(B3, w2, F+6, B1 + r0 * EMB, nullptr, 0, (float*)d_out + r0 * EMB, 2048, EMB, FFN);
        }
    } else {
        // ---- fallback tier B ----
        unsigned short* hlow = (unsigned short*)d_out;
        unsigned short* x2up = (unsigned short*)d_out + SZE;
        unsigned short* wsQ = base;
        unsigned short* wsK = wsQ + (size_t)1024 * EMB;
        unsigned short* wsV = wsK + (size_t)1024 * EMB;
        unsigned short* wsC = wsV + (size_t)1024 * EMB;
        ln_kernel<<<MROWS / 4, blk, 0, stream>>>(x, F+0, g1, F+7, s1, F+8, hlow);
        dim3 q768(1024 / 128, EMB / 128);
        for (int grp = 0; grp < BATCH; ++grp) {
            const size_t r0 = (size_t)grp * 1024;
            gemm_bt<false, false, false><<<q768, blk, 0, stream>>>(hlow + r0 * EMB, wq, F+1, nullptr, nullptr, 0, wsQ, 1024, EMB, EMB);
            gemm_bt<false, false, false><<<q768, blk, 0, stream>>>(hlow + r0 * EMB, wk, F+2, nullptr, nullptr, 0, wsK, 1024, EMB, EMB);
            gemm_bt<false, false, false><<<q768, blk, 0, stream>>>(hlow + r0 * EMB, wv, F+3, nullptr, nullptr, 0, wsV, 1024, EMB, EMB);
            fattn_kernel<<<1 * NHEADS * 8, blk, 0, stream>>>(wsQ, wsK, wsV, EMB, wsC);
            gemm_bt<false, true, false><<<q768, blk, 0, stream>>>(wsC, wo, F+4, x, F+0, r0 * EMB, x2up + r0 * EMB, 1024, EMB, EMB);
        }
        unsigned short* xb = base;
        unsigned short* h2 = xb + (size_t)1024 * EMB;
        unsigned short* gb = h2 + (size_t)1024 * EMB;
        dim3 f3072(1024 / 128, FFN / 128), f768(1024 / 128, EMB / 128);
        for (int c = 0; c < BATCH; ++c) {
            const size_t r0 = (size_t)c * 1024;
            hipMemcpyAsync(xb, x2up + r0 * EMB, (size_t)1024 * EMB * 2,
                           hipMemcpyDeviceToDevice, stream);
            ln_kernel<<<1024 / 4, blk, 0, stream>>>(xb, nullptr, g2, F+9, s2, F+10, h2);
            gemm_bt<true, false, false><<<f3072, blk, 0, stream>>>(h2, w1, F+5, nullptr, nullptr, 0, gb, 1024, FFN, EMB);
            gemm_bt<false, true, true><<<f768, blk, 0, stream>>>(gb, w2, F+6, xb, nullptr, 0, (float*)d_out + r0 * EMB, 1024, EMB, FFN);
        }
    }
}

// Round 11
// 451.208 us; speedup vs baseline: 5.7250x; 1.1151x over previous
//
#include <hip/hip_runtime.h>
#include <hip/hip_bf16.h>
#include <cstdint>

#define EMB    768
#define NHEADS 12
#define HDIM   64
#define SEQ    1024
#define BATCH  8
#define MROWS  (BATCH*SEQ)   /* 8192 */
#define FFN    3072
#define W2E    (EMB*EMB)     /* 589824 */
#define W4E    (FFN*EMB)     /* 2359296 */

typedef __bf16 bf16_t;
typedef bf16_t bf16x8 __attribute__((ext_vector_type(8)));
typedef float  f32x4  __attribute__((ext_vector_type(4)));

__device__ __forceinline__ float b2f(unsigned short u) {
    union { unsigned int i; float f; } t; t.i = ((unsigned int)u) << 16; return t.f;
}
__device__ __forceinline__ unsigned short f2b(float f) {
    union { float f; unsigned int i; } t; t.f = f;
    unsigned int lsb = (t.i >> 16) & 1u;
    t.i += 0x7fffu + lsb;
    return (unsigned short)(t.i >> 16);
}

#if defined(__has_builtin)
#if __has_builtin(__builtin_amdgcn_global_load_lds)
#define HAS_GLL 1
#endif
#endif
#ifndef HAS_GLL
#define HAS_GLL 0
#endif

__device__ __forceinline__ void gll16(const unsigned short* g, unsigned short* lds_wave_base) {
#if HAS_GLL
    __builtin_amdgcn_global_load_lds(
        (const __attribute__((address_space(1))) unsigned int*)g,
        (__attribute__((address_space(3))) unsigned int*)lds_wave_base, 16, 0, 0);
#endif
}

__device__ __forceinline__ int4 load8(const void* src, size_t eoff, bool f32) {
    if (f32) {
        const float4* p = reinterpret_cast<const float4*>((const float*)src + eoff);
        float4 a = p[0], b = p[1];
        union { unsigned short u[8]; int4 v; } r;
        r.u[0] = f2b(a.x); r.u[1] = f2b(a.y); r.u[2] = f2b(a.z); r.u[3] = f2b(a.w);
        r.u[4] = f2b(b.x); r.u[5] = f2b(b.y); r.u[6] = f2b(b.z); r.u[7] = f2b(b.w);
        return r.v;
    }
    return *reinterpret_cast<const int4*>((const unsigned short*)src + eoff);
}
__device__ __forceinline__ float4 load4f(const void* src, size_t eoff, bool f32) {
    if (f32) return *reinterpret_cast<const float4*>((const float*)src + eoff);
    ushort4 u = *reinterpret_cast<const ushort4*>((const unsigned short*)src + eoff);
    float4 r; r.x = b2f(u.x); r.y = b2f(u.y); r.z = b2f(u.z); r.w = b2f(u.w);
    return r;
}

// ---------------- dtype probe: one block per input ------------------------
struct DetectArgs { const unsigned short* p[11]; int n[11]; };

__global__ __launch_bounds__(256) void detect_all(DetectArgs a, int* __restrict__ flags) {
    __shared__ int cnt;
    if (threadIdx.x == 0) cnt = 0;
    __syncthreads();
    const unsigned short* src = a.p[blockIdx.x];
    int npairs = a.n[blockIdx.x] / 2;
    if (npairs > 4096) npairs = 4096;
    int local = 0;
    for (int p = threadIdx.x; p < npairs; p += 256) {
        unsigned short u0 = src[2 * p], u1 = src[2 * p + 1];
        int e0 = (u0 >> 7) & 0xFF;
        bool insane0 = (e0 == 0xFF) || (u0 != 0 && (e0 < 96 || e0 > 159));
        bool zpat    = (u0 == 0 && u1 != 0);
        if (insane0 || zpat) ++local;
    }
    atomicAdd(&cnt, local);
    __syncthreads();
    if (threadIdx.x == 0) flags[blockIdx.x] = (cnt * 8 > npairs) ? 1 : 0;
}

// ---------------- adaptive convert (single buffer; middle tier) -----------
__global__ __launch_bounds__(256) void cvt_adapt(
        const void* __restrict__ src, unsigned short* __restrict__ dst,
        int n, const int* __restrict__ flag) {
    int i = blockIdx.x * 256 + threadIdx.x;
    if (i * 4 >= n) return;
    if (*flag) {
        float4 f = reinterpret_cast<const float4*>(src)[i];
        ushort4 o;
        o.x = f2b(f.x); o.y = f2b(f.y); o.z = f2b(f.z); o.w = f2b(f.w);
        reinterpret_cast<ushort4*>(dst)[i] = o;
    } else {
        reinterpret_cast<ushort4*>(dst)[i] = reinterpret_cast<const ushort4*>(src)[i];
    }
}

// ---------------- fused weight convert: all 6 weights, one launch ---------
struct CvtArgs {
    const void* src[6];
    unsigned short* dst[6];
    int n[6];
    int blkoff[7];
    const int* F;
    int fidx[6];
};
__global__ __launch_bounds__(256) void cvt_weights(CvtArgs a) {
    int b = blockIdx.x, seg = 0;
    #pragma unroll
    for (int s = 0; s < 6; ++s) if (b >= a.blkoff[s + 1]) seg = s + 1;
    int i = (b - a.blkoff[seg]) * 256 + threadIdx.x;
    if (i * 4 >= a.n[seg]) return;
    if (a.F[a.fidx[seg]]) {
        float4 f = reinterpret_cast<const float4*>(a.src[seg])[i];
        ushort4 o;
        o.x = f2b(f.x); o.y = f2b(f.y); o.z = f2b(f.z); o.w = f2b(f.w);
        reinterpret_cast<ushort4*>(a.dst[seg])[i] = o;
    } else {
        reinterpret_cast<ushort4*>(a.dst[seg])[i] =
            reinterpret_cast<const ushort4*>(a.src[seg])[i];
    }
}

// ---------------- LayerNorm: one wave per row; bf16 out -------------------
__global__ __launch_bounds__(256) void ln_kernel(
        const void* __restrict__ x,     const int* __restrict__ fx,
        const void* __restrict__ scale, const int* __restrict__ fsc,
        const void* __restrict__ shift, const int* __restrict__ fsh,
        unsigned short* __restrict__ out) {
    const bool xf = fx && *fx, scf = fsc && *fsc, shf = fsh && *fsh;
    int wave = threadIdx.x >> 6;
    int lane = threadIdx.x & 63;
    int row  = blockIdx.x * 4 + wave;
    const size_t rbase = (size_t)row * EMB;
    float v[12];
    float s = 0.f, s2 = 0.f;
    #pragma unroll
    for (int i = 0; i < 3; ++i) {
        float4 a = load4f(x, rbase + i * 256 + lane * 4, xf);
        v[i*4+0] = a.x; v[i*4+1] = a.y; v[i*4+2] = a.z; v[i*4+3] = a.w;
        s  += a.x + a.y + a.z + a.w;
        s2 += a.x*a.x + a.y*a.y + a.z*a.z + a.w*a.w;
    }
    #pragma unroll
    for (int off = 1; off < 64; off <<= 1) {
        s  += __shfl_xor(s,  off);
        s2 += __shfl_xor(s2, off);
    }
    float mean = s * (1.f / EMB);
    float var  = fmaxf(s2 * (1.f / EMB) - mean * mean, 0.f);
    float rstd = rsqrtf(var + 1e-5f);
    unsigned short* orow = out + rbase;
    #pragma unroll
    for (int i = 0; i < 3; ++i) {
        float4 sc = load4f(scale, i * 256 + lane * 4, scf);
        float4 sh = load4f(shift, i * 256 + lane * 4, shf);
        ushort4 o;
        o.x = f2b((v[i*4+0] - mean) * rstd * sc.x + sh.x);
        o.y = f2b((v[i*4+1] - mean) * rstd * sc.y + sh.y);
        o.z = f2b((v[i*4+2] - mean) * rstd * sc.z + sh.z);
        o.w = f2b((v[i*4+3] - mean) * rstd * sc.w + sh.w);
        *reinterpret_cast<ushort4*>(orow + i * 256 + lane * 4) = o;
    }
}

// ---------------- gemm_lds: pure-bf16 GEMM with async LDS staging ---------
template<bool GELU, bool RESID, bool OUTF32>
__global__ __launch_bounds__(256) void gemm_lds(
        const unsigned short* __restrict__ A,
        const unsigned short* __restrict__ W,
        const void* R, const int* __restrict__ fR, size_t rOff,
        void* C, int M, int N, int K) {
    constexpr int BK = 32;
    __shared__ __align__(16) unsigned short sA[128 * BK];
    __shared__ __align__(16) unsigned short sB[128 * BK];
    const int m0 = blockIdx.x * 128, n0 = blockIdx.y * 128;
    const int t = threadIdx.x, wave = t >> 6, lane = t & 63;
    const int wrow = (wave >> 1) * 64, wcol = (wave & 1) * 64;
    const int quad = lane >> 4, lr = lane & 15;
    const int r0 = t >> 2;
    const int c0 = (t & 3) * 8;
    const bool rf = fR && *fR;

    f32x4 acc[4][4];
    #pragma unroll
    for (int i = 0; i < 4; ++i)
        #pragma unroll
        for (int j = 0; j < 4; ++j)
            acc[i][j] = (f32x4){0.f, 0.f, 0.f, 0.f};

    const unsigned short* gA0 = A + (size_t)(m0 + r0) * K + c0;
    const unsigned short* gA1 = A + (size_t)(m0 + 64 + r0) * K + c0;
    const unsigned short* gB0 = W + (size_t)(n0 + r0) * K + c0;
    const unsigned short* gB1 = W + (size_t)(n0 + 64 + r0) * K + c0;
    unsigned short* lA0 = sA + wave * 512;
    unsigned short* lA1 = sA + 2048 + wave * 512;
    unsigned short* lB0 = sB + wave * 512;
    unsigned short* lB1 = sB + 2048 + wave * 512;

    for (int k0 = 0; k0 < K; k0 += BK) {
#if HAS_GLL
        gll16(gA0 + k0, lA0);
        gll16(gA1 + k0, lA1);
        gll16(gB0 + k0, lB0);
        gll16(gB1 + k0, lB1);
#else
        *reinterpret_cast<int4*>(sA + t * 8)        = *reinterpret_cast<const int4*>(gA0 + k0);
        *reinterpret_cast<int4*>(sA + 2048 + t * 8) = *reinterpret_cast<const int4*>(gA1 + k0);
        *reinterpret_cast<int4*>(sB + t * 8)        = *reinterpret_cast<const int4*>(gB0 + k0);
        *reinterpret_cast<int4*>(sB + 2048 + t * 8) = *reinterpret_cast<const int4*>(gB1 + k0);
#endif
        __syncthreads();
        bf16x8 af[4], bfv[4];
        #pragma unroll
        for (int i = 0; i < 4; ++i)
            af[i] = *reinterpret_cast<const bf16x8*>(sA + (wrow + i * 16 + lr) * BK + quad * 8);
        #pragma unroll
        for (int j = 0; j < 4; ++j)
            bfv[j] = *reinterpret_cast<const bf16x8*>(sB + (wcol + j * 16 + lr) * BK + quad * 8);
        #pragma unroll
        for (int i = 0; i < 4; ++i)
            #pragma unroll
            for (int j = 0; j < 4; ++j)
                acc[i][j] = __builtin_amdgcn_mfma_f32_16x16x32_bf16(af[i], bfv[j], acc[i][j], 0, 0, 0);
        __syncthreads();
    }

    #pragma unroll
    for (int i = 0; i < 4; ++i) {
        #pragma unroll
        for (int j = 0; j < 4; ++j) {
            #pragma unroll
            for (int r = 0; r < 4; ++r) {
                int row = m0 + wrow + i * 16 + quad * 4 + r;
                int col = n0 + wcol + j * 16 + lr;
                float val = acc[i][j][r];
                if (GELU) {
                    float x3 = val * val * val;
                    val = 0.5f * val * (1.f + tanhf(0.7978845608028654f * (val + 0.044715f * x3)));
                }
                size_t idx = (size_t)row * N + col;
                if (RESID) {
                    float rv = rf ? ((const float*)R)[idx + rOff]
                                  : b2f(((const unsigned short*)R)[idx + rOff]);
                    val += rv;
                }
                if (OUTF32) ((float*)C)[idx] = val;
                else        ((unsigned short*)C)[idx] = f2b(val);
            }
        }
    }
}

// ---------------- legacy flagged GEMM (fallback tiers only) ---------------
template<bool GELU, bool RESID, bool OUTF32>
__global__ __launch_bounds__(256) void gemm_bt(
        const unsigned short* __restrict__ A,
        const void* __restrict__ W, const int* __restrict__ fW,
        const void* R, const int* __restrict__ fR, size_t rOff,
        void* C,
        int M, int N, int K) {
    const bool wf = fW && *fW;
    const bool rf = fR && *fR;
    constexpr int BK = 32, PAD = 8, LDW = BK + PAD;
    __shared__ __align__(16) unsigned short sA[128 * LDW];
    __shared__ __align__(16) unsigned short sB[128 * LDW];
    const int m0 = blockIdx.x * 128;
    const int n0 = blockIdx.y * 128;
    const int t    = threadIdx.x;
    const int wave = t >> 6, lane = t & 63;
    const int wrow = (wave >> 1) * 64, wcol = (wave & 1) * 64;
    const int quad = lane >> 4, lr = lane & 15;
    const int srow = t >> 2, scol = (t & 3) * 8;

    f32x4 acc[4][4];
    #pragma unroll
    for (int i = 0; i < 4; ++i)
        #pragma unroll
        for (int j = 0; j < 4; ++j)
            acc[i][j] = (f32x4){0.f, 0.f, 0.f, 0.f};

    const size_t aBase = (size_t)(m0 + srow) * K + scol;
    const size_t bBase = (size_t)(n0 + srow) * K + scol;

    for (int k0 = 0; k0 < K; k0 += BK) {
        int4 av0 = *reinterpret_cast<const int4*>(A + aBase + k0);
        int4 av1 = *reinterpret_cast<const int4*>(A + aBase + (size_t)64 * K + k0);
        int4 bv0 = load8(W, bBase + k0, wf);
        int4 bv1 = load8(W, bBase + (size_t)64 * K + k0, wf);
        *reinterpret_cast<int4*>(sA + srow * LDW + scol)        = av0;
        *reinterpret_cast<int4*>(sA + (srow + 64) * LDW + scol) = av1;
        *reinterpret_cast<int4*>(sB + srow * LDW + scol)        = bv0;
        *reinterpret_cast<int4*>(sB + (srow + 64) * LDW + scol) = bv1;
        __syncthreads();
        bf16x8 af[4], bfv[4];
        #pragma unroll
        for (int i = 0; i < 4; ++i)
            af[i] = *reinterpret_cast<const bf16x8*>(sA + (wrow + i * 16 + lr) * LDW + quad * 8);
        #pragma unroll
        for (int j = 0; j < 4; ++j)
            bfv[j] = *reinterpret_cast<const bf16x8*>(sB + (wcol + j * 16 + lr) * LDW + quad * 8);
        #pragma unroll
        for (int i = 0; i < 4; ++i)
            #pragma unroll
            for (int j = 0; j < 4; ++j)
                acc[i][j] = __builtin_amdgcn_mfma_f32_16x16x32_bf16(af[i], bfv[j], acc[i][j], 0, 0, 0);
        __syncthreads();
    }

    #pragma unroll
    for (int i = 0; i < 4; ++i) {
        #pragma unroll
        for (int j = 0; j < 4; ++j) {
            #pragma unroll
            for (int r = 0; r < 4; ++r) {
                int row = m0 + wrow + i * 16 + quad * 4 + r;
                int col = n0 + wcol + j * 16 + lr;
                float val = acc[i][j][r];
                if (GELU) {
                    float x3 = val * val * val;
                    val = 0.5f * val * (1.f + tanhf(0.7978845608028654f * (val + 0.044715f * x3)));
                }
                size_t idx = (size_t)row * N + col;
                if (RESID) {
                    float rv = rf ? ((const float*)R)[idx + rOff]
                                  : b2f(((const unsigned short*)R)[idx + rOff]);
                    val += rv;
                }
                if (OUTF32) ((float*)C)[idx] = val;
                else        ((unsigned short*)C)[idx] = f2b(val);
            }
        }
    }
}

// ---------------- MFMA flash attention, paired 64-q tiles ------------------
// grid.x = NH*8 (NH = nb*NHEADS). Block = head x {qt=15-pr, qt=pr}: exactly
// 17 k-tile-units per block (perfect balance). blockIdx = pr*NH + head so all
// blocks of head h share blockIdx%8 -> same XCD under round-robin dispatch.
__global__ __launch_bounds__(256) void fattn_kernel(
        const unsigned short* __restrict__ q,
        const unsigned short* __restrict__ k,
        const unsigned short* __restrict__ v,
        int rs, unsigned short* __restrict__ ctx) {
    constexpr int VTP = 72;
    __shared__ unsigned short Vt[64 * VTP];
    __shared__ unsigned short Pl[4][16 * VTP];
    const int tid  = threadIdx.x;
    const int wave = tid >> 6, lane = tid & 63;
    const int quad = lane >> 4, lr = lane & 15;
    const int NH   = gridDim.x >> 3;
    const int head = blockIdx.x % NH;
    const int pr   = blockIdx.x / NH;          // 0..7
    const int bb   = head / NHEADS, hd = head % NHEADS;
    const size_t seqbase = (size_t)bb * SEQ;

    #pragma unroll
    for (int seg = 0; seg < 2; ++seg) {
        const int qt = seg == 0 ? (15 - pr) : pr;
        const int q0 = qt * 64 + wave * 16;

        bf16x8 aQ0, aQ1;
        {
            const unsigned short* qp = q + (seqbase + q0 + lr) * rs + hd * HDIM + quad * 8;
            aQ0 = *reinterpret_cast<const bf16x8*>(qp);
            aQ1 = *reinterpret_cast<const bf16x8*>(qp + 32);
        }

        f32x4 O[4];
        #pragma unroll
        for (int i = 0; i < 4; ++i) O[i] = (f32x4){0.f, 0.f, 0.f, 0.f};
        float mrow[4], lrow[4];
        #pragma unroll
        for (int r = 0; r < 4; ++r) { mrow[r] = -__builtin_inff(); lrow[r] = 0.f; }

        for (int kt = 0; kt <= qt; ++kt) {
            {   // stage V^T tile
                const int vrow = tid >> 2;
                const int vcol = (tid & 3) * 16;
                const unsigned short* vp = v + (seqbase + kt * 64 + vrow) * rs + hd * HDIM + vcol;
                union { int4 v4; unsigned short u[8]; } ua, ub;
                ua.v4 = *reinterpret_cast<const int4*>(vp);
                ub.v4 = *reinterpret_cast<const int4*>(vp + 8);
                #pragma unroll
                for (int e = 0; e < 8; ++e) Vt[(vcol + e) * VTP + vrow]     = ua.u[e];
                #pragma unroll
                for (int e = 0; e < 8; ++e) Vt[(vcol + 8 + e) * VTP + vrow] = ub.u[e];
            }
            __syncthreads();

            f32x4 S[4];
            #pragma unroll
            for (int sub = 0; sub < 4; ++sub) {
                const unsigned short* kp = k + (seqbase + kt * 64 + sub * 16 + lr) * rs + hd * HDIM + quad * 8;
                bf16x8 b0 = *reinterpret_cast<const bf16x8*>(kp);
                bf16x8 b1 = *reinterpret_cast<const bf16x8*>(kp + 32);
                f32x4 accS = (f32x4){0.f, 0.f, 0.f, 0.f};
                accS = __builtin_amdgcn_mfma_f32_16x16x32_bf16(aQ0, b0, accS, 0, 0, 0);
                accS = __builtin_amdgcn_mfma_f32_16x16x32_bf16(aQ1, b1, accS, 0, 0, 0);
                S[sub] = accS;
            }
            const bool diag = (kt == qt);
            #pragma unroll
            for (int sub = 0; sub < 4; ++sub) {
                const int kg = kt * 64 + sub * 16 + lr;
                #pragma unroll
                for (int r = 0; r < 4; ++r) {
                    float s = S[sub][r] * 0.125f;
                    if (diag && kg > q0 + quad * 4 + r) s = -__builtin_inff();
                    S[sub][r] = s;
                }
            }
            float mnew[4], alpha[4];
            #pragma unroll
            for (int r = 0; r < 4; ++r) {
                float mx = fmaxf(fmaxf(S[0][r], S[1][r]), fmaxf(S[2][r], S[3][r]));
                #pragma unroll
                for (int m = 1; m < 16; m <<= 1) mx = fmaxf(mx, __shfl_xor(mx, m));
                mnew[r]  = fmaxf(mrow[r], mx);
                alpha[r] = __expf(mrow[r] - mnew[r]);
                mrow[r]  = mnew[r];
            }
            float rsum[4] = {0.f, 0.f, 0.f, 0.f};
            #pragma unroll
            for (int sub = 0; sub < 4; ++sub)
                #pragma unroll
                for (int r = 0; r < 4; ++r) {
                    float p = __expf(S[sub][r] - mnew[r]);
                    S[sub][r] = p;
                    rsum[r] += p;
                }
            #pragma unroll
            for (int r = 0; r < 4; ++r) {
                float rs2 = rsum[r];
                #pragma unroll
                for (int m = 1; m < 16; m <<= 1) rs2 += __shfl_xor(rs2, m);
                lrow[r] = lrow[r] * alpha[r] + rs2;
            }
            #pragma unroll
            for (int d = 0; d < 4; ++d)
                #pragma unroll
                for (int r = 0; r < 4; ++r)
                    O[d][r] *= alpha[r];

            unsigned short* Pw = Pl[wave];
            #pragma unroll
            for (int sub = 0; sub < 4; ++sub)
                #pragma unroll
                for (int r = 0; r < 4; ++r)
                    Pw[(quad * 4 + r) * VTP + sub * 16 + lr] = f2b(S[sub][r]);
            __syncthreads();

            #pragma unroll
            for (int c = 0; c < 2; ++c) {
                bf16x8 aP = *reinterpret_cast<const bf16x8*>(&Pw[lr * VTP + c * 32 + quad * 8]);
                #pragma unroll
                for (int d = 0; d < 4; ++d) {
                    bf16x8 bV = *reinterpret_cast<const bf16x8*>(&Vt[(d * 16 + lr) * VTP + c * 32 + quad * 8]);
                    O[d] = __builtin_amdgcn_mfma_f32_16x16x32_bf16(aP, bV, O[d], 0, 0, 0);
                }
            }
            __syncthreads();
        }

        #pragma unroll
        for (int r = 0; r < 4; ++r) {
            const float rinv = 1.f / lrow[r];
            const int qg = q0 + quad * 4 + r;
            unsigned short* crow = ctx + (seqbase + qg) * EMB + hd * HDIM;
            #pragma unroll
            for (int d = 0; d < 4; ++d)
                crow[d * 16 + lr] = f2b(O[d][r] * rinv);
        }
    }
}

// ---------------------------------------------------------------------------
extern "C" void kernel_launch(void* const* d_in, const int* in_sizes, int n_in,
                              void* d_out, int out_size, void* d_ws, size_t ws_size,
                              hipStream_t stream) {
    const void* x  = d_in[0];
    const void* wq = d_in[1], *wk = d_in[2], *wv = d_in[3], *wo = d_in[4];
    const void* w1 = d_in[5], *w2 = d_in[6];
    const void* g1 = d_in[7], *s1 = d_in[8], *g2 = d_in[9], *s2 = d_in[10];
    char* ws = (char*)d_ws;
    dim3 blk(256);

    int* F = (int*)ws;
    {
        DetectArgs da;
        for (int i = 0; i < 11; ++i) { da.p[i] = (const unsigned short*)d_in[i]; da.n[i] = in_sizes[i]; }
        detect_all<<<11, blk, 0, stream>>>(da, F);
    }

    const size_t SZE = (size_t)MROWS * EMB;
    const size_t SZB = SZE * 2;
    unsigned short* base = (unsigned short*)(ws + 256);
    dim3 g768(MROWS / 128, EMB / 128);

    const size_t FULLB = 256 + 2ULL * (2 * W4E) + 2ULL * (4 * W2E)
                       + 2ULL * ((size_t)MROWS * 2304) + 2 * SZB
                       + 2ULL * ((size_t)MROWS * FFN);   // = 127,402,240 B

    if (ws_size >= FULLB) {
        // ---- full path: fused QKV, paired flash, full-width FFN ----
        unsigned short* w1b   = base;
        unsigned short* w2b   = w1b + W4E;
        unsigned short* wqkvb = w2b + W4E;
        unsigned short* wob   = wqkvb + 3 * W2E;
        unsigned short* P     = wob + W2E;
        unsigned short* B0    = P + (size_t)MROWS * 2304;
        unsigned short* B1    = B0 + SZE;
        unsigned short* G     = B1 + SZE;

        {
            CvtArgs ca;
            ca.src[0] = wq; ca.src[1] = wk; ca.src[2] = wv;
            ca.src[3] = wo; ca.src[4] = w1; ca.src[5] = w2;
            ca.dst[0] = wqkvb; ca.dst[1] = wqkvb + W2E; ca.dst[2] = wqkvb + 2 * W2E;
            ca.dst[3] = wob;   ca.dst[4] = w1b;         ca.dst[5] = w2b;
            ca.n[0] = ca.n[1] = ca.n[2] = ca.n[3] = W2E; ca.n[4] = ca.n[5] = W4E;
            int off = 0;
            for (int s = 0; s < 6; ++s) { ca.blkoff[s] = off; off += ca.n[s] / 1024; }
            ca.blkoff[6] = off;
            ca.F = F;
            ca.fidx[0] = 1; ca.fidx[1] = 2; ca.fidx[2] = 3;
            ca.fidx[3] = 4; ca.fidx[4] = 5; ca.fidx[5] = 6;
            cvt_weights<<<off, blk, 0, stream>>>(ca);
        }

        ln_kernel<<<MROWS / 4, blk, 0, stream>>>(x, F+0, g1, F+7, s1, F+8, B1);
        dim3 gqkv(MROWS / 128, 2304 / 128);
        gemm_lds<false, false, false><<<gqkv, blk, 0, stream>>>(B1, wqkvb, nullptr, nullptr, 0, P, MROWS, 2304, EMB);
        fattn_kernel<<<BATCH * NHEADS * 8, blk, 0, stream>>>(P, P + 768, P + 1536, 2304, B0);
        gemm_lds<false, true, false><<<g768, blk, 0, stream>>>(B0, wob, x, F+0, 0, B1, MROWS, EMB, EMB);
        ln_kernel<<<MROWS / 4, blk, 0, stream>>>(B1, nullptr, g2, F+9, s2, F+10, B0);
        dim3 gffn1(MROWS / 128, FFN / 128);
        gemm_lds<true, false, false><<<gffn1, blk, 0, stream>>>(B0, w1b, nullptr, nullptr, 0, G, MROWS, FFN, EMB);
        gemm_lds<false, true, true><<<g768, blk, 0, stream>>>(G, w2b, B1, nullptr, 0, d_out, MROWS, EMB, FFN);
    } else if (ws_size >= 256 + 7 * SZB) {
        // ---- r9 optimized path (77 MB) ----
        unsigned short* wqb = base;
        unsigned short* wkb = wqb + W2E;
        unsigned short* wvb = wkb + W2E;
        unsigned short* wob = wvb + W2E;
        unsigned short* w1b = wob + W2E;
        unsigned short* w2b = w1b + W4E;
        unsigned short* B0  = w2b + W4E;
        unsigned short* B1  = B0 + SZE;
        unsigned short* B2  = B1 + SZE;
        unsigned short* B3  = B2 + SZE;

        cvt_adapt<<<W2E / 1024, blk, 0, stream>>>(wq, wqb, W2E, F + 1);
        cvt_adapt<<<W2E / 1024, blk, 0, stream>>>(wk, wkb, W2E, F + 2);
        cvt_adapt<<<W2E / 1024, blk, 0, stream>>>(wv, wvb, W2E, F + 3);
        cvt_adapt<<<W2E / 1024, blk, 0, stream>>>(wo, wob, W2E, F + 4);
        cvt_adapt<<<W4E / 1024, blk, 0, stream>>>(w1, w1b, W4E, F + 5);
        cvt_adapt<<<W4E / 1024, blk, 0, stream>>>(w2, w2b, W4E, F + 6);

        ln_kernel<<<MROWS / 4, blk, 0, stream>>>(x, F+0, g1, F+7, s1, F+8, B0);
        gemm_lds<false, false, false><<<g768, blk, 0, stream>>>(B0, wqb, nullptr, nullptr, 0, B1, MROWS, EMB, EMB);
        gemm_lds<false, false, false><<<g768, blk, 0, stream>>>(B0, wkb, nullptr, nullptr, 0, B2, MROWS, EMB, EMB);
        gemm_lds<false, false, false><<<g768, blk, 0, stream>>>(B0, wvb, nullptr, nullptr, 0, B3, MROWS, EMB, EMB);
        fattn_kernel<<<BATCH * NHEADS * 8, blk, 0, stream>>>(B1, B2, B3, EMB, B0);
        gemm_lds<false, true, false><<<g768, blk, 0, stream>>>(B0, wob, x, F+0, 0, B1, MROWS, EMB, EMB);
        ln_kernel<<<MROWS / 4, blk, 0, stream>>>(B1, nullptr, g2, F+9, s2, F+10, B2);
        dim3 c3072(4096 / 128, FFN / 128), c768(4096 / 128, EMB / 128);
        for (int c = 0; c < 2; ++c) {
            const size_t r0 = (size_t)c * 4096;
            gemm_lds<true, false, false><<<c3072, blk, 0, stream>>>(B2 + r0 * EMB, w1b, nullptr, nullptr, 0, B3, 4096, FFN, EMB);
            gemm_lds<false, true, true><<<c768, blk, 0, stream>>>(B3, w2b, B1 + r0 * EMB, nullptr, 0, (float*)d_out + r0 * EMB, 4096, EMB, FFN);
        }
    } else if (ws_size >= 256 + 4 * SZB) {
        // ---- fallback tier M ----
        unsigned short* B0 = base;
        unsigned short* B1 = B0 + SZE;
        unsigned short* B2 = B1 + SZE;
        unsigned short* B3 = B2 + SZE;
        ln_kernel<<<MROWS / 4, blk, 0, stream>>>(x, F+0, g1, F+7, s1, F+8, B0);
        gemm_bt<false, false, false><<<g768, blk, 0, stream>>>(B0, wq, F+1, nullptr, nullptr, 0, B1, MROWS, EMB, EMB);
        gemm_bt<false, false, false><<<g768, blk, 0, stream>>>(B0, wk, F+2, nullptr, nullptr, 0, B2, MROWS, EMB, EMB);
        gemm_bt<false, false, false><<<g768, blk, 0, stream>>>(B0, wv, F+3, nullptr, nullptr, 0, B3, MROWS, EMB, EMB);
        fattn_kernel<<<BATCH * NHEADS * 8, blk, 0, stream>>>(B1, B2, B3, EMB, B0);
        gemm_bt<false, true, false><<<g768, blk, 0, stream>>>(B0, wo, F+4, x, F+0, 0, B1, MROWS, EMB, EMB);
        ln_kernel<<<MROWS / 4, blk, 0, stream>>>(B1, nullptr, g2, F+9, s2, F+10, B2);
        dim3 c3072(2048 / 128, FFN / 128), c768(2048 / 128, EMB / 128);
        for (int c = 0; c < 4; ++c) {
            const size_t r0 = (size_t)c * 2048;
            gemm_bt<true, false, false><<<c3072, blk, 0, stream>>>(B2 + r0 * EMB, w1, F+5, nullptr, nullptr, 0, B3, 2048, FFN, EMB);
            gemm_bt<false, true, true><<<c768, blk, 0, stream>>>(B3, w2, F+6, B1 + r0 * EMB, nullptr, 0, (float*)d_out + r0 * EMB, 2048, EMB, FFN);
        }
    } else {
        // ---- fallback tier B ----
        unsigned short* hlow = (unsigned short*)d_out;
        unsigned short* x2up = (unsigned short*)d_out + SZE;
        unsigned short* wsQ = base;
        unsigned short* wsK = wsQ + (size_t)1024 * EMB;
        unsigned short* wsV = wsK + (size_t)1024 * EMB;
        unsigned short* wsC = wsV + (size_t)1024 * EMB;
        ln_kernel<<<MROWS / 4, blk, 0, stream>>>(x, F+0, g1, F+7, s1, F+8, hlow);
        dim3 q768(1024 / 128, EMB / 128);
        for (int grp = 0; grp < BATCH; ++grp) {
            const size_t r0 = (size_t)grp * 1024;
            gemm_bt<false, false, false><<<q768, blk, 0, stream>>>(hlow + r0 * EMB, wq, F+1, nullptr, nullptr, 0, wsQ, 1024, EMB, EMB);
            gemm_bt<false, false, false><<<q768, blk, 0, stream>>>(hlow + r0 * EMB, wk, F+2, nullptr, nullptr, 0, wsK, 1024, EMB, EMB);
            gemm_bt<false, false, false><<<q768, blk, 0, stream>>>(hlow + r0 * EMB, wv, F+3, nullptr, nullptr, 0, wsV, 1024, EMB, EMB);
            fattn_kernel<<<1 * NHEADS * 8, blk, 0, stream>>>(wsQ, wsK, wsV, EMB, wsC);
            gemm_bt<false, true, false><<<q768, blk, 0, stream>>>(wsC, wo, F+4, x, F+0, r0 * EMB, x2up + r0 * EMB, 1024, EMB, EMB);
        }
        unsigned short* xb = base;
        unsigned short* h2 = xb + (size_t)1024 * EMB;
        unsigned short* gb = h2 + (size_t)1024 * EMB;
        dim3 f3072(1024 / 128, FFN / 128), f768(1024 / 128, EMB / 128);
        for (int c = 0; c < BATCH; ++c) {
            const size_t r0 = (size_t)c * 1024;
            hipMemcpyAsync(xb, x2up + r0 * EMB, (size_t)1024 * EMB * 2,
                           hipMemcpyDeviceToDevice, stream);
            ln_kernel<<<1024 / 4, blk, 0, stream>>>(xb, nullptr, g2, F+9, s2, F+10, h2);
            gemm_bt<true, false, false><<<f3072, blk, 0, stream>>>(h2, w1, F+5, nullptr, nullptr, 0, gb, 1024, FFN, EMB);
            gemm_bt<false, true, true><<<f768, blk, 0, stream>>>(gb, w2, F+6, xb, nullptr, 0, (float*)d_out + r0 * EMB, 1024, EMB, FFN);
        }
    }
}

// Round 12
// 440.156 us; speedup vs baseline: 5.8688x; 1.0251x over previous
//
#include <hip/hip_runtime.h>
#include <hip/hip_bf16.h>
#include <cstdint>

#define EMB    768
#define NHEADS 12
#define HDIM   64
#define SEQ    1024
#define BATCH  8
#define MROWS  (BATCH*SEQ)   /* 8192 */
#define FFN    3072
#define W2E    (EMB*EMB)     /* 589824 */
#define W4E    (FFN*EMB)     /* 2359296 */

typedef __bf16 bf16_t;
typedef bf16_t bf16x8 __attribute__((ext_vector_type(8)));
typedef float  f32x4  __attribute__((ext_vector_type(4)));

__device__ __forceinline__ float b2f(unsigned short u) {
    union { unsigned int i; float f; } t; t.i = ((unsigned int)u) << 16; return t.f;
}
__device__ __forceinline__ unsigned short f2b(float f) {
    union { float f; unsigned int i; } t; t.f = f;
    unsigned int lsb = (t.i >> 16) & 1u;
    t.i += 0x7fffu + lsb;
    return (unsigned short)(t.i >> 16);
}

#if defined(__has_builtin)
#if __has_builtin(__builtin_amdgcn_global_load_lds)
#define HAS_GLL 1
#endif
#endif
#ifndef HAS_GLL
#define HAS_GLL 0
#endif

__device__ __forceinline__ void gll16(const unsigned short* g, unsigned short* lds_wave_base) {
#if HAS_GLL
    __builtin_amdgcn_global_load_lds(
        (const __attribute__((address_space(1))) unsigned int*)g,
        (__attribute__((address_space(3))) unsigned int*)lds_wave_base, 16, 0, 0);
#endif
}

__device__ __forceinline__ int4 load8(const void* src, size_t eoff, bool f32) {
    if (f32) {
        const float4* p = reinterpret_cast<const float4*>((const float*)src + eoff);
        float4 a = p[0], b = p[1];
        union { unsigned short u[8]; int4 v; } r;
        r.u[0] = f2b(a.x); r.u[1] = f2b(a.y); r.u[2] = f2b(a.z); r.u[3] = f2b(a.w);
        r.u[4] = f2b(b.x); r.u[5] = f2b(b.y); r.u[6] = f2b(b.z); r.u[7] = f2b(b.w);
        return r.v;
    }
    return *reinterpret_cast<const int4*>((const unsigned short*)src + eoff);
}
__device__ __forceinline__ float4 load4f(const void* src, size_t eoff, bool f32) {
    if (f32) return *reinterpret_cast<const float4*>((const float*)src + eoff);
    ushort4 u = *reinterpret_cast<const ushort4*>((const unsigned short*)src + eoff);
    float4 r; r.x = b2f(u.x); r.y = b2f(u.y); r.z = b2f(u.z); r.w = b2f(u.w);
    return r;
}

// ---------------- dtype probe: one block per input ------------------------
struct DetectArgs { const unsigned short* p[11]; int n[11]; };

__global__ __launch_bounds__(256) void detect_all(DetectArgs a, int* __restrict__ flags) {
    __shared__ int cnt;
    if (threadIdx.x == 0) cnt = 0;
    __syncthreads();
    const unsigned short* src = a.p[blockIdx.x];
    int npairs = a.n[blockIdx.x] / 2;
    if (npairs > 4096) npairs = 4096;
    int local = 0;
    for (int p = threadIdx.x; p < npairs; p += 256) {
        unsigned short u0 = src[2 * p], u1 = src[2 * p + 1];
        int e0 = (u0 >> 7) & 0xFF;
        bool insane0 = (e0 == 0xFF) || (u0 != 0 && (e0 < 96 || e0 > 159));
        bool zpat    = (u0 == 0 && u1 != 0);
        if (insane0 || zpat) ++local;
    }
    atomicAdd(&cnt, local);
    __syncthreads();
    if (threadIdx.x == 0) flags[blockIdx.x] = (cnt * 8 > npairs) ? 1 : 0;
}

// ---------------- adaptive convert (single buffer; middle tier) -----------
__global__ __launch_bounds__(256) void cvt_adapt(
        const void* __restrict__ src, unsigned short* __restrict__ dst,
        int n, const int* __restrict__ flag) {
    int i = blockIdx.x * 256 + threadIdx.x;
    if (i * 4 >= n) return;
    if (*flag) {
        float4 f = reinterpret_cast<const float4*>(src)[i];
        ushort4 o;
        o.x = f2b(f.x); o.y = f2b(f.y); o.z = f2b(f.z); o.w = f2b(f.w);
        reinterpret_cast<ushort4*>(dst)[i] = o;
    } else {
        reinterpret_cast<ushort4*>(dst)[i] = reinterpret_cast<const ushort4*>(src)[i];
    }
}

// ---------------- fused weight convert: all 6 weights, one launch ---------
struct CvtArgs {
    const void* src[6];
    unsigned short* dst[6];
    int n[6];
    int blkoff[7];
    const int* F;
    int fidx[6];
};
__global__ __launch_bounds__(256) void cvt_weights(CvtArgs a) {
    int b = blockIdx.x, seg = 0;
    #pragma unroll
    for (int s = 0; s < 6; ++s) if (b >= a.blkoff[s + 1]) seg = s + 1;
    int i = (b - a.blkoff[seg]) * 256 + threadIdx.x;
    if (i * 4 >= a.n[seg]) return;
    if (a.F[a.fidx[seg]]) {
        float4 f = reinterpret_cast<const float4*>(a.src[seg])[i];
        ushort4 o;
        o.x = f2b(f.x); o.y = f2b(f.y); o.z = f2b(f.z); o.w = f2b(f.w);
        reinterpret_cast<ushort4*>(a.dst[seg])[i] = o;
    } else {
        reinterpret_cast<ushort4*>(a.dst[seg])[i] =
            reinterpret_cast<const ushort4*>(a.src[seg])[i];
    }
}

// ---------------- split-K reduce: out = P0 + P1 + resid (fp32 out) --------
__global__ __launch_bounds__(256) void reduce2_kernel(
        const float* __restrict__ P, const unsigned short* __restrict__ resid,
        float* __restrict__ out, int n4) {
    int i = blockIdx.x * 256 + threadIdx.x;
    if (i >= n4) return;
    float4 a = reinterpret_cast<const float4*>(P)[i];
    float4 b = reinterpret_cast<const float4*>(P + (size_t)MROWS * EMB)[i];
    ushort4 r = reinterpret_cast<const ushort4*>(resid)[i];
    float4 o;
    o.x = a.x + b.x + b2f(r.x);
    o.y = a.y + b.y + b2f(r.y);
    o.z = a.z + b.z + b2f(r.z);
    o.w = a.w + b.w + b2f(r.w);
    reinterpret_cast<float4*>(out)[i] = o;
}

// ---------------- LayerNorm: one wave per row; bf16 out -------------------
__global__ __launch_bounds__(256) void ln_kernel(
        const void* __restrict__ x,     const int* __restrict__ fx,
        const void* __restrict__ scale, const int* __restrict__ fsc,
        const void* __restrict__ shift, const int* __restrict__ fsh,
        unsigned short* __restrict__ out) {
    const bool xf = fx && *fx, scf = fsc && *fsc, shf = fsh && *fsh;
    int wave = threadIdx.x >> 6;
    int lane = threadIdx.x & 63;
    int row  = blockIdx.x * 4 + wave;
    const size_t rbase = (size_t)row * EMB;
    float v[12];
    float s = 0.f, s2 = 0.f;
    #pragma unroll
    for (int i = 0; i < 3; ++i) {
        float4 a = load4f(x, rbase + i * 256 + lane * 4, xf);
        v[i*4+0] = a.x; v[i*4+1] = a.y; v[i*4+2] = a.z; v[i*4+3] = a.w;
        s  += a.x + a.y + a.z + a.w;
        s2 += a.x*a.x + a.y*a.y + a.z*a.z + a.w*a.w;
    }
    #pragma unroll
    for (int off = 1; off < 64; off <<= 1) {
        s  += __shfl_xor(s,  off);
        s2 += __shfl_xor(s2, off);
    }
    float mean = s * (1.f / EMB);
    float var  = fmaxf(s2 * (1.f / EMB) - mean * mean, 0.f);
    float rstd = rsqrtf(var + 1e-5f);
    unsigned short* orow = out + rbase;
    #pragma unroll
    for (int i = 0; i < 3; ++i) {
        float4 sc = load4f(scale, i * 256 + lane * 4, scf);
        float4 sh = load4f(shift, i * 256 + lane * 4, shf);
        ushort4 o;
        o.x = f2b((v[i*4+0] - mean) * rstd * sc.x + sh.x);
        o.y = f2b((v[i*4+1] - mean) * rstd * sc.y + sh.y);
        o.z = f2b((v[i*4+2] - mean) * rstd * sc.z + sh.z);
        o.w = f2b((v[i*4+3] - mean) * rstd * sc.w + sh.w);
        *reinterpret_cast<ushort4*>(orow + i * 256 + lane * 4) = o;
    }
}

// ---------------- gemm_lds: pure-bf16 GEMM with async LDS staging ---------
// C[M,N] = A[M,K-slice] @ W[N,K-slice]^T. lda/ldw = row strides (elements).
// Split-K: blockIdx.z selects chunk z (A/W offset z*K; fp32 C offset z*M*N).
template<bool GELU, bool RESID, bool OUTF32>
__global__ __launch_bounds__(256) void gemm_lds(
        const unsigned short* __restrict__ A,
        const unsigned short* __restrict__ W,
        const void* R, const int* __restrict__ fR, size_t rOff,
        void* C, int M, int N, int K, int lda, int ldw) {
    constexpr int BK = 32;
    __shared__ __align__(16) unsigned short sA[128 * BK];
    __shared__ __align__(16) unsigned short sB[128 * BK];
    const int m0 = blockIdx.x * 128, n0 = blockIdx.y * 128;
    const int kz = blockIdx.z;
    const int t = threadIdx.x, wave = t >> 6, lane = t & 63;
    const int wrow = (wave >> 1) * 64, wcol = (wave & 1) * 64;
    const int quad = lane >> 4, lr = lane & 15;
    const int r0 = t >> 2;
    const int c0 = (t & 3) * 8;
    const bool rf = fR && *fR;

    A += (size_t)kz * K;
    W += (size_t)kz * K;

    f32x4 acc[4][4];
    #pragma unroll
    for (int i = 0; i < 4; ++i)
        #pragma unroll
        for (int j = 0; j < 4; ++j)
            acc[i][j] = (f32x4){0.f, 0.f, 0.f, 0.f};

    const unsigned short* gA0 = A + (size_t)(m0 + r0) * lda + c0;
    const unsigned short* gA1 = A + (size_t)(m0 + 64 + r0) * lda + c0;
    const unsigned short* gB0 = W + (size_t)(n0 + r0) * ldw + c0;
    const unsigned short* gB1 = W + (size_t)(n0 + 64 + r0) * ldw + c0;
    unsigned short* lA0 = sA + wave * 512;
    unsigned short* lA1 = sA + 2048 + wave * 512;
    unsigned short* lB0 = sB + wave * 512;
    unsigned short* lB1 = sB + 2048 + wave * 512;

    for (int k0 = 0; k0 < K; k0 += BK) {
#if HAS_GLL
        gll16(gA0 + k0, lA0);
        gll16(gA1 + k0, lA1);
        gll16(gB0 + k0, lB0);
        gll16(gB1 + k0, lB1);
#else
        *reinterpret_cast<int4*>(sA + t * 8)        = *reinterpret_cast<const int4*>(gA0 + k0);
        *reinterpret_cast<int4*>(sA + 2048 + t * 8) = *reinterpret_cast<const int4*>(gA1 + k0);
        *reinterpret_cast<int4*>(sB + t * 8)        = *reinterpret_cast<const int4*>(gB0 + k0);
        *reinterpret_cast<int4*>(sB + 2048 + t * 8) = *reinterpret_cast<const int4*>(gB1 + k0);
#endif
        __syncthreads();
        bf16x8 af[4], bfv[4];
        #pragma unroll
        for (int i = 0; i < 4; ++i)
            af[i] = *reinterpret_cast<const bf16x8*>(sA + (wrow + i * 16 + lr) * BK + quad * 8);
        #pragma unroll
        for (int j = 0; j < 4; ++j)
            bfv[j] = *reinterpret_cast<const bf16x8*>(sB + (wcol + j * 16 + lr) * BK + quad * 8);
        #pragma unroll
        for (int i = 0; i < 4; ++i)
            #pragma unroll
            for (int j = 0; j < 4; ++j)
                acc[i][j] = __builtin_amdgcn_mfma_f32_16x16x32_bf16(af[i], bfv[j], acc[i][j], 0, 0, 0);
        __syncthreads();
    }

    float* Cf = (float*)C + (size_t)kz * M * N;   // kz=0 unless split launch
    #pragma unroll
    for (int i = 0; i < 4; ++i) {
        #pragma unroll
        for (int j = 0; j < 4; ++j) {
            #pragma unroll
            for (int r = 0; r < 4; ++r) {
                int row = m0 + wrow + i * 16 + quad * 4 + r;
                int col = n0 + wcol + j * 16 + lr;
                float val = acc[i][j][r];
                if (GELU) {
                    float x3 = val * val * val;
                    val = 0.5f * val * (1.f + tanhf(0.7978845608028654f * (val + 0.044715f * x3)));
                }
                size_t idx = (size_t)row * N + col;
                if (RESID) {
                    float rv = rf ? ((const float*)R)[idx + rOff]
                                  : b2f(((const unsigned short*)R)[idx + rOff]);
                    val += rv;
                }
                if (OUTF32) Cf[idx] = val;
                else        ((unsigned short*)C)[idx] = f2b(val);
            }
        }
    }
}

// ---------------- legacy flagged GEMM (fallback tiers only) ---------------
template<bool GELU, bool RESID, bool OUTF32>
__global__ __launch_bounds__(256) void gemm_bt(
        const unsigned short* __restrict__ A,
        const void* __restrict__ W, const int* __restrict__ fW,
        const void* R, const int* __restrict__ fR, size_t rOff,
        void* C,
        int M, int N, int K) {
    const bool wf = fW && *fW;
    const bool rf = fR && *fR;
    constexpr int BK = 32, PAD = 8, LDW = BK + PAD;
    __shared__ __align__(16) unsigned short sA[128 * LDW];
    __shared__ __align__(16) unsigned short sB[128 * LDW];
    const int m0 = blockIdx.x * 128;
    const int n0 = blockIdx.y * 128;
    const int t    = threadIdx.x;
    const int wave = t >> 6, lane = t & 63;
    const int wrow = (wave >> 1) * 64, wcol = (wave & 1) * 64;
    const int quad = lane >> 4, lr = lane & 15;
    const int srow = t >> 2, scol = (t & 3) * 8;

    f32x4 acc[4][4];
    #pragma unroll
    for (int i = 0; i < 4; ++i)
        #pragma unroll
        for (int j = 0; j < 4; ++j)
            acc[i][j] = (f32x4){0.f, 0.f, 0.f, 0.f};

    const size_t aBase = (size_t)(m0 + srow) * K + scol;
    const size_t bBase = (size_t)(n0 + srow) * K + scol;

    for (int k0 = 0; k0 < K; k0 += BK) {
        int4 av0 = *reinterpret_cast<const int4*>(A + aBase + k0);
        int4 av1 = *reinterpret_cast<const int4*>(A + aBase + (size_t)64 * K + k0);
        int4 bv0 = load8(W, bBase + k0, wf);
        int4 bv1 = load8(W, bBase + (size_t)64 * K + k0, wf);
        *reinterpret_cast<int4*>(sA + srow * LDW + scol)        = av0;
        *reinterpret_cast<int4*>(sA + (srow + 64) * LDW + scol) = av1;
        *reinterpret_cast<int4*>(sB + srow * LDW + scol)        = bv0;
        *reinterpret_cast<int4*>(sB + (srow + 64) * LDW + scol) = bv1;
        __syncthreads();
        bf16x8 af[4], bfv[4];
        #pragma unroll
        for (int i = 0; i < 4; ++i)
            af[i] = *reinterpret_cast<const bf16x8*>(sA + (wrow + i * 16 + lr) * LDW + quad * 8);
        #pragma unroll
        for (int j = 0; j < 4; ++j)
            bfv[j] = *reinterpret_cast<const bf16x8*>(sB + (wcol + j * 16 + lr) * LDW + quad * 8);
        #pragma unroll
        for (int i = 0; i < 4; ++i)
            #pragma unroll
            for (int j = 0; j < 4; ++j)
                acc[i][j] = __builtin_amdgcn_mfma_f32_16x16x32_bf16(af[i], bfv[j], acc[i][j], 0, 0, 0);
        __syncthreads();
    }

    #pragma unroll
    for (int i = 0; i < 4; ++i) {
        #pragma unroll
        for (int j = 0; j < 4; ++j) {
            #pragma unroll
            for (int r = 0; r < 4; ++r) {
                int row = m0 + wrow + i * 16 + quad * 4 + r;
                int col = n0 + wcol + j * 16 + lr;
                float val = acc[i][j][r];
                if (GELU) {
                    float x3 = val * val * val;
                    val = 0.5f * val * (1.f + tanhf(0.7978845608028654f * (val + 0.044715f * x3)));
                }
                size_t idx = (size_t)row * N + col;
                if (RESID) {
                    float rv = rf ? ((const float*)R)[idx + rOff]
                                  : b2f(((const unsigned short*)R)[idx + rOff]);
                    val += rv;
                }
                if (OUTF32) ((float*)C)[idx] = val;
                else        ((unsigned short*)C)[idx] = f2b(val);
            }
        }
    }
}

// ---------------- MFMA flash attention, paired 64-q tiles ------------------
__global__ __launch_bounds__(256) void fattn_kernel(
        const unsigned short* __restrict__ q,
        const unsigned short* __restrict__ k,
        const unsigned short* __restrict__ v,
        int rs, unsigned short* __restrict__ ctx) {
    constexpr int VTP = 72;
    __shared__ unsigned short Vt[64 * VTP];
    __shared__ unsigned short Pl[4][16 * VTP];
    const int tid  = threadIdx.x;
    const int wave = tid >> 6, lane = tid & 63;
    const int quad = lane >> 4, lr = lane & 15;
    const int NH   = gridDim.x >> 3;
    const int head = blockIdx.x % NH;
    const int pr   = blockIdx.x / NH;
    const int bb   = head / NHEADS, hd = head % NHEADS;
    const size_t seqbase = (size_t)bb * SEQ;

    #pragma unroll
    for (int seg = 0; seg < 2; ++seg) {
        const int qt = seg == 0 ? (15 - pr) : pr;
        const int q0 = qt * 64 + wave * 16;

        bf16x8 aQ0, aQ1;
        {
            const unsigned short* qp = q + (seqbase + q0 + lr) * rs + hd * HDIM + quad * 8;
            aQ0 = *reinterpret_cast<const bf16x8*>(qp);
            aQ1 = *reinterpret_cast<const bf16x8*>(qp + 32);
        }

        f32x4 O[4];
        #pragma unroll
        for (int i = 0; i < 4; ++i) O[i] = (f32x4){0.f, 0.f, 0.f, 0.f};
        float mrow[4], lrow[4];
        #pragma unroll
        for (int r = 0; r < 4; ++r) { mrow[r] = -__builtin_inff(); lrow[r] = 0.f; }

        for (int kt = 0; kt <= qt; ++kt) {
            {
                const int vrow = tid >> 2;
                const int vcol = (tid & 3) * 16;
                const unsigned short* vp = v + (seqbase + kt * 64 + vrow) * rs + hd * HDIM + vcol;
                union { int4 v4; unsigned short u[8]; } ua, ub;
                ua.v4 = *reinterpret_cast<const int4*>(vp);
                ub.v4 = *reinterpret_cast<const int4*>(vp + 8);
                #pragma unroll
                for (int e = 0; e < 8; ++e) Vt[(vcol + e) * VTP + vrow]     = ua.u[e];
                #pragma unroll
                for (int e = 0; e < 8; ++e) Vt[(vcol + 8 + e) * VTP + vrow] = ub.u[e];
            }
            __syncthreads();

            f32x4 S[4];
            #pragma unroll
            for (int sub = 0; sub < 4; ++sub) {
                const unsigned short* kp = k + (seqbase + kt * 64 + sub * 16 + lr) * rs + hd * HDIM + quad * 8;
                bf16x8 b0 = *reinterpret_cast<const bf16x8*>(kp);
                bf16x8 b1 = *reinterpret_cast<const bf16x8*>(kp + 32);
                f32x4 accS = (f32x4){0.f, 0.f, 0.f, 0.f};
                accS = __builtin_amdgcn_mfma_f32_16x16x32_bf16(aQ0, b0, accS, 0, 0, 0);
                accS = __builtin_amdgcn_mfma_f32_16x16x32_bf16(aQ1, b1, accS, 0, 0, 0);
                S[sub] = accS;
            }
            const bool diag = (kt == qt);
            #pragma unroll
            for (int sub = 0; sub < 4; ++sub) {
                const int kg = kt * 64 + sub * 16 + lr;
                #pragma unroll
                for (int r = 0; r < 4; ++r) {
                    float s = S[sub][r] * 0.125f;
                    if (diag && kg > q0 + quad * 4 + r) s = -__builtin_inff();
                    S[sub][r] = s;
                }
            }
            float mnew[4], alpha[4];
            #pragma unroll
            for (int r = 0; r < 4; ++r) {
                float mx = fmaxf(fmaxf(S[0][r], S[1][r]), fmaxf(S[2][r], S[3][r]));
                #pragma unroll
                for (int m = 1; m < 16; m <<= 1) mx = fmaxf(mx, __shfl_xor(mx, m));
                mnew[r]  = fmaxf(mrow[r], mx);
                alpha[r] = __expf(mrow[r] - mnew[r]);
                mrow[r]  = mnew[r];
            }
            float rsum[4] = {0.f, 0.f, 0.f, 0.f};
            #pragma unroll
            for (int sub = 0; sub < 4; ++sub)
                #pragma unroll
                for (int r = 0; r < 4; ++r) {
                    float p = __expf(S[sub][r] - mnew[r]);
                    S[sub][r] = p;
                    rsum[r] += p;
                }
            #pragma unroll
            for (int r = 0; r < 4; ++r) {
                float rs2 = rsum[r];
                #pragma unroll
                for (int m = 1; m < 16; m <<= 1) rs2 += __shfl_xor(rs2, m);
                lrow[r] = lrow[r] * alpha[r] + rs2;
            }
            #pragma unroll
            for (int d = 0; d < 4; ++d)
                #pragma unroll
                for (int r = 0; r < 4; ++r)
                    O[d][r] *= alpha[r];

            unsigned short* Pw = Pl[wave];
            #pragma unroll
            for (int sub = 0; sub < 4; ++sub)
                #pragma unroll
                for (int r = 0; r < 4; ++r)
                    Pw[(quad * 4 + r) * VTP + sub * 16 + lr] = f2b(S[sub][r]);
            __syncthreads();

            #pragma unroll
            for (int c = 0; c < 2; ++c) {
                bf16x8 aP = *reinterpret_cast<const bf16x8*>(&Pw[lr * VTP + c * 32 + quad * 8]);
                #pragma unroll
                for (int d = 0; d < 4; ++d) {
                    bf16x8 bV = *reinterpret_cast<const bf16x8*>(&Vt[(d * 16 + lr) * VTP + c * 32 + quad * 8]);
                    O[d] = __builtin_amdgcn_mfma_f32_16x16x32_bf16(aP, bV, O[d], 0, 0, 0);
                }
            }
            __syncthreads();
        }

        #pragma unroll
        for (int r = 0; r < 4; ++r) {
            const float rinv = 1.f / lrow[r];
            const int qg = q0 + quad * 4 + r;
            unsigned short* crow = ctx + (seqbase + qg) * EMB + hd * HDIM;
            #pragma unroll
            for (int d = 0; d < 4; ++d)
                crow[d * 16 + lr] = f2b(O[d][r] * rinv);
        }
    }
}

// ---------------------------------------------------------------------------
extern "C" void kernel_launch(void* const* d_in, const int* in_sizes, int n_in,
                              void* d_out, int out_size, void* d_ws, size_t ws_size,
                              hipStream_t stream) {
    const void* x  = d_in[0];
    const void* wq = d_in[1], *wk = d_in[2], *wv = d_in[3], *wo = d_in[4];
    const void* w1 = d_in[5], *w2 = d_in[6];
    const void* g1 = d_in[7], *s1 = d_in[8], *g2 = d_in[9], *s2 = d_in[10];
    char* ws = (char*)d_ws;
    dim3 blk(256);

    int* F = (int*)ws;
    {
        DetectArgs da;
        for (int i = 0; i < 11; ++i) { da.p[i] = (const unsigned short*)d_in[i]; da.n[i] = in_sizes[i]; }
        detect_all<<<11, blk, 0, stream>>>(da, F);
    }

    const size_t SZE = (size_t)MROWS * EMB;
    const size_t SZB = SZE * 2;
    unsigned short* base = (unsigned short*)(ws + 256);
    dim3 g768(MROWS / 128, EMB / 128);

    const size_t FULLB = 256 + 2ULL * (2 * W4E) + 2ULL * (4 * W2E)
                       + 2ULL * ((size_t)MROWS * 2304) + 2 * SZB
                       + 2ULL * ((size_t)MROWS * FFN);   // = 127,402,240 B
    const size_t FULLB2 = FULLB + 2ULL * SZE * 4;        // + 50.3 MB fp32 partials

    if (ws_size >= FULLB2) {
        // ---- full path + split-K FFN2 ----
        unsigned short* w1b   = base;
        unsigned short* w2b   = w1b + W4E;
        unsigned short* wqkvb = w2b + W4E;
        unsigned short* wob   = wqkvb + 3 * W2E;
        unsigned short* P     = wob + W2E;
        unsigned short* B0    = P + (size_t)MROWS * 2304;
        unsigned short* B1    = B0 + SZE;
        unsigned short* G     = B1 + SZE;
        float*          PK    = (float*)(G + (size_t)MROWS * FFN);  // 2 x M x N fp32

        {
            CvtArgs ca;
            ca.src[0] = wq; ca.src[1] = wk; ca.src[2] = wv;
            ca.src[3] = wo; ca.src[4] = w1; ca.src[5] = w2;
            ca.dst[0] = wqkvb; ca.dst[1] = wqkvb + W2E; ca.dst[2] = wqkvb + 2 * W2E;
            ca.dst[3] = wob;   ca.dst[4] = w1b;         ca.dst[5] = w2b;
            ca.n[0] = ca.n[1] = ca.n[2] = ca.n[3] = W2E; ca.n[4] = ca.n[5] = W4E;
            int off = 0;
            for (int s = 0; s < 6; ++s) { ca.blkoff[s] = off; off += ca.n[s] / 1024; }
            ca.blkoff[6] = off;
            ca.F = F;
            ca.fidx[0] = 1; ca.fidx[1] = 2; ca.fidx[2] = 3;
            ca.fidx[3] = 4; ca.fidx[4] = 5; ca.fidx[5] = 6;
            cvt_weights<<<off, blk, 0, stream>>>(ca);
        }

        ln_kernel<<<MROWS / 4, blk, 0, stream>>>(x, F+0, g1, F+7, s1, F+8, B1);
        dim3 gqkv(MROWS / 128, 2304 / 128);
        gemm_lds<false, false, false><<<gqkv, blk, 0, stream>>>(B1, wqkvb, nullptr, nullptr, 0, P, MROWS, 2304, EMB, EMB, EMB);
        fattn_kernel<<<BATCH * NHEADS * 8, blk, 0, stream>>>(P, P + 768, P + 1536, 2304, B0);
        gemm_lds<false, true, false><<<g768, blk, 0, stream>>>(B0, wob, x, F+0, 0, B1, MROWS, EMB, EMB, EMB, EMB);
        ln_kernel<<<MROWS / 4, blk, 0, stream>>>(B1, nullptr, g2, F+9, s2, F+10, B0);
        dim3 gffn1(MROWS / 128, FFN / 128);
        gemm_lds<true, false, false><<<gffn1, blk, 0, stream>>>(B0, w1b, nullptr, nullptr, 0, G, MROWS, FFN, EMB, EMB, EMB);
        // FFN2: split-K=2 -> fp32 partials, then fused reduce + residual
        dim3 gsk(MROWS / 128, EMB / 128, 2);
        gemm_lds<false, false, true><<<gsk, blk, 0, stream>>>(G, w2b, nullptr, nullptr, 0, PK, MROWS, EMB, FFN / 2, FFN, FFN);
        reduce2_kernel<<<(SZE / 4 + 255) / 256, blk, 0, stream>>>(PK, B1, (float*)d_out, SZE / 4);
    } else if (ws_size >= FULLB) {
        // ---- full path, single-launch FFN2 ----
        unsigned short* w1b   = base;
        unsigned short* w2b   = w1b + W4E;
        unsigned short* wqkvb = w2b + W4E;
        unsigned short* wob   = wqkvb + 3 * W2E;
        unsigned short* P     = wob + W2E;
        unsigned short* B0    = P + (size_t)MROWS * 2304;
        unsigned short* B1    = B0 + SZE;
        unsigned short* G     = B1 + SZE;

        {
            CvtArgs ca;
            ca.src[0] = wq; ca.src[1] = wk; ca.src[2] = wv;
            ca.src[3] = wo; ca.src[4] = w1; ca.src[5] = w2;
            ca.dst[0] = wqkvb; ca.dst[1] = wqkvb + W2E; ca.dst[2] = wqkvb + 2 * W2E;
            ca.dst[3] = wob;   ca.dst[4] = w1b;         ca.dst[5] = w2b;
            ca.n[0] = ca.n[1] = ca.n[2] = ca.n[3] = W2E; ca.n[4] = ca.n[5] = W4E;
            int off = 0;
            for (int s = 0; s < 6; ++s) { ca.blkoff[s] = off; off += ca.n[s] / 1024; }
            ca.blkoff[6] = off;
            ca.F = F;
            ca.fidx[0] = 1; ca.fidx[1] = 2; ca.fidx[2] = 3;
            ca.fidx[3] = 4; ca.fidx[4] = 5; ca.fidx[5] = 6;
            cvt_weights<<<off, blk, 0, stream>>>(ca);
        }

        ln_kernel<<<MROWS / 4, blk, 0, stream>>>(x, F+0, g1, F+7, s1, F+8, B1);
        dim3 gqkv(MROWS / 128, 2304 / 128);
        gemm_lds<false, false, false><<<gqkv, blk, 0, stream>>>(B1, wqkvb, nullptr, nullptr, 0, P, MROWS, 2304, EMB, EMB, EMB);
        fattn_kernel<<<BATCH * NHEADS * 8, blk, 0, stream>>>(P, P + 768, P + 1536, 2304, B0);
        gemm_lds<false, true, false><<<g768, blk, 0, stream>>>(B0, wob, x, F+0, 0, B1, MROWS, EMB, EMB, EMB, EMB);
        ln_kernel<<<MROWS / 4, blk, 0, stream>>>(B1, nullptr, g2, F+9, s2, F+10, B0);
        dim3 gffn1(MROWS / 128, FFN / 128);
        gemm_lds<true, false, false><<<gffn1, blk, 0, stream>>>(B0, w1b, nullptr, nullptr, 0, G, MROWS, FFN, EMB, EMB, EMB);
        gemm_lds<false, true, true><<<g768, blk, 0, stream>>>(G, w2b, B1, nullptr, 0, d_out, MROWS, EMB, FFN, FFN, FFN);
    } else if (ws_size >= 256 + 4 * SZB) {
        // ---- fallback tier M ----
        unsigned short* B0 = base;
        unsigned short* B1 = B0 + SZE;
        unsigned short* B2 = B1 + SZE;
        unsigned short* B3 = B2 + SZE;
        ln_kernel<<<MROWS / 4, blk, 0, stream>>>(x, F+0, g1, F+7, s1, F+8, B0);
        gemm_bt<false, false, false><<<g768, blk, 0, stream>>>(B0, wq, F+1, nullptr, nullptr, 0, B1, MROWS, EMB, EMB);
        gemm_bt<false, false, false><<<g768, blk, 0, stream>>>(B0, wk, F+2, nullptr, nullptr, 0, B2, MROWS, EMB, EMB);
        gemm_bt<false, false, false><<<g768, blk, 0, stream>>>(B0, wv, F+3, nullptr, nullptr, 0, B3, MROWS, EMB, EMB);
        fattn_kernel<<<BATCH * NHEADS * 8, blk, 0, stream>>>(B1, B2, B3, EMB, B0);
        gemm_bt<false, true, false><<<g768, blk, 0, stream>>>(B0, wo, F+4, x, F+0, 0, B1, MROWS, EMB, EMB);
        ln_kernel<<<MROWS / 4, blk, 0, stream>>>(B1, nullptr, g2, F+9, s2, F+10, B2);
        dim3 c3072(2048 / 128, FFN / 128), c768(2048 / 128, EMB / 128);
        for (int c = 0; c < 4; ++c) {
            const size_t r0 = (size_t)c * 2048;
            gemm_bt<true, false, false><<<c3072, blk, 0, stream>>>(B2 + r0 * EMB, w1, F+5, nullptr, nullptr, 0, B3, 2048, FFN, EMB);
            gemm_bt<false, true, true><<<c768, blk, 0, stream>>>(B3, w2, F+6, B1 + r0 * EMB, nullptr, 0, (float*)d_out + r0 * EMB, 2048, EMB, FFN);
        }
    } else {
        // ---- fallback tier B ----
        unsigned short* hlow = (unsigned short*)d_out;
        unsigned short* x2up = (unsigned short*)d_out + SZE;
        unsigned short* wsQ = base;
        unsigned short* wsK = wsQ + (size_t)1024 * EMB;
        unsigned short* wsV = wsK + (size_t)1024 * EMB;
        unsigned short* wsC = wsV + (size_t)1024 * EMB;
        ln_kernel<<<MROWS / 4, blk, 0, stream>>>(x, F+0, g1, F+7, s1, F+8, hlow);
        dim3 q768(1024 / 128, EMB / 128);
        for (int grp = 0; grp < BATCH; ++grp) {
            const size_t r0 = (size_t)grp * 1024;
            gemm_bt<false, false, false><<<q768, blk, 0, stream>>>(hlow + r0 * EMB, wq, F+1, nullptr, nullptr, 0, wsQ, 1024, EMB, EMB);
            gemm_bt<false, false, false><<<q768, blk, 0, stream>>>(hlow + r0 * EMB, wk, F+2, nullptr, nullptr, 0, wsK, 1024, EMB, EMB);
            gemm_bt<false, false, false><<<q768, blk, 0, stream>>>(hlow + r0 * EMB, wv, F+3, nullptr, nullptr, 0, wsV, 1024, EMB, EMB);
            fattn_kernel<<<1 * NHEADS * 8, blk, 0, stream>>>(wsQ, wsK, wsV, EMB, wsC);
            gemm_bt<false, true, false><<<q768, blk, 0, stream>>>(wsC, wo, F+4, x, F+0, r0 * EMB, x2up + r0 * EMB, 1024, EMB, EMB);
        }
        unsigned short* xb = base;
        unsigned short* h2 = xb + (size_t)1024 * EMB;
        unsigned short* gb = h2 + (size_t)1024 * EMB;
        dim3 f3072(1024 / 128, FFN / 128), f768(1024 / 128, EMB / 128);
        for (int c = 0; c < BATCH; ++c) {
            const size_t r0 = (size_t)c * 1024;
            hipMemcpyAsync(xb, x2up + r0 * EMB, (size_t)1024 * EMB * 2,
                           hipMemcpyDeviceToDevice, stream);
            ln_kernel<<<1024 / 4, blk, 0, stream>>>(xb, nullptr, g2, F+9, s2, F+10, h2);
            gemm_bt<true, false, false><<<f3072, blk, 0, stream>>>(h2, w1, F+5, nullptr, nullptr, 0, gb, 1024, FFN, EMB);
            gemm_bt<false, true, true><<<f768, blk, 0, stream>>>(gb, w2, F+6, xb, nullptr, 0, (float*)d_out + r0 * EMB, 1024, EMB, FFN);
        }
    }
}

// Round 13
// 428.273 us; speedup vs baseline: 6.0316x; 1.0277x over previous
//
#include <hip/hip_runtime.h>
#include <hip/hip_bf16.h>
#include <cstdint>

#define EMB    768
#define NHEADS 12
#define HDIM   64
#define SEQ    1024
#define BATCH  8
#define MROWS  (BATCH*SEQ)   /* 8192 */
#define FFN    3072
#define W2E    (EMB*EMB)     /* 589824 */
#define W4E    (FFN*EMB)     /* 2359296 */

typedef __bf16 bf16_t;
typedef bf16_t bf16x8 __attribute__((ext_vector_type(8)));
typedef float  f32x4  __attribute__((ext_vector_type(4)));

__device__ __forceinline__ float b2f(unsigned short u) {
    union { unsigned int i; float f; } t; t.i = ((unsigned int)u) << 16; return t.f;
}
__device__ __forceinline__ unsigned short f2b(float f) {
    union { float f; unsigned int i; } t; t.f = f;
    unsigned int lsb = (t.i >> 16) & 1u;
    t.i += 0x7fffu + lsb;
    return (unsigned short)(t.i >> 16);
}
// fast tanh-gelu: 0.5x(1+tanh(u)) = x * sigmoid(2u); safe in both tails
__device__ __forceinline__ float gelu_f(float x) {
    float u = 0.7978845608028654f * (x + 0.044715f * x * x * x);
    return x * (1.f / (1.f + __expf(-2.f * u)));
}

#if defined(__has_builtin)
#if __has_builtin(__builtin_amdgcn_global_load_lds)
#define HAS_GLL 1
#endif
#endif
#ifndef HAS_GLL
#define HAS_GLL 0
#endif

__device__ __forceinline__ void gll16(const unsigned short* g, unsigned short* lds_wave_base) {
#if HAS_GLL
    __builtin_amdgcn_global_load_lds(
        (const __attribute__((address_space(1))) unsigned int*)g,
        (__attribute__((address_space(3))) unsigned int*)lds_wave_base, 16, 0, 0);
#endif
}

__device__ __forceinline__ int4 load8(const void* src, size_t eoff, bool f32) {
    if (f32) {
        const float4* p = reinterpret_cast<const float4*>((const float*)src + eoff);
        float4 a = p[0], b = p[1];
        union { unsigned short u[8]; int4 v; } r;
        r.u[0] = f2b(a.x); r.u[1] = f2b(a.y); r.u[2] = f2b(a.z); r.u[3] = f2b(a.w);
        r.u[4] = f2b(b.x); r.u[5] = f2b(b.y); r.u[6] = f2b(b.z); r.u[7] = f2b(b.w);
        return r.v;
    }
    return *reinterpret_cast<const int4*>((const unsigned short*)src + eoff);
}
__device__ __forceinline__ float4 load4f(const void* src, size_t eoff, bool f32) {
    if (f32) return *reinterpret_cast<const float4*>((const float*)src + eoff);
    ushort4 u = *reinterpret_cast<const ushort4*>((const unsigned short*)src + eoff);
    float4 r; r.x = b2f(u.x); r.y = b2f(u.y); r.z = b2f(u.z); r.w = b2f(u.w);
    return r;
}

// ---------------- dtype probe: one block per input ------------------------
struct DetectArgs { const unsigned short* p[11]; int n[11]; };

__global__ __launch_bounds__(256) void detect_all(DetectArgs a, int* __restrict__ flags) {
    __shared__ int cnt;
    if (threadIdx.x == 0) cnt = 0;
    __syncthreads();
    const unsigned short* src = a.p[blockIdx.x];
    int npairs = a.n[blockIdx.x] / 2;
    if (npairs > 4096) npairs = 4096;
    int local = 0;
    for (int p = threadIdx.x; p < npairs; p += 256) {
        unsigned short u0 = src[2 * p], u1 = src[2 * p + 1];
        int e0 = (u0 >> 7) & 0xFF;
        bool insane0 = (e0 == 0xFF) || (u0 != 0 && (e0 < 96 || e0 > 159));
        bool zpat    = (u0 == 0 && u1 != 0);
        if (insane0 || zpat) ++local;
    }
    atomicAdd(&cnt, local);
    __syncthreads();
    if (threadIdx.x == 0) flags[blockIdx.x] = (cnt * 8 > npairs) ? 1 : 0;
}

// ---------------- adaptive convert (middle tier) --------------------------
__global__ __launch_bounds__(256) void cvt_adapt(
        const void* __restrict__ src, unsigned short* __restrict__ dst,
        int n, const int* __restrict__ flag) {
    int i = blockIdx.x * 256 + threadIdx.x;
    if (i * 4 >= n) return;
    if (*flag) {
        float4 f = reinterpret_cast<const float4*>(src)[i];
        ushort4 o;
        o.x = f2b(f.x); o.y = f2b(f.y); o.z = f2b(f.z); o.w = f2b(f.w);
        reinterpret_cast<ushort4*>(dst)[i] = o;
    } else {
        reinterpret_cast<ushort4*>(dst)[i] = reinterpret_cast<const ushort4*>(src)[i];
    }
}

// ---------------- fused weight convert: all 6 weights, one launch ---------
struct CvtArgs {
    const void* src[6];
    unsigned short* dst[6];
    int n[6];
    int blkoff[7];
    const int* F;
    int fidx[6];
};
__global__ __launch_bounds__(256) void cvt_weights(CvtArgs a) {
    int b = blockIdx.x, seg = 0;
    #pragma unroll
    for (int s = 0; s < 6; ++s) if (b >= a.blkoff[s + 1]) seg = s + 1;
    int i = (b - a.blkoff[seg]) * 256 + threadIdx.x;
    if (i * 4 >= a.n[seg]) return;
    if (a.F[a.fidx[seg]]) {
        float4 f = reinterpret_cast<const float4*>(a.src[seg])[i];
        ushort4 o;
        o.x = f2b(f.x); o.y = f2b(f.y); o.z = f2b(f.z); o.w = f2b(f.w);
        reinterpret_cast<ushort4*>(a.dst[seg])[i] = o;
    } else {
        reinterpret_cast<ushort4*>(a.dst[seg])[i] =
            reinterpret_cast<const ushort4*>(a.src[seg])[i];
    }
}

// ---------------- split-K reduce: out = P0 + P1 + resid (fp32 out) --------
__global__ __launch_bounds__(256) void reduce2_kernel(
        const float* __restrict__ P, const unsigned short* __restrict__ resid,
        float* __restrict__ out, int n4) {
    int i = blockIdx.x * 256 + threadIdx.x;
    if (i >= n4) return;
    float4 a = reinterpret_cast<const float4*>(P)[i];
    float4 b = reinterpret_cast<const float4*>(P + (size_t)MROWS * EMB)[i];
    ushort4 r = reinterpret_cast<const ushort4*>(resid)[i];
    float4 o;
    o.x = a.x + b.x + b2f(r.x);
    o.y = a.y + b.y + b2f(r.y);
    o.z = a.z + b.z + b2f(r.z);
    o.w = a.w + b.w + b2f(r.w);
    reinterpret_cast<float4*>(out)[i] = o;
}

// ---------------- LayerNorm: one wave per row; bf16 out -------------------
__global__ __launch_bounds__(256) void ln_kernel(
        const void* __restrict__ x,     const int* __restrict__ fx,
        const void* __restrict__ scale, const int* __restrict__ fsc,
        const void* __restrict__ shift, const int* __restrict__ fsh,
        unsigned short* __restrict__ out) {
    const bool xf = fx && *fx, scf = fsc && *fsc, shf = fsh && *fsh;
    int wave = threadIdx.x >> 6;
    int lane = threadIdx.x & 63;
    int row  = blockIdx.x * 4 + wave;
    const size_t rbase = (size_t)row * EMB;
    float v[12];
    float s = 0.f, s2 = 0.f;
    #pragma unroll
    for (int i = 0; i < 3; ++i) {
        float4 a = load4f(x, rbase + i * 256 + lane * 4, xf);
        v[i*4+0] = a.x; v[i*4+1] = a.y; v[i*4+2] = a.z; v[i*4+3] = a.w;
        s  += a.x + a.y + a.z + a.w;
        s2 += a.x*a.x + a.y*a.y + a.z*a.z + a.w*a.w;
    }
    #pragma unroll
    for (int off = 1; off < 64; off <<= 1) {
        s  += __shfl_xor(s,  off);
        s2 += __shfl_xor(s2, off);
    }
    float mean = s * (1.f / EMB);
    float var  = fmaxf(s2 * (1.f / EMB) - mean * mean, 0.f);
    float rstd = rsqrtf(var + 1e-5f);
    unsigned short* orow = out + rbase;
    #pragma unroll
    for (int i = 0; i < 3; ++i) {
        float4 sc = load4f(scale, i * 256 + lane * 4, scf);
        float4 sh = load4f(shift, i * 256 + lane * 4, shf);
        ushort4 o;
        o.x = f2b((v[i*4+0] - mean) * rstd * sc.x + sh.x);
        o.y = f2b((v[i*4+1] - mean) * rstd * sc.y + sh.y);
        o.z = f2b((v[i*4+2] - mean) * rstd * sc.z + sh.z);
        o.w = f2b((v[i*4+3] - mean) * rstd * sc.w + sh.w);
        *reinterpret_cast<ushort4*>(orow + i * 256 + lane * 4) = o;
    }
}

// ---------------- gemm_lds: bf16 GEMM, async LDS staging, XOR-swizzled ----
// C[M,N] = A[M,K-slice] @ W[N,K-slice]^T. lda/ldw row strides (elements).
// Split-K via blockIdx.z. LDS layout: lane ell of the 256-thread staging set
// fetches col-group (ell&3)^((ell>>3)&3) so that fragment ds_read_b128s
// spread 16 consecutive lanes over all 8 bank-groups (2/bank = free, m136).
template<bool GELU, bool RESID, bool OUTF32>
__global__ __launch_bounds__(256) void gemm_lds(
        const unsigned short* __restrict__ A,
        const unsigned short* __restrict__ W,
        const void* R, const int* __restrict__ fR, size_t rOff,
        void* C, int M, int N, int K, int lda, int ldw) {
    constexpr int BK = 32;
    __shared__ __align__(16) unsigned short sA[128 * BK];
    __shared__ __align__(16) unsigned short sB[128 * BK];
    const int m0 = blockIdx.x * 128, n0 = blockIdx.y * 128;
    const int kz = blockIdx.z;
    const int t = threadIdx.x, wave = t >> 6, lane = t & 63;
    const int wrow = (wave >> 1) * 64, wcol = (wave & 1) * 64;
    const int quad = lane >> 4, lr = lane & 15;
    const int r0 = t >> 2;                          // staging row 0..63
    const int scg = (t & 3) ^ ((t >> 3) & 3);       // swizzled col-group
    const int c0 = scg * 8;
    const int xq = quad ^ ((lr >> 1) & 3);          // read-side xor (lane-const)
    const bool rf = fR && *fR;

    A += (size_t)kz * K;
    W += (size_t)kz * K;

    f32x4 acc[4][4];
    #pragma unroll
    for (int i = 0; i < 4; ++i)
        #pragma unroll
        for (int j = 0; j < 4; ++j)
            acc[i][j] = (f32x4){0.f, 0.f, 0.f, 0.f};

    const unsigned short* gA0 = A + (size_t)(m0 + r0) * lda + c0;
    const unsigned short* gA1 = A + (size_t)(m0 + 64 + r0) * lda + c0;
    const unsigned short* gB0 = W + (size_t)(n0 + r0) * ldw + c0;
    const unsigned short* gB1 = W + (size_t)(n0 + 64 + r0) * ldw + c0;
    unsigned short* lA0 = sA + wave * 512;
    unsigned short* lA1 = sA + 2048 + wave * 512;
    unsigned short* lB0 = sB + wave * 512;
    unsigned short* lB1 = sB + 2048 + wave * 512;

    for (int k0 = 0; k0 < K; k0 += BK) {
#if HAS_GLL
        gll16(gA0 + k0, lA0);
        gll16(gA1 + k0, lA1);
        gll16(gB0 + k0, lB0);
        gll16(gB1 + k0, lB1);
#else
        *reinterpret_cast<int4*>(sA + t * 8)        = *reinterpret_cast<const int4*>(gA0 + k0);
        *reinterpret_cast<int4*>(sA + 2048 + t * 8) = *reinterpret_cast<const int4*>(gA1 + k0);
        *reinterpret_cast<int4*>(sB + t * 8)        = *reinterpret_cast<const int4*>(gB0 + k0);
        *reinterpret_cast<int4*>(sB + 2048 + t * 8) = *reinterpret_cast<const int4*>(gB1 + k0);
#endif
        __syncthreads();
        bf16x8 af[4], bfv[4];
        #pragma unroll
        for (int i = 0; i < 4; ++i)
            af[i] = *reinterpret_cast<const bf16x8*>(
                sA + (wrow >> 6) * 2048 + (i * 16 + lr) * 32 + xq * 8);
        #pragma unroll
        for (int j = 0; j < 4; ++j)
            bfv[j] = *reinterpret_cast<const bf16x8*>(
                sB + (wcol >> 6) * 2048 + (j * 16 + lr) * 32 + xq * 8);
        #pragma unroll
        for (int i = 0; i < 4; ++i)
            #pragma unroll
            for (int j = 0; j < 4; ++j)
                acc[i][j] = __builtin_amdgcn_mfma_f32_16x16x32_bf16(af[i], bfv[j], acc[i][j], 0, 0, 0);
        __syncthreads();
    }

    float* Cf = (float*)C + (size_t)kz * M * N;
    #pragma unroll
    for (int i = 0; i < 4; ++i) {
        #pragma unroll
        for (int j = 0; j < 4; ++j) {
            #pragma unroll
            for (int r = 0; r < 4; ++r) {
                int row = m0 + wrow + i * 16 + quad * 4 + r;
                int col = n0 + wcol + j * 16 + lr;
                float val = acc[i][j][r];
                if (GELU) val = gelu_f(val);
                size_t idx = (size_t)row * N + col;
                if (RESID) {
                    float rv = rf ? ((const float*)R)[idx + rOff]
                                  : b2f(((const unsigned short*)R)[idx + rOff]);
                    val += rv;
                }
                if (OUTF32) Cf[idx] = val;
                else        ((unsigned short*)C)[idx] = f2b(val);
            }
        }
    }
}

// ---------------- legacy flagged GEMM (fallback tiers only) ---------------
template<bool GELU, bool RESID, bool OUTF32>
__global__ __launch_bounds__(256) void gemm_bt(
        const unsigned short* __restrict__ A,
        const void* __restrict__ W, const int* __restrict__ fW,
        const void* R, const int* __restrict__ fR, size_t rOff,
        void* C,
        int M, int N, int K) {
    const bool wf = fW && *fW;
    const bool rf = fR && *fR;
    constexpr int BK = 32, PAD = 8, LDW = BK + PAD;
    __shared__ __align__(16) unsigned short sA[128 * LDW];
    __shared__ __align__(16) unsigned short sB[128 * LDW];
    const int m0 = blockIdx.x * 128;
    const int n0 = blockIdx.y * 128;
    const int t    = threadIdx.x;
    const int wave = t >> 6, lane = t & 63;
    const int wrow = (wave >> 1) * 64, wcol = (wave & 1) * 64;
    const int quad = lane >> 4, lr = lane & 15;
    const int srow = t >> 2, scol = (t & 3) * 8;

    f32x4 acc[4][4];
    #pragma unroll
    for (int i = 0; i < 4; ++i)
        #pragma unroll
        for (int j = 0; j < 4; ++j)
            acc[i][j] = (f32x4){0.f, 0.f, 0.f, 0.f};

    const size_t aBase = (size_t)(m0 + srow) * K + scol;
    const size_t bBase = (size_t)(n0 + srow) * K + scol;

    for (int k0 = 0; k0 < K; k0 += BK) {
        int4 av0 = *reinterpret_cast<const int4*>(A + aBase + k0);
        int4 av1 = *reinterpret_cast<const int4*>(A + aBase + (size_t)64 * K + k0);
        int4 bv0 = load8(W, bBase + k0, wf);
        int4 bv1 = load8(W, bBase + (size_t)64 * K + k0, wf);
        *reinterpret_cast<int4*>(sA + srow * LDW + scol)        = av0;
        *reinterpret_cast<int4*>(sA + (srow + 64) * LDW + scol) = av1;
        *reinterpret_cast<int4*>(sB + srow * LDW + scol)        = bv0;
        *reinterpret_cast<int4*>(sB + (srow + 64) * LDW + scol) = bv1;
        __syncthreads();
        bf16x8 af[4], bfv[4];
        #pragma unroll
        for (int i = 0; i < 4; ++i)
            af[i] = *reinterpret_cast<const bf16x8*>(sA + (wrow + i * 16 + lr) * LDW + quad * 8);
        #pragma unroll
        for (int j = 0; j < 4; ++j)
            bfv[j] = *reinterpret_cast<const bf16x8*>(sB + (wcol + j * 16 + lr) * LDW + quad * 8);
        #pragma unroll
        for (int i = 0; i < 4; ++i)
            #pragma unroll
            for (int j = 0; j < 4; ++j)
                acc[i][j] = __builtin_amdgcn_mfma_f32_16x16x32_bf16(af[i], bfv[j], acc[i][j], 0, 0, 0);
        __syncthreads();
    }

    #pragma unroll
    for (int i = 0; i < 4; ++i) {
        #pragma unroll
        for (int j = 0; j < 4; ++j) {
            #pragma unroll
            for (int r = 0; r < 4; ++r) {
                int row = m0 + wrow + i * 16 + quad * 4 + r;
                int col = n0 + wcol + j * 16 + lr;
                float val = acc[i][j][r];
                if (GELU) val = gelu_f(val);
                size_t idx = (size_t)row * N + col;
                if (RESID) {
                    float rv = rf ? ((const float*)R)[idx + rOff]
                                  : b2f(((const unsigned short*)R)[idx + rOff]);
                    val += rv;
                }
                if (OUTF32) ((float*)C)[idx] = val;
                else        ((unsigned short*)C)[idx] = f2b(val);
            }
        }
    }
}

// ---------------- MFMA flash attention, paired 64-q tiles ------------------
__global__ __launch_bounds__(256) void fattn_kernel(
        const unsigned short* __restrict__ q,
        const unsigned short* __restrict__ k,
        const unsigned short* __restrict__ v,
        int rs, unsigned short* __restrict__ ctx) {
    constexpr int VTP = 72;
    __shared__ unsigned short Vt[64 * VTP];
    __shared__ unsigned short Pl[4][16 * VTP];
    const int tid  = threadIdx.x;
    const int wave = tid >> 6, lane = tid & 63;
    const int quad = lane >> 4, lr = lane & 15;
    const int NH   = gridDim.x >> 3;
    const int head = blockIdx.x % NH;
    const int pr   = blockIdx.x / NH;
    const int bb   = head / NHEADS, hd = head % NHEADS;
    const size_t seqbase = (size_t)bb * SEQ;

    #pragma unroll
    for (int seg = 0; seg < 2; ++seg) {
        const int qt = seg == 0 ? (15 - pr) : pr;
        const int q0 = qt * 64 + wave * 16;

        bf16x8 aQ0, aQ1;
        {
            const unsigned short* qp = q + (seqbase + q0 + lr) * rs + hd * HDIM + quad * 8;
            aQ0 = *reinterpret_cast<const bf16x8*>(qp);
            aQ1 = *reinterpret_cast<const bf16x8*>(qp + 32);
        }

        f32x4 O[4];
        #pragma unroll
        for (int i = 0; i < 4; ++i) O[i] = (f32x4){0.f, 0.f, 0.f, 0.f};
        float mrow[4], lrow[4];
        #pragma unroll
        for (int r = 0; r < 4; ++r) { mrow[r] = -__builtin_inff(); lrow[r] = 0.f; }

        for (int kt = 0; kt <= qt; ++kt) {
            {
                const int vrow = tid >> 2;
                const int vcol = (tid & 3) * 16;
                const unsigned short* vp = v + (seqbase + kt * 64 + vrow) * rs + hd * HDIM + vcol;
                union { int4 v4; unsigned short u[8]; } ua, ub;
                ua.v4 = *reinterpret_cast<const int4*>(vp);
                ub.v4 = *reinterpret_cast<const int4*>(vp + 8);
                #pragma unroll
                for (int e = 0; e < 8; ++e) Vt[(vcol + e) * VTP + vrow]     = ua.u[e];
                #pragma unroll
                for (int e = 0; e < 8; ++e) Vt[(vcol + 8 + e) * VTP + vrow] = ub.u[e];
            }
            __syncthreads();

            f32x4 S[4];
            #pragma unroll
            for (int sub = 0; sub < 4; ++sub) {
                const unsigned short* kp = k + (seqbase + kt * 64 + sub * 16 + lr) * rs + hd * HDIM + quad * 8;
                bf16x8 b0 = *reinterpret_cast<const bf16x8*>(kp);
                bf16x8 b1 = *reinterpret_cast<const bf16x8*>(kp + 32);
                f32x4 accS = (f32x4){0.f, 0.f, 0.f, 0.f};
                accS = __builtin_amdgcn_mfma_f32_16x16x32_bf16(aQ0, b0, accS, 0, 0, 0);
                accS = __builtin_amdgcn_mfma_f32_16x16x32_bf16(aQ1, b1, accS, 0, 0, 0);
                S[sub] = accS;
            }
            const bool diag = (kt == qt);
            #pragma unroll
            for (int sub = 0; sub < 4; ++sub) {
                const int kg = kt * 64 + sub * 16 + lr;
                #pragma unroll
                for (int r = 0; r < 4; ++r) {
                    float s = S[sub][r] * 0.125f;
                    if (diag && kg > q0 + quad * 4 + r) s = -__builtin_inff();
                    S[sub][r] = s;
                }
            }
            float mnew[4], alpha[4];
            #pragma unroll
            for (int r = 0; r < 4; ++r) {
                float mx = fmaxf(fmaxf(S[0][r], S[1][r]), fmaxf(S[2][r], S[3][r]));
                #pragma unroll
                for (int m = 1; m < 16; m <<= 1) mx = fmaxf(mx, __shfl_xor(mx, m));
                mnew[r]  = fmaxf(mrow[r], mx);
                alpha[r] = __expf(mrow[r] - mnew[r]);
                mrow[r]  = mnew[r];
            }
            float rsum[4] = {0.f, 0.f, 0.f, 0.f};
            #pragma unroll
            for (int sub = 0; sub < 4; ++sub)
                #pragma unroll
                for (int r = 0; r < 4; ++r) {
                    float p = __expf(S[sub][r] - mnew[r]);
                    S[sub][r] = p;
                    rsum[r] += p;
                }
            #pragma unroll
            for (int r = 0; r < 4; ++r) {
                float rs2 = rsum[r];
                #pragma unroll
                for (int m = 1; m < 16; m <<= 1) rs2 += __shfl_xor(rs2, m);
                lrow[r] = lrow[r] * alpha[r] + rs2;
            }
            #pragma unroll
            for (int d = 0; d < 4; ++d)
                #pragma unroll
                for (int r = 0; r < 4; ++r)
                    O[d][r] *= alpha[r];

            unsigned short* Pw = Pl[wave];
            #pragma unroll
            for (int sub = 0; sub < 4; ++sub)
                #pragma unroll
                for (int r = 0; r < 4; ++r)
                    Pw[(quad * 4 + r) * VTP + sub * 16 + lr] = f2b(S[sub][r]);
            __syncthreads();

            #pragma unroll
            for (int c = 0; c < 2; ++c) {
                bf16x8 aP = *reinterpret_cast<const bf16x8*>(&Pw[lr * VTP + c * 32 + quad * 8]);
                #pragma unroll
                for (int d = 0; d < 4; ++d) {
                    bf16x8 bV = *reinterpret_cast<const bf16x8*>(&Vt[(d * 16 + lr) * VTP + c * 32 + quad * 8]);
                    O[d] = __builtin_amdgcn_mfma_f32_16x16x32_bf16(aP, bV, O[d], 0, 0, 0);
                }
            }
            __syncthreads();
        }

        #pragma unroll
        for (int r = 0; r < 4; ++r) {
            const float rinv = 1.f / lrow[r];
            const int qg = q0 + quad * 4 + r;
            unsigned short* crow = ctx + (seqbase + qg) * EMB + hd * HDIM;
            #pragma unroll
            for (int d = 0; d < 4; ++d)
                crow[d * 16 + lr] = f2b(O[d][r] * rinv);
        }
    }
}

// ---------------------------------------------------------------------------
extern "C" void kernel_launch(void* const* d_in, const int* in_sizes, int n_in,
                              void* d_out, int out_size, void* d_ws, size_t ws_size,
                              hipStream_t stream) {
    const void* x  = d_in[0];
    const void* wq = d_in[1], *wk = d_in[2], *wv = d_in[3], *wo = d_in[4];
    const void* w1 = d_in[5], *w2 = d_in[6];
    const void* g1 = d_in[7], *s1 = d_in[8], *g2 = d_in[9], *s2 = d_in[10];
    char* ws = (char*)d_ws;
    dim3 blk(256);

    int* F = (int*)ws;
    {
        DetectArgs da;
        for (int i = 0; i < 11; ++i) { da.p[i] = (const unsigned short*)d_in[i]; da.n[i] = in_sizes[i]; }
        detect_all<<<11, blk, 0, stream>>>(da, F);
    }

    const size_t SZE = (size_t)MROWS * EMB;
    const size_t SZB = SZE * 2;
    unsigned short* base = (unsigned short*)(ws + 256);
    dim3 g768(MROWS / 128, EMB / 128);

    const size_t FULLB = 256 + 2ULL * (2 * W4E) + 2ULL * (4 * W2E)
                       + 2ULL * ((size_t)MROWS * 2304) + 2 * SZB
                       + 2ULL * ((size_t)MROWS * FFN);   // = 127,402,240 B
    const size_t FULLB2 = FULLB + 2ULL * SZE * 4;        // + 50.3 MB fp32 partials

    if (ws_size >= FULLB2) {
        // ---- full path + split-K FFN2 ----
        unsigned short* w1b   = base;
        unsigned short* w2b   = w1b + W4E;
        unsigned short* wqkvb = w2b + W4E;
        unsigned short* wob   = wqkvb + 3 * W2E;
        unsigned short* P     = wob + W2E;
        unsigned short* B0    = P + (size_t)MROWS * 2304;
        unsigned short* B1    = B0 + SZE;
        unsigned short* G     = B1 + SZE;
        float*          PK    = (float*)(G + (size_t)MROWS * FFN);

        {
            CvtArgs ca;
            ca.src[0] = wq; ca.src[1] = wk; ca.src[2] = wv;
            ca.src[3] = wo; ca.src[4] = w1; ca.src[5] = w2;
            ca.dst[0] = wqkvb; ca.dst[1] = wqkvb + W2E; ca.dst[2] = wqkvb + 2 * W2E;
            ca.dst[3] = wob;   ca.dst[4] = w1b;         ca.dst[5] = w2b;
            ca.n[0] = ca.n[1] = ca.n[2] = ca.n[3] = W2E; ca.n[4] = ca.n[5] = W4E;
            int off = 0;
            for (int s = 0; s < 6; ++s) { ca.blkoff[s] = off; off += ca.n[s] / 1024; }
            ca.blkoff[6] = off;
            ca.F = F;
            ca.fidx[0] = 1; ca.fidx[1] = 2; ca.fidx[2] = 3;
            ca.fidx[3] = 4; ca.fidx[4] = 5; ca.fidx[5] = 6;
            cvt_weights<<<off, blk, 0, stream>>>(ca);
        }

        ln_kernel<<<MROWS / 4, blk, 0, stream>>>(x, F+0, g1, F+7, s1, F+8, B1);
        dim3 gqkv(MROWS / 128, 2304 / 128);
        gemm_lds<false, false, false><<<gqkv, blk, 0, stream>>>(B1, wqkvb, nullptr, nullptr, 0, P, MROWS, 2304, EMB, EMB, EMB);
        fattn_kernel<<<BATCH * NHEADS * 8, blk, 0, stream>>>(P, P + 768, P + 1536, 2304, B0);
        gemm_lds<false, true, false><<<g768, blk, 0, stream>>>(B0, wob, x, F+0, 0, B1, MROWS, EMB, EMB, EMB, EMB);
        ln_kernel<<<MROWS / 4, blk, 0, stream>>>(B1, nullptr, g2, F+9, s2, F+10, B0);
        dim3 gffn1(MROWS / 128, FFN / 128);
        gemm_lds<true, false, false><<<gffn1, blk, 0, stream>>>(B0, w1b, nullptr, nullptr, 0, G, MROWS, FFN, EMB, EMB, EMB);
        dim3 gsk(MROWS / 128, EMB / 128, 2);
        gemm_lds<false, false, true><<<gsk, blk, 0, stream>>>(G, w2b, nullptr, nullptr, 0, PK, MROWS, EMB, FFN / 2, FFN, FFN);
        reduce2_kernel<<<(SZE / 4 + 255) / 256, blk, 0, stream>>>(PK, B1, (float*)d_out, SZE / 4);
    } else if (ws_size >= FULLB) {
        // ---- full path, single-launch FFN2 ----
        unsigned short* w1b   = base;
        unsigned short* w2b   = w1b + W4E;
        unsigned short* wqkvb = w2b + W4E;
        unsigned short* wob   = wqkvb + 3 * W2E;
        unsigned short* P     = wob + W2E;
        unsigned short* B0    = P + (size_t)MROWS * 2304;
        unsigned short* B1    = B0 + SZE;
        unsigned short* G     = B1 + SZE;

        {
            CvtArgs ca;
            ca.src[0] = wq; ca.src[1] = wk; ca.src[2] = wv;
            ca.src[3] = wo; ca.src[4] = w1; ca.src[5] = w2;
            ca.dst[0] = wqkvb; ca.dst[1] = wqkvb + W2E; ca.dst[2] = wqkvb + 2 * W2E;
            ca.dst[3] = wob;   ca.dst[4] = w1b;         ca.dst[5] = w2b;
            ca.n[0] = ca.n[1] = ca.n[2] = ca.n[3] = W2E; ca.n[4] = ca.n[5] = W4E;
            int off = 0;
            for (int s = 0; s < 6; ++s) { ca.blkoff[s] = off; off += ca.n[s] / 1024; }
            ca.blkoff[6] = off;
            ca.F = F;
            ca.fidx[0] = 1; ca.fidx[1] = 2; ca.fidx[2] = 3;
            ca.fidx[3] = 4; ca.fidx[4] = 5; ca.fidx[5] = 6;
            cvt_weights<<<off, blk, 0, stream>>>(ca);
        }

        ln_kernel<<<MROWS / 4, blk, 0, stream>>>(x, F+0, g1, F+7, s1, F+8, B1);
        dim3 gqkv(MROWS / 128, 2304 / 128);
        gemm_lds<false, false, false><<<gqkv, blk, 0, stream>>>(B1, wqkvb, nullptr, nullptr, 0, P, MROWS, 2304, EMB, EMB, EMB);
        fattn_kernel<<<BATCH * NHEADS * 8, blk, 0, stream>>>(P, P + 768, P + 1536, 2304, B0);
        gemm_lds<false, true, false><<<g768, blk, 0, stream>>>(B0, wob, x, F+0, 0, B1, MROWS, EMB, EMB, EMB, EMB);
        ln_kernel<<<MROWS / 4, blk, 0, stream>>>(B1, nullptr, g2, F+9, s2, F+10, B0);
        dim3 gffn1(MROWS / 128, FFN / 128);
        gemm_lds<true, false, false><<<gffn1, blk, 0, stream>>>(B0, w1b, nullptr, nullptr, 0, G, MROWS, FFN, EMB, EMB, EMB);
        gemm_lds<false, true, true><<<g768, blk, 0, stream>>>(G, w2b, B1, nullptr, 0, d_out, MROWS, EMB, FFN, FFN, FFN);
    } else if (ws_size >= 256 + 4 * SZB) {
        // ---- fallback tier M ----
        unsigned short* B0 = base;
        unsigned short* B1 = B0 + SZE;
        unsigned short* B2 = B1 + SZE;
        unsigned short* B3 = B2 + SZE;
        ln_kernel<<<MROWS / 4, blk, 0, stream>>>(x, F+0, g1, F+7, s1, F+8, B0);
        gemm_bt<false, false, false><<<g768, blk, 0, stream>>>(B0, wq, F+1, nullptr, nullptr, 0, B1, MROWS, EMB, EMB);
        gemm_bt<false, false, false><<<g768, blk, 0, stream>>>(B0, wk, F+2, nullptr, nullptr, 0, B2, MROWS, EMB, EMB);
        gemm_bt<false, false, false><<<g768, blk, 0, stream>>>(B0, wv, F+3, nullptr, nullptr, 0, B3, MROWS, EMB, EMB);
        fattn_kernel<<<BATCH * NHEADS * 8, blk, 0, stream>>>(B1, B2, B3, EMB, B0);
        gemm_bt<false, true, false><<<g768, blk, 0, stream>>>(B0, wo, F+4, x, F+0, 0, B1, MROWS, EMB, EMB);
        ln_kernel<<<MROWS / 4, blk, 0, stream>>>(B1, nullptr, g2, F+9, s2, F+10, B2);
        dim3 c3072(2048 / 128, FFN / 128), c768(2048 / 128, EMB / 128);
        for (int c = 0; c < 4; ++c) {
            const size_t r0 = (size_t)c * 2048;
            gemm_bt<true, false, false><<<c3072, blk, 0, stream>>>(B2 + r0 * EMB, w1, F+5, nullptr, nullptr, 0, B3, 2048, FFN, EMB);
            gemm_bt<false, true, true><<<c768, blk, 0, stream>>>(B3, w2, F+6, B1 + r0 * EMB, nullptr, 0, (float*)d_out + r0 * EMB, 2048, EMB, FFN);
        }
    } else {
        // ---- fallback tier B ----
        unsigned short* hlow = (unsigned short*)d_out;
        unsigned short* x2up = (unsigned short*)d_out + SZE;
        unsigned short* wsQ = base;
        unsigned short* wsK = wsQ + (size_t)1024 * EMB;
        unsigned short* wsV = wsK + (size_t)1024 * EMB;
        unsigned short* wsC = wsV + (size_t)1024 * EMB;
        ln_kernel<<<MROWS / 4, blk, 0, stream>>>(x, F+0, g1, F+7, s1, F+8, hlow);
        dim3 q768(1024 / 128, EMB / 128);
        for (int grp = 0; grp < BATCH; ++grp) {
            const size_t r0 = (size_t)grp * 1024;
            gemm_bt<false, false, false><<<q768, blk, 0, stream>>>(hlow + r0 * EMB, wq, F+1, nullptr, nullptr, 0, wsQ, 1024, EMB, EMB);
            gemm_bt<false, false, false><<<q768, blk, 0, stream>>>(hlow + r0 * EMB, wk, F+2, nullptr, nullptr, 0, wsK, 1024, EMB, EMB);
            gemm_bt<false, false, false><<<q768, blk, 0, stream>>>(hlow + r0 * EMB, wv, F+3, nullptr, nullptr, 0, wsV, 1024, EMB, EMB);
            fattn_kernel<<<1 * NHEADS * 8, blk, 0, stream>>>(wsQ, wsK, wsV, EMB, wsC);
            gemm_bt<false, true, false><<<q768, blk, 0, stream>>>(wsC, wo, F+4, x, F+0, r0 * EMB, x2up + r0 * EMB, 1024, EMB, EMB);
        }
        unsigned short* xb = base;
        unsigned short* h2 = xb + (size_t)1024 * EMB;
        unsigned short* gb = h2 + (size_t)1024 * EMB;
        dim3 f3072(1024 / 128, FFN / 128), f768(1024 / 128, EMB / 128);
        for (int c = 0; c < BATCH; ++c) {
            const size_t r0 = (size_t)c * 1024;
            hipMemcpyAsync(xb, x2up + r0 * EMB, (size_t)1024 * EMB * 2,
                           hipMemcpyDeviceToDevice, stream);
            ln_kernel<<<1024 / 4, blk, 0, stream>>>(xb, nullptr, g2, F+9, s2, F+10, h2);
            gemm_bt<true, false, false><<<f3072, blk, 0, stream>>>(h2, w1, F+5, nullptr, nullptr, 0, gb, 1024, FFN, EMB);
            gemm_bt<false, true, true><<<f768, blk, 0, stream>>>(gb, w2, F+6, xb, nullptr, 0, (float*)d_out + r0 * EMB, 1024, EMB, FFN);
        }
    }
}